// Round 8
// baseline (969.585 us; speedup 1.0000x reference)
//
#include <hip/hip_runtime.h>
#include <math.h>

#define NLINES 2048
#define WPL 32
#define EMBD 300
#define AD 400
#define NH 8
#define DPH 50
#define QKV_S 52
#define SC_S 36
#define BATCH 16
#define LPD 128
#define NCOLS 1200     // 3 proj * 400
#define NPAD 1280      // padded col count for Wt tables
#define WLINE_FL 39936 // per-line floats in word layout: 8*3*32*52
#define HBLK 4992      // per-(line,head) floats: 3*32*52

typedef __bf16 bf16;
typedef bf16  v8bf __attribute__((ext_vector_type(8)));
typedef float v4f  __attribute__((ext_vector_type(4)));

__device__ __forceinline__ float elu(float x) {
    return x > 0.f ? x : expm1f(x);
}

#define SCALE 7.0710678118654755f   // sqrt(50)

// ===========================================================================
// Split helpers: fp32 -> (hi, lo) bf16 pair.  x ~= hi + lo, rel err ~2^-18.
// ===========================================================================
__global__ void split_rows(const float* __restrict__ src,
                           bf16* __restrict__ hi, bf16* __restrict__ lo,
                           int rows, int K, int K2)
{
    long idx = (long)blockIdx.x * 256 + threadIdx.x;
    if (idx >= (long)rows * K2) return;
    int r = (int)(idx / K2), k = (int)(idx - (long)r * K2);
    float x = (k < K) ? src[(long)r * K + k] : 0.f;
    bf16 h = (bf16)x;
    float hf = (float)h;
    bf16 l = (bf16)(x - hf);
    hi[idx] = h; lo[idx] = l;
}

__global__ void split_wt(const float* __restrict__ W0, const float* __restrict__ W1,
                         const float* __restrict__ W2,
                         const float* __restrict__ B0, const float* __restrict__ B1,
                         const float* __restrict__ B2,
                         bf16* __restrict__ hi, bf16* __restrict__ lo,
                         float* __restrict__ biasCat, int K, int K2)
{
    long idx = (long)blockIdx.x * 256 + threadIdx.x;
    if (idx >= (long)NPAD * K2) return;
    int n = (int)(idx / K2), k = (int)(idx - (long)n * K2);
    float x = 0.f;
    if (k < K && n < NCOLS) {
        int p = n / 400, c = n - p * 400;
        const float* W = (p == 0) ? W0 : (p == 1) ? W1 : W2;
        x = W[(long)k * 400 + c];
    }
    bf16 h = (bf16)x;
    float hf = (float)h;
    bf16 l = (bf16)(x - hf);
    hi[idx] = h; lo[idx] = l;
    if (k == 0) {
        float b = 0.f;
        if (n < NCOLS) {
            int p = n / 400, c = n - p * 400;
            const float* Bp = (p == 0) ? B0 : (p == 1) ? B1 : B2;
            b = Bp[c];
        }
        biasCat[n] = b;
    }
}

// ===========================================================================
// mfma_gemm_d: C = elu( A @ Wt^T + biasCat ), split-bf16 3-product.
// DIRECT fragment loads: tables are k-contiguous per row, which IS the MFMA
// fragment layout (lane m=r16, k=quad*8+j -> 16B at row_ptr + k0 + quad*8).
// No LDS staging, no barriers in the K-loop -> fully pipelineable.
// GRID: x = col-block (fastest, shares A rows), y = row-block.
// word_layout=1: C[(line*8+h)*3+p][32][52]; word_layout=0: row-major [row][1200].
// ===========================================================================
__launch_bounds__(256)
__global__ void mfma_gemm_d(const bf16* __restrict__ Ah_t, const bf16* __restrict__ Al_t,
                            const int* __restrict__ docs,
                            const bf16* __restrict__ Bh_t, const bf16* __restrict__ Bl_t,
                            const float* __restrict__ biasCat,
                            float* __restrict__ C, int K2, int word_layout)
{
    __shared__ int tok[128];

    const int tid = threadIdx.x;
    const int row0 = blockIdx.y * 128;     // y = row-block
    const int n0 = blockIdx.x * 128;       // x = col-block (fastest)

    if (tid < 128) tok[tid] = docs ? docs[row0 + tid] : (row0 + tid);
    __syncthreads();

    const int wv = tid >> 6, lane = tid & 63;
    const int quad = lane >> 4, r16 = lane & 15;
    const int wm0 = (wv >> 1) * 64, wn0 = (wv & 1) * 64;

    // per-lane row/col base pointers (k-contiguous rows)
    const bf16* pAh[4]; const bf16* pAl[4];
    const bf16* pBh[4]; const bf16* pBl[4];
    #pragma unroll
    for (int t = 0; t < 4; ++t) {
        const long ao = (long)tok[wm0 + t * 16 + r16] * K2 + quad * 8;
        pAh[t] = Ah_t + ao;
        pAl[t] = Al_t + ao;
        const long bo = (long)(n0 + wn0 + t * 16 + r16) * K2 + quad * 8;
        pBh[t] = Bh_t + bo;
        pBl[t] = Bl_t + bo;
    }

    v4f acc[4][4];
    #pragma unroll
    for (int a = 0; a < 4; ++a)
        #pragma unroll
        for (int b = 0; b < 4; ++b) acc[a][b] = (v4f)0.f;

    const int nk = K2 >> 5;
    for (int kt = 0; kt < nk; ++kt) {
        const int k0 = kt * 32;
        v8bf fa_h[4], fa_l[4], fb_h[4], fb_l[4];
        #pragma unroll
        for (int t = 0; t < 4; ++t) {
            fa_h[t] = *(const v8bf*)(pAh[t] + k0);
            fa_l[t] = *(const v8bf*)(pAl[t] + k0);
            fb_h[t] = *(const v8bf*)(pBh[t] + k0);
            fb_l[t] = *(const v8bf*)(pBl[t] + k0);
        }
        #pragma unroll
        for (int mt = 0; mt < 4; ++mt)
            #pragma unroll
            for (int nt = 0; nt < 4; ++nt) {
                acc[mt][nt] = __builtin_amdgcn_mfma_f32_16x16x32_bf16(fa_h[mt], fb_h[nt], acc[mt][nt], 0, 0, 0);
                acc[mt][nt] = __builtin_amdgcn_mfma_f32_16x16x32_bf16(fa_h[mt], fb_l[nt], acc[mt][nt], 0, 0, 0);
                acc[mt][nt] = __builtin_amdgcn_mfma_f32_16x16x32_bf16(fa_l[mt], fb_h[nt], acc[mt][nt], 0, 0, 0);
            }
    }

    // ---- epilogue: D row = quad*4+reg, col = lane&15
    if (word_layout) {
        #pragma unroll
        for (int nt = 0; nt < 4; ++nt) {
            const int col = n0 + wn0 + nt * 16 + r16;
            if (col >= NCOLS) continue;
            const float bv = biasCat[col];
            const int p = col / 400;
            const int rem = col - p * 400;
            const int hh = rem / 50;
            const int d  = rem - hh * 50;
            #pragma unroll
            for (int mt = 0; mt < 4; ++mt) {
                const int rbase = row0 + wm0 + mt * 16 + quad * 4;
                #pragma unroll
                for (int rg = 0; rg < 4; ++rg) {
                    const int row = rbase + rg;
                    const int ln = row >> 5, r = row & 31;
                    const float x = acc[mt][nt][rg] + bv;
                    C[(((long)ln * NH + hh) * 3 + p) * 1664 + r * 52 + d] =
                        x > 0.f ? x : expm1f(x);
                }
            }
        }
    } else {
        #pragma unroll
        for (int nt = 0; nt < 4; ++nt) {
            const int col = n0 + wn0 + nt * 16 + r16;
            if (col >= NCOLS) continue;
            const float bv = biasCat[col];
            #pragma unroll
            for (int mt = 0; mt < 4; ++mt) {
                const int rbase = row0 + wm0 + mt * 16 + quad * 4;
                #pragma unroll
                for (int rg = 0; rg < 4; ++rg) {
                    const float x = acc[mt][nt][rg] + bv;
                    C[(long)(rbase + rg) * NCOLS + col] = x > 0.f ? x : expm1f(x);
                }
            }
        }
    }
}

// ===========================================================================
// word_attn3: one WAVE per (line, head).  qkvw layout [line][h][3][32][52].
// ===========================================================================
__launch_bounds__(64)
__global__ void word_attn3(const float* __restrict__ qkvw, const int* __restrict__ docs,
                           const float* __restrict__ w_tgt,
                           float* __restrict__ line_e, float* __restrict__ mask_l)
{
    __shared__ __align__(16) float sh[HBLK];   // q[0..1663] k[1664..] v[3328..]
    __shared__ float sc[32 * 33];
    __shared__ float msk[WPL];
    __shared__ float cwl[WPL];
    __shared__ float tg[52];

    const int lane = threadIdx.x;
    const int bid = blockIdx.x;
    const int line = bid >> 3;
    const int h = bid & 7;
    const int j = lane & 31;
    const int khalf = lane >> 5;

    const int tokj = docs[line * WPL + j];
    const float mskj = (tokj != 0) ? 1.f : 0.f;
    if (lane < 32) msk[lane] = mskj;
    const unsigned long long bal = __ballot(tokj != 0);
    const float mls = bal ? 1.f : 0.f;
    if (lane == 0 && h == 0) mask_l[line] = mls;

    // ---- stage this (line, head)'s contiguous 20KB block
    const float* src = qkvw + ((long)line * NH + h) * HBLK;
    for (int i = lane; i < HBLK / 4; i += 64)
        *(float4*)&sh[i * 4] = *(const float4*)&src[i * 4];
    // zero d=50,51 pads (GEMM never writes them)
    for (int idx = lane; idx < 192; idx += 64) {
        const int a = idx / 64, rem = idx - a * 64;
        sh[a * 1664 + (rem >> 1) * 52 + 50 + (rem & 1)] = 0.f;
    }
    if (lane < 52) tg[lane] = (lane < 50) ? w_tgt[h * 50 + lane] : 0.f;
    __syncthreads();

    // ---- q row into regs
    float4 qv[13];
    #pragma unroll
    for (int i = 0; i < 13; ++i) qv[i] = *(const float4*)&sh[j * 52 + i * 4];

    // ---- scores for kk = khalf*16 + c
    float w1[16];
    float rmax = -1e30f;
    #pragma unroll
    for (int c = 0; c < 16; ++c) {
        const int kk = khalf * 16 + c;
        const float* kr = &sh[1664 + kk * 52];
        float s = 0.f;
        #pragma unroll
        for (int i = 0; i < 13; ++i) {
            const float4 kv = *(const float4*)&kr[i * 4];
            s += qv[i].x * kv.x + qv[i].y * kv.y + qv[i].z * kv.z + qv[i].w * kv.w;
        }
        s = s / SCALE - 1e7f * (1.f - msk[kk]);
        w1[c] = s;
        rmax = fmaxf(rmax, s);
    }
    rmax = fmaxf(rmax, __shfl_xor(rmax, 32));
    float rsum = 0.f;
    #pragma unroll
    for (int c = 0; c < 16; ++c) { w1[c] = expf(w1[c] - rmax); rsum += w1[c]; }
    rsum += __shfl_xor(rsum, 32);
    const float rinv = 1.f / rsum;

    // ---- target score for key row j (duplicated across halves)
    float ts;
    {
        const float* kr = &sh[1664 + j * 52];
        float s = 0.f;
        #pragma unroll
        for (int i = 0; i < 13; ++i) {
            const float4 kv = *(const float4*)&kr[i * 4];
            const float4 tv = *(const float4*)&tg[i * 4];
            s += kv.x * tv.x + kv.y * tv.y + kv.z * tv.z + kv.w * tv.w;
        }
        ts = s / SCALE - 1e7f * (1.f - mskj);
    }
    float tm = ts;
    #pragma unroll
    for (int off = 16; off >= 1; off >>= 1) tm = fmaxf(tm, __shfl_xor(tm, off));
    const float te = expf(ts - tm);
    float tsum = te;
    #pragma unroll
    for (int off = 16; off >= 1; off >>= 1) tsum += __shfl_xor(tsum, off);
    const float twj = te / tsum;

    // ---- sc[j][kk] = tw[j]*msk[j]*softmax_row_j[kk]
    const float coef = twj * mskj * rinv;
    #pragma unroll
    for (int c = 0; c < 16; ++c)
        sc[j * 33 + khalf * 16 + c] = coef * w1[c];
    __syncthreads();

    if (lane < 32) {
        float cv = 0.f;
        #pragma unroll
        for (int jj = 0; jj < 32; ++jj) cv += sc[jj * 33 + lane];
        cwl[lane] = cv;
    }
    __syncthreads();

    if (lane < DPH) {
        float acc2 = 0.f;
        #pragma unroll
        for (int kk = 0; kk < 32; ++kk)
            acc2 += cwl[kk] * sh[3328 + kk * 52 + lane];
        line_e[(long)line * AD + h * 50 + lane] = acc2 * mls;
    }
}

// ===========================================================================
// FALLBACK kernels (fp32 path, round-3 proven)
// ===========================================================================
__launch_bounds__(256)
__global__ void word_attn(const float* __restrict__ qkv, const int* __restrict__ docs,
                          const float* __restrict__ w_tgt,
                          float* __restrict__ line_e, float* __restrict__ mask_l)
{
    __shared__ float qs[WPL * QKV_S];
    __shared__ float ks[WPL * QKV_S];
    __shared__ float vs[WPL * QKV_S];
    __shared__ float sc[WPL * SC_S];
    __shared__ float ts[WPL], tw[WPL], cw[WPL], msk[WPL];
    __shared__ float mls;

    const int tid = threadIdx.x;
    const int line = blockIdx.x;

    if (tid < WPL) msk[tid] = (docs[line * WPL + tid] != 0) ? 1.f : 0.f;
    __syncthreads();
    if (tid == 0) {
        float ml = 0.f;
        for (int w = 0; w < WPL; ++w) ml = fmaxf(ml, msk[w]);
        mls = ml;
        mask_l[line] = ml;
    }
    for (int h = 0; h < NH; ++h) {
        for (int idx = tid; idx < WPL * DPH; idx += 256) {
            const int r = idx / DPH, d = idx - r * DPH;
            const size_t base = (size_t)(line * WPL + r) * NCOLS + h * DPH + d;
            qs[r * QKV_S + d] = qkv[base];
            ks[r * QKV_S + d] = qkv[base + 400];
            vs[r * QKV_S + d] = qkv[base + 800];
        }
        __syncthreads();
        {
            const int j = tid >> 3, kg = tid & 7;
            #pragma unroll
            for (int c = 0; c < 4; ++c) {
                const int kk = kg * 4 + c;
                float s = 0.f;
                for (int dd = 0; dd < DPH; ++dd)
                    s += qs[j * QKV_S + dd] * ks[kk * QKV_S + dd];
                sc[j * SC_S + kk] = s / SCALE - 1e7f * (1.f - msk[kk]);
            }
        }
        if (tid < WPL) {
            float s = 0.f;
            for (int dd = 0; dd < DPH; ++dd)
                s += w_tgt[h * DPH + dd] * ks[tid * QKV_S + dd];
            ts[tid] = s / SCALE - 1e7f * (1.f - msk[tid]);
        }
        __syncthreads();
        if (tid < WPL) {
            const int j = tid;
            float m = -1e30f;
            for (int kk = 0; kk < WPL; ++kk) m = fmaxf(m, sc[j * SC_S + kk]);
            float sum = 0.f;
            for (int kk = 0; kk < WPL; ++kk) {
                const float e = expf(sc[j * SC_S + kk] - m);
                sc[j * SC_S + kk] = e;
                sum += e;
            }
            const float inv = 1.f / sum;
            for (int kk = 0; kk < WPL; ++kk) sc[j * SC_S + kk] *= inv;
        } else if (tid == WPL) {
            float m = -1e30f;
            for (int jj = 0; jj < WPL; ++jj) m = fmaxf(m, ts[jj]);
            float sum = 0.f;
            for (int jj = 0; jj < WPL; ++jj) { const float e = expf(ts[jj] - m); tw[jj] = e; sum += e; }
            const float inv = 1.f / sum;
            for (int jj = 0; jj < WPL; ++jj) tw[jj] *= inv;
        }
        __syncthreads();
        if (tid < WPL) {
            const int kk = tid;
            float c = 0.f;
            for (int jj = 0; jj < WPL; ++jj) c += tw[jj] * msk[jj] * sc[jj * SC_S + kk];
            cw[kk] = c;
        }
        __syncthreads();
        if (tid < DPH) {
            float acc = 0.f;
            for (int kk = 0; kk < WPL; ++kk) acc += cw[kk] * vs[kk * QKV_S + tid];
            line_e[line * AD + h * DPH + tid] = acc * mls;
        }
        __syncthreads();
    }
}

__launch_bounds__(256, 2)
__global__ void gemm_qkv(const float* __restrict__ Asrc,
                         const int* __restrict__ docs,
                         const float* __restrict__ emb,
                         const float* __restrict__ W0, const float* __restrict__ W1,
                         const float* __restrict__ W2,
                         const float* __restrict__ B0, const float* __restrict__ B1,
                         const float* __restrict__ B2,
                         float* __restrict__ C, int M, int K)
{
    __shared__ __align__(16) float As[32][132];
    __shared__ __align__(16) float Bs[32][132];

    const int tid = threadIdx.x;
    const int row0 = blockIdx.x * 128;
    const int n0 = blockIdx.y * 128;
    const int tc = tid & 15, tr = tid >> 4;

    float acc[2][2][4][4];
    #pragma unroll
    for (int a = 0; a < 2; ++a)
        #pragma unroll
        for (int b = 0; b < 2; ++b)
            #pragma unroll
            for (int c = 0; c < 4; ++c)
                #pragma unroll
                for (int d = 0; d < 4; ++d) acc[a][b][c][d] = 0.f;

    const int ma = tid & 127;
    const int kq = tid >> 7;
    const float* arow;
    if (docs) arow = emb + (size_t)docs[row0 + ma] * EMBD;
    else      arow = Asrc + (size_t)(row0 + ma) * K;

    const int gcol = n0 + ma;
    const int p = gcol / 400;
    const int ccol = gcol - p * 400;
    const float* Wp = (p == 0) ? W0 : (p == 1) ? W1 : W2;
    const bool colv = gcol < NCOLS;

    const int nk = (K + 31) >> 5;
    for (int ck = 0; ck < nk; ++ck) {
        const int k0 = ck * 32;
        #pragma unroll
        for (int f = 0; f < 4; ++f) {
            const int kl = kq * 16 + f * 4;
            const int kg = k0 + kl;
            float4 v = make_float4(0.f, 0.f, 0.f, 0.f);
            if (kg < K) v = *(const float4*)(arow + kg);
            As[kl + 0][ma] = v.x;
            As[kl + 1][ma] = v.y;
            As[kl + 2][ma] = v.z;
            As[kl + 3][ma] = v.w;
        }
        #pragma unroll
        for (int i = 0; i < 16; ++i) {
            const int kl = kq * 16 + i;
            const int kg = k0 + kl;
            float v = 0.f;
            if (colv && kg < K) v = Wp[(size_t)kg * 400 + ccol];
            Bs[kl][ma] = v;
        }
        __syncthreads();

        #pragma unroll 8
        for (int k = 0; k < 32; ++k) {
            const float4 a0 = *(const float4*)&As[k][tr * 4];
            const float4 a1 = *(const float4*)&As[k][64 + tr * 4];
            const float4 b0 = *(const float4*)&Bs[k][tc * 4];
            const float4 b1 = *(const float4*)&Bs[k][64 + tc * 4];
            const float ar[2][4] = {{a0.x, a0.y, a0.z, a0.w}, {a1.x, a1.y, a1.z, a1.w}};
            const float br[2][4] = {{b0.x, b0.y, b0.z, b0.w}, {b1.x, b1.y, b1.z, b1.w}};
            #pragma unroll
            for (int im = 0; im < 2; ++im)
                #pragma unroll
                for (int in_ = 0; in_ < 2; ++in_)
                    #pragma unroll
                    for (int rr = 0; rr < 4; ++rr)
                        #pragma unroll
                        for (int cc = 0; cc < 4; ++cc)
                            acc[im][in_][rr][cc] += ar[im][rr] * br[in_][cc];
        }
        __syncthreads();
    }

    #pragma unroll
    for (int in_ = 0; in_ < 2; ++in_) {
        const int ncol = n0 + in_ * 64 + tc * 4;
        if (ncol >= NCOLS) continue;
        const int pj = ncol / 400;
        const int cj = ncol - pj * 400;
        const float* Bp = (pj == 0) ? B0 : (pj == 1) ? B1 : B2;
        const float4 bv = *(const float4*)(Bp + cj);
        #pragma unroll
        for (int im = 0; im < 2; ++im) {
            #pragma unroll
            for (int rr = 0; rr < 4; ++rr) {
                const int row = row0 + im * 64 + tr * 4 + rr;
                float4 o;
                o.x = elu(acc[im][in_][rr][0] + bv.x);
                o.y = elu(acc[im][in_][rr][1] + bv.y);
                o.z = elu(acc[im][in_][rr][2] + bv.z);
                o.w = elu(acc[im][in_][rr][3] + bv.w);
                *(float4*)(C + (size_t)row * NCOLS + ncol) = o;
            }
        }
    }
}

// ---------------------------------------------------------------------------
__launch_bounds__(256)
__global__ void line_attn_g(const float* __restrict__ Q, const float* __restrict__ Kp,
                            const float* __restrict__ Vp,
                            long DS, long HS, long LS,
                            const float* __restrict__ l_tgt, const float* __restrict__ mask_l,
                            float* __restrict__ doc_e)
{
    __shared__ float kl[LPD * 53];
    __shared__ float ql[32 * 53];
    __shared__ float sc[32 * 132];
    __shared__ float ts[LPD];
    __shared__ float tw[LPD];
    __shared__ float cw[LPD];
    __shared__ float ml[LPD];

    const int tid = threadIdx.x;
    const int doc = blockIdx.x >> 3;
    const int h = blockIdx.x & 7;
    const float* qbase = Q + doc * DS + h * HS;
    const float* kbase = Kp + doc * DS + h * HS;
    const float* vbase = Vp + doc * DS + h * HS;

    if (tid < LPD) { ml[tid] = mask_l[doc * LPD + tid]; cw[tid] = 0.f; }
    for (int idx = tid; idx < LPD * DPH; idx += 256) {
        int kk = idx / DPH, d = idx - kk * DPH;
        kl[kk * 53 + d] = kbase[kk * LS + d];
    }
    __syncthreads();

    if (tid < LPD) {
        float s = 0.f;
        for (int d = 0; d < DPH; ++d) s += l_tgt[h * DPH + d] * kl[tid * 53 + d];
        ts[tid] = s / SCALE - 1e7f * (1.f - ml[tid]);
    }
    __syncthreads();
    if (tid < LPD) {
        float m = -1e30f;
        for (int jj = 0; jj < LPD; ++jj) m = fmaxf(m, ts[jj]);
        float sum = 0.f;
        for (int jj = 0; jj < LPD; ++jj) sum += expf(ts[jj] - m);
        tw[tid] = expf(ts[tid] - m) / sum;
    }
    __syncthreads();

    for (int qc = 0; qc < 4; ++qc) {
        for (int idx = tid; idx < 32 * DPH; idx += 256) {
            int r = idx / DPH, d = idx - r * DPH;
            ql[r * 53 + d] = qbase[(qc * 32 + r) * LS + d];
        }
        __syncthreads();
        {
            int jj = tid >> 3, kg = tid & 7;
            for (int c = 0; c < 16; ++c) {
                int kk = kg * 16 + c;
                float s = 0.f;
                for (int d = 0; d < DPH; ++d) s += ql[jj * 53 + d] * kl[kk * 53 + d];
                sc[jj * 132 + kk] = s / SCALE - 1e7f * (1.f - ml[kk]);
            }
        }
        __syncthreads();
        if (tid < 32) {
            float m = -1e30f;
            for (int kk = 0; kk < LPD; ++kk) m = fmaxf(m, sc[tid * 132 + kk]);
            float sum = 0.f;
            for (int kk = 0; kk < LPD; ++kk) {
                float e = expf(sc[tid * 132 + kk] - m);
                sc[tid * 132 + kk] = e;
                sum += e;
            }
            float inv = 1.f / sum;
            for (int kk = 0; kk < LPD; ++kk) sc[tid * 132 + kk] *= inv;
        }
        __syncthreads();
        if (tid < LPD) {
            int kk = tid;
            float c = 0.f;
            for (int r = 0; r < 32; ++r) {
                int jj = qc * 32 + r;
                c += tw[jj] * ml[jj] * sc[r * 132 + kk];
            }
            cw[kk] += c;
        }
        __syncthreads();
    }

    if (tid < DPH) {
        float acc = 0.f;
        for (int kk = 0; kk < LPD; ++kk) acc += cw[kk] * vbase[kk * LS + tid];
        doc_e[doc * AD + h * DPH + tid] = acc;
    }
}

__global__ void logits_kernel(const float* __restrict__ doc_e,
                              const float* __restrict__ fc1_w, const float* __restrict__ fc1_b,
                              const float* __restrict__ fc2_w, const float* __restrict__ fc2_b,
                              float* __restrict__ out)
{
    int o = blockIdx.x * blockDim.x + threadIdx.x;
    if (o >= BATCH * 582) return;
    int b = o / 582, jj = o - b * 582;
    const float* de = doc_e + b * AD;
    float acc;
    if (jj < 70) {
        acc = fc1_b[jj];
        for (int k = 0; k < AD; ++k) acc += de[k] * fc1_w[k * 70 + jj];
    } else {
        int j2 = jj - 70;
        acc = fc2_b[j2];
        for (int k = 0; k < AD; ++k) acc += de[k] * fc2_w[k * 512 + j2];
    }
    out[o] = acc;
}

// ---------------------------------------------------------------------------
extern "C" void kernel_launch(void* const* d_in, const int* in_sizes, int n_in,
                              void* d_out, int out_size, void* d_ws, size_t ws_size,
                              hipStream_t stream) {
    const int*   docs  = (const int*)  d_in[0];
    const float* emb   = (const float*)d_in[1];
    const float* wq_w  = (const float*)d_in[2];
    const float* wq_b  = (const float*)d_in[3];
    const float* wk_w  = (const float*)d_in[4];
    const float* wk_b  = (const float*)d_in[5];
    const float* wv_w  = (const float*)d_in[6];
    const float* wv_b  = (const float*)d_in[7];
    const float* w_tgt = (const float*)d_in[8];
    const float* lq_w  = (const float*)d_in[9];
    const float* lq_b  = (const float*)d_in[10];
    const float* lk_w  = (const float*)d_in[11];
    const float* lk_b  = (const float*)d_in[12];
    const float* lv_w  = (const float*)d_in[13];
    const float* lv_b  = (const float*)d_in[14];
    const float* l_tgt = (const float*)d_in[15];
    const float* fc1_w = (const float*)d_in[16];
    const float* fc1_b = (const float*)d_in[17];
    const float* fc2_w = (const float*)d_in[18];
    const float* fc2_b = (const float*)d_in[19];
    float* out = (float*)d_out;
    float* ws = (float*)d_ws;

    const long O_LINE_E = 0;
    const long O_MASK_L = 819200;
    const long O_DOC_E  = 821248;
    const long O_BIAS_W = 827648;
    const long O_BIAS_L = 828928;
    const long O_EMB_H  = 830208;
    const long O_EMB_L  = 5630208;
    const long O_WTW_H  = 10430208;
    const long O_WTW_L  = 10635008;
    const long O_WTL_H  = 10839808;
    const long O_WTL_L  = 11106048;
    const long O_LE_H   = 11372288;
    const long O_LE_L   = 11798272;
    const long O_R      = 12224256;

    const long LINE_QKV_FL = (long)NLINES * NCOLS;    // 2457600
    long ws_fl = (long)(ws_size / 4);
    long Rcap = ws_fl - O_R;

    if (Rcap >= LINE_QKV_FL) {
        // ================= MFMA fast path =================
        float* line_e = ws + O_LINE_E;
        float* mask_l = ws + O_MASK_L;
        float* doc_e  = ws + O_DOC_E;
        float* bias_w = ws + O_BIAS_W;
        float* bias_l = ws + O_BIAS_L;
        bf16* embh = (bf16*)(ws + O_EMB_H);
        bf16* embl = (bf16*)(ws + O_EMB_L);
        bf16* wtwh = (bf16*)(ws + O_WTW_H);
        bf16* wtwl = (bf16*)(ws + O_WTW_L);
        bf16* wtlh = (bf16*)(ws + O_WTL_H);
        bf16* wtll = (bf16*)(ws + O_WTL_L);
        bf16* leh  = (bf16*)(ws + O_LE_H);
        bf16* lel  = (bf16*)(ws + O_LE_L);
        float* R   = ws + O_R;

        split_rows<<<(30000L * 320 + 255) / 256, 256, 0, stream>>>(emb, embh, embl, 30000, 300, 320);
        split_wt<<<((long)NPAD * 320 + 255) / 256, 256, 0, stream>>>(wq_w, wk_w, wv_w,
                                                                     wq_b, wk_b, wv_b,
                                                                     wtwh, wtwl, bias_w, 300, 320);
        split_wt<<<((long)NPAD * 416 + 255) / 256, 256, 0, stream>>>(lq_w, lk_w, lv_w,
                                                                     lq_b, lk_b, lv_b,
                                                                     wtlh, wtll, bias_l, 400, 416);

        long maxl = Rcap / WLINE_FL;
        if (maxl > 1024) maxl = 1024;      // keep qkv chunk L3-resident
        long chunk = (maxl / 4) * 4;
        if (chunk < 4) chunk = 4;
        for (long c0 = 0; c0 < NLINES; c0 += chunk) {
            long cl = NLINES - c0 < chunk ? NLINES - c0 : chunk;   // multiple of 4
            dim3 g1(10, (unsigned)((cl * 32) / 128));   // x=col (fastest), y=row
            mfma_gemm_d<<<g1, 256, 0, stream>>>(embh, embl, docs + c0 * WPL,
                                                wtwh, wtwl, bias_w, R, 320, 1);
            word_attn3<<<(unsigned)(cl * NH), 64, 0, stream>>>(R, docs + c0 * WPL, w_tgt,
                                                               line_e + c0 * AD, mask_l + c0);
        }

        split_rows<<<((long)NLINES * 416 + 255) / 256, 256, 0, stream>>>(line_e, leh, lel,
                                                                         NLINES, 400, 416);
        dim3 g2(10, NLINES / 128);
        mfma_gemm_d<<<g2, 256, 0, stream>>>(leh, lel, nullptr, wtlh, wtll, bias_l, R, 416, 0);
        line_attn_g<<<BATCH * NH, 256, 0, stream>>>(R, R + 400, R + 800,
                                                    (long)LPD * NCOLS, (long)DPH, (long)NCOLS,
                                                    l_tgt, mask_l, doc_e);
        logits_kernel<<<(BATCH * 582 + 255) / 256, 256, 0, stream>>>(doc_e, fc1_w, fc1_b,
                                                                     fc2_w, fc2_b, out);
    } else {
        // ================= fp32 fallback =================
        const long F_FIXED = 827648;
        const long PER_LINE_FL = (long)WPL * NCOLS;
        float* line_e = ws;
        float* mask_l = ws + 819200;
        float* doc_e  = ws + 821248;
        float* R      = ws + F_FIXED;
        long Rcap2 = ws_fl - F_FIXED;

        long maxl = Rcap2 / PER_LINE_FL;
        if (maxl > NLINES) maxl = NLINES;
        long maxl4 = (maxl / 4) * 4;
        int nc = (int)((NLINES + maxl4 - 1) / maxl4);
        int chunk = (int)((NLINES + nc - 1) / nc);
        chunk = ((chunk + 3) / 4) * 4;

        for (int c0 = 0; c0 < NLINES; c0 += chunk) {
            int cl = NLINES - c0 < chunk ? NLINES - c0 : chunk;
            dim3 g1((cl * 32) / 128, 10);
            gemm_qkv<<<g1, 256, 0, stream>>>(nullptr, docs + (size_t)c0 * WPL, emb,
                                             wq_w, wk_w, wv_w, wq_b, wk_b, wv_b,
                                             R, cl * 32, EMBD);
            word_attn<<<cl, 256, 0, stream>>>(R, docs + (size_t)c0 * WPL, w_tgt,
                                              line_e + (size_t)c0 * AD, mask_l + c0);
        }
        dim3 g2(16, 10);
        gemm_qkv<<<g2, 256, 0, stream>>>(line_e, nullptr, emb,
                                         lq_w, lk_w, lv_w, lq_b, lk_b, lv_b,
                                         R, NLINES, AD);
        line_attn_g<<<BATCH * NH, 256, 0, stream>>>(R, R + 400, R + 800,
                                                    (long)LPD * NCOLS, (long)DPH, (long)NCOLS,
                                                    l_tgt, mask_l, doc_e);
        logits_kernel<<<(BATCH * 582 + 255) / 256, 256, 0, stream>>>(doc_e, fc1_w, fc1_b,
                                                                     fc2_w, fc2_b, out);
    }
}

// Round 9
// 856.483 us; speedup vs baseline: 1.1321x; 1.1321x over previous
//
#include <hip/hip_runtime.h>
#include <math.h>

#define NLINES 2048
#define WPL 32
#define EMBD 300
#define AD 400
#define NH 8
#define DPH 50
#define QKV_S 52
#define SC_S 36
#define BATCH 16
#define LPD 128
#define NCOLS 1200     // 3 proj * 400
#define NPAD 1280      // padded col count for Wt tables
#define WLINE_FL 39936 // per-line floats in word layout: 8*3*32*52
#define HBLK 4992      // per-(line,head) floats: 3*32*52

typedef __bf16 bf16;
typedef bf16  v8bf __attribute__((ext_vector_type(8)));
typedef float v4f  __attribute__((ext_vector_type(4)));

__device__ __forceinline__ float elu(float x) {
    return x > 0.f ? x : expm1f(x);
}

#define SCALE 7.0710678118654755f   // sqrt(50)

// ===========================================================================
// Split helpers: fp32 -> (hi, lo) bf16 pair.  x ~= hi + lo, rel err ~2^-18.
// ===========================================================================
__global__ void split_rows(const float* __restrict__ src,
                           bf16* __restrict__ hi, bf16* __restrict__ lo,
                           int rows, int K, int K2)
{
    long idx = (long)blockIdx.x * 256 + threadIdx.x;
    if (idx >= (long)rows * K2) return;
    int r = (int)(idx / K2), k = (int)(idx - (long)r * K2);
    float x = (k < K) ? src[(long)r * K + k] : 0.f;
    bf16 h = (bf16)x;
    float hf = (float)h;
    bf16 l = (bf16)(x - hf);
    hi[idx] = h; lo[idx] = l;
}

__global__ void split_wt(const float* __restrict__ W0, const float* __restrict__ W1,
                         const float* __restrict__ W2,
                         const float* __restrict__ B0, const float* __restrict__ B1,
                         const float* __restrict__ B2,
                         bf16* __restrict__ hi, bf16* __restrict__ lo,
                         float* __restrict__ biasCat, int K, int K2)
{
    long idx = (long)blockIdx.x * 256 + threadIdx.x;
    if (idx >= (long)NPAD * K2) return;
    int n = (int)(idx / K2), k = (int)(idx - (long)n * K2);
    float x = 0.f;
    if (k < K && n < NCOLS) {
        int p = n / 400, c = n - p * 400;
        const float* W = (p == 0) ? W0 : (p == 1) ? W1 : W2;
        x = W[(long)k * 400 + c];
    }
    bf16 h = (bf16)x;
    float hf = (float)h;
    bf16 l = (bf16)(x - hf);
    hi[idx] = h; lo[idx] = l;
    if (k == 0) {
        float b = 0.f;
        if (n < NCOLS) {
            int p = n / 400, c = n - p * 400;
            const float* Bp = (p == 0) ? B0 : (p == 1) ? B1 : B2;
            b = Bp[c];
        }
        biasCat[n] = b;
    }
}

// ===========================================================================
// mfma_gemm: C = elu( A @ Wt^T + biasCat ), split-bf16 3-product, staged LDS
// (round-4/5 proven structure, best measured K-loop: ~190 us at 1024-line
// chunks).  GRID: x = col-block (fastest, shares A rows), y = row-block.
// word_layout=1: C[(line*8+h)*3+p][32][52]; word_layout=0: row-major [row][1200].
// ===========================================================================
__launch_bounds__(256)
__global__ void mfma_gemm(const bf16* __restrict__ Ah_t, const bf16* __restrict__ Al_t,
                          const int* __restrict__ docs,
                          const bf16* __restrict__ Bh_t, const bf16* __restrict__ Bl_t,
                          const float* __restrict__ biasCat,
                          float* __restrict__ C, int K2, int word_layout)
{
    __shared__ __align__(16) bf16 Ah[4096];
    __shared__ __align__(16) bf16 Al[4096];
    __shared__ __align__(16) bf16 Bh[4096];
    __shared__ __align__(16) bf16 Bl[4096];
    __shared__ int tok[128];

    const int tid = threadIdx.x;
    const int row0 = blockIdx.y * 128;     // y = row-block
    const int n0 = blockIdx.x * 128;       // x = col-block (fastest)

    if (tid < 128) tok[tid] = docs ? docs[row0 + tid] : (row0 + tid);
    __syncthreads();

    const int qa = tid >> 7;
    const int sm = tid & 127;
    const long aoff = (long)tok[sm] * K2;
    const long boff = (long)(n0 + sm) * K2;

    const int wv = tid >> 6, lane = tid & 63;
    const int quad = lane >> 4, r16 = lane & 15;
    const int wm0 = (wv >> 1) * 64, wn0 = (wv & 1) * 64;

    v4f acc[4][4];
    #pragma unroll
    for (int a = 0; a < 4; ++a)
        #pragma unroll
        for (int b = 0; b < 4; ++b) acc[a][b] = (v4f)0.f;

    const int nk = K2 >> 5;
    // prefetch tile 0
    v8bf pa0 = *(const v8bf*)(Ah_t + aoff + qa * 8);
    v8bf pa1 = *(const v8bf*)(Ah_t + aoff + (qa + 2) * 8);
    v8bf pl0 = *(const v8bf*)(Al_t + aoff + qa * 8);
    v8bf pl1 = *(const v8bf*)(Al_t + aoff + (qa + 2) * 8);
    v8bf pb0 = *(const v8bf*)(Bh_t + boff + qa * 8);
    v8bf pb1 = *(const v8bf*)(Bh_t + boff + (qa + 2) * 8);
    v8bf pc0 = *(const v8bf*)(Bl_t + boff + qa * 8);
    v8bf pc1 = *(const v8bf*)(Bl_t + boff + (qa + 2) * 8);

    for (int kt = 0; kt < nk; ++kt) {
        *(v8bf*)&Ah[tid * 8]         = pa0;
        *(v8bf*)&Ah[(256 + tid) * 8] = pa1;
        *(v8bf*)&Al[tid * 8]         = pl0;
        *(v8bf*)&Al[(256 + tid) * 8] = pl1;
        *(v8bf*)&Bh[tid * 8]         = pb0;
        *(v8bf*)&Bh[(256 + tid) * 8] = pb1;
        *(v8bf*)&Bl[tid * 8]         = pc0;
        *(v8bf*)&Bl[(256 + tid) * 8] = pc1;
        __syncthreads();

        if (kt + 1 < nk) {   // next tile's loads fly during MFMA
            const int k1 = (kt + 1) * 32;
            pa0 = *(const v8bf*)(Ah_t + aoff + k1 + qa * 8);
            pa1 = *(const v8bf*)(Ah_t + aoff + k1 + (qa + 2) * 8);
            pl0 = *(const v8bf*)(Al_t + aoff + k1 + qa * 8);
            pl1 = *(const v8bf*)(Al_t + aoff + k1 + (qa + 2) * 8);
            pb0 = *(const v8bf*)(Bh_t + boff + k1 + qa * 8);
            pb1 = *(const v8bf*)(Bh_t + boff + k1 + (qa + 2) * 8);
            pc0 = *(const v8bf*)(Bl_t + boff + k1 + qa * 8);
            pc1 = *(const v8bf*)(Bl_t + boff + k1 + (qa + 2) * 8);
        }

        v8bf fa_h[4], fa_l[4], fb_h[4], fb_l[4];
        #pragma unroll
        for (int t = 0; t < 4; ++t) {
            const int ea = quad * 128 + wm0 + t * 16 + r16;
            fa_h[t] = *(const v8bf*)&Ah[ea * 8];
            fa_l[t] = *(const v8bf*)&Al[ea * 8];
            const int eb = quad * 128 + wn0 + t * 16 + r16;
            fb_h[t] = *(const v8bf*)&Bh[eb * 8];
            fb_l[t] = *(const v8bf*)&Bl[eb * 8];
        }

        #pragma unroll
        for (int mt = 0; mt < 4; ++mt)
            #pragma unroll
            for (int nt = 0; nt < 4; ++nt) {
                acc[mt][nt] = __builtin_amdgcn_mfma_f32_16x16x32_bf16(fa_h[mt], fb_h[nt], acc[mt][nt], 0, 0, 0);
                acc[mt][nt] = __builtin_amdgcn_mfma_f32_16x16x32_bf16(fa_h[mt], fb_l[nt], acc[mt][nt], 0, 0, 0);
                acc[mt][nt] = __builtin_amdgcn_mfma_f32_16x16x32_bf16(fa_l[mt], fb_h[nt], acc[mt][nt], 0, 0, 0);
            }
        __syncthreads();
    }

    // ---- epilogue: D row = quad*4+reg, col = lane&15
    if (word_layout) {
        #pragma unroll
        for (int nt = 0; nt < 4; ++nt) {
            const int col = n0 + wn0 + nt * 16 + r16;
            if (col >= NCOLS) continue;
            const float bv = biasCat[col];
            const int p = col / 400;
            const int rem = col - p * 400;
            const int hh = rem / 50;
            const int d  = rem - hh * 50;
            #pragma unroll
            for (int mt = 0; mt < 4; ++mt) {
                const int rbase = row0 + wm0 + mt * 16 + quad * 4;
                #pragma unroll
                for (int rg = 0; rg < 4; ++rg) {
                    const int row = rbase + rg;
                    const int ln = row >> 5, r = row & 31;
                    const float x = acc[mt][nt][rg] + bv;
                    C[(((long)ln * NH + hh) * 3 + p) * 1664 + r * 52 + d] =
                        x > 0.f ? x : expm1f(x);
                }
            }
        }
    } else {
        #pragma unroll
        for (int nt = 0; nt < 4; ++nt) {
            const int col = n0 + wn0 + nt * 16 + r16;
            if (col >= NCOLS) continue;
            const float bv = biasCat[col];
            #pragma unroll
            for (int mt = 0; mt < 4; ++mt) {
                const int rbase = row0 + wm0 + mt * 16 + quad * 4;
                #pragma unroll
                for (int rg = 0; rg < 4; ++rg) {
                    const float x = acc[mt][nt][rg] + bv;
                    C[(long)(rbase + rg) * NCOLS + col] = x > 0.f ? x : expm1f(x);
                }
            }
        }
    }
}

// ===========================================================================
// word_attn3: one WAVE per (line, head).  qkvw layout [line][h][3][32][52].
// ===========================================================================
__launch_bounds__(64)
__global__ void word_attn3(const float* __restrict__ qkvw, const int* __restrict__ docs,
                           const float* __restrict__ w_tgt,
                           float* __restrict__ line_e, float* __restrict__ mask_l)
{
    __shared__ __align__(16) float sh[HBLK];   // q[0..1663] k[1664..] v[3328..]
    __shared__ float sc[32 * 33];
    __shared__ float msk[WPL];
    __shared__ float cwl[WPL];
    __shared__ float tg[52];

    const int lane = threadIdx.x;
    const int bid = blockIdx.x;
    const int line = bid >> 3;
    const int h = bid & 7;
    const int j = lane & 31;
    const int khalf = lane >> 5;

    const int tokj = docs[line * WPL + j];
    const float mskj = (tokj != 0) ? 1.f : 0.f;
    if (lane < 32) msk[lane] = mskj;
    const unsigned long long bal = __ballot(tokj != 0);
    const float mls = bal ? 1.f : 0.f;
    if (lane == 0 && h == 0) mask_l[line] = mls;

    // ---- stage this (line, head)'s contiguous 20KB block
    const float* src = qkvw + ((long)line * NH + h) * HBLK;
    for (int i = lane; i < HBLK / 4; i += 64)
        *(float4*)&sh[i * 4] = *(const float4*)&src[i * 4];
    // zero d=50,51 pads (GEMM never writes them)
    for (int idx = lane; idx < 192; idx += 64) {
        const int a = idx / 64, rem = idx - a * 64;
        sh[a * 1664 + (rem >> 1) * 52 + 50 + (rem & 1)] = 0.f;
    }
    if (lane < 52) tg[lane] = (lane < 50) ? w_tgt[h * 50 + lane] : 0.f;
    __syncthreads();

    // ---- q row into regs
    float4 qv[13];
    #pragma unroll
    for (int i = 0; i < 13; ++i) qv[i] = *(const float4*)&sh[j * 52 + i * 4];

    // ---- scores for kk = khalf*16 + c
    float w1[16];
    float rmax = -1e30f;
    #pragma unroll
    for (int c = 0; c < 16; ++c) {
        const int kk = khalf * 16 + c;
        const float* kr = &sh[1664 + kk * 52];
        float s = 0.f;
        #pragma unroll
        for (int i = 0; i < 13; ++i) {
            const float4 kv = *(const float4*)&kr[i * 4];
            s += qv[i].x * kv.x + qv[i].y * kv.y + qv[i].z * kv.z + qv[i].w * kv.w;
        }
        s = s / SCALE - 1e7f * (1.f - msk[kk]);
        w1[c] = s;
        rmax = fmaxf(rmax, s);
    }
    rmax = fmaxf(rmax, __shfl_xor(rmax, 32));
    float rsum = 0.f;
    #pragma unroll
    for (int c = 0; c < 16; ++c) { w1[c] = expf(w1[c] - rmax); rsum += w1[c]; }
    rsum += __shfl_xor(rsum, 32);
    const float rinv = 1.f / rsum;

    // ---- target score for key row j (duplicated across halves)
    float ts;
    {
        const float* kr = &sh[1664 + j * 52];
        float s = 0.f;
        #pragma unroll
        for (int i = 0; i < 13; ++i) {
            const float4 kv = *(const float4*)&kr[i * 4];
            const float4 tv = *(const float4*)&tg[i * 4];
            s += kv.x * tv.x + kv.y * tv.y + kv.z * tv.z + kv.w * tv.w;
        }
        ts = s / SCALE - 1e7f * (1.f - mskj);
    }
    float tm = ts;
    #pragma unroll
    for (int off = 16; off >= 1; off >>= 1) tm = fmaxf(tm, __shfl_xor(tm, off));
    const float te = expf(ts - tm);
    float tsum = te;
    #pragma unroll
    for (int off = 16; off >= 1; off >>= 1) tsum += __shfl_xor(tsum, off);
    const float twj = te / tsum;

    // ---- sc[j][kk] = tw[j]*msk[j]*softmax_row_j[kk]
    const float coef = twj * mskj * rinv;
    #pragma unroll
    for (int c = 0; c < 16; ++c)
        sc[j * 33 + khalf * 16 + c] = coef * w1[c];
    __syncthreads();

    if (lane < 32) {
        float cv = 0.f;
        #pragma unroll
        for (int jj = 0; jj < 32; ++jj) cv += sc[jj * 33 + lane];
        cwl[lane] = cv;
    }
    __syncthreads();

    if (lane < DPH) {
        float acc2 = 0.f;
        #pragma unroll
        for (int kk = 0; kk < 32; ++kk)
            acc2 += cwl[kk] * sh[3328 + kk * 52 + lane];
        line_e[(long)line * AD + h * 50 + lane] = acc2 * mls;
    }
}

// ===========================================================================
// FALLBACK kernels (fp32 path, round-3 proven)
// ===========================================================================
__launch_bounds__(256)
__global__ void word_attn(const float* __restrict__ qkv, const int* __restrict__ docs,
                          const float* __restrict__ w_tgt,
                          float* __restrict__ line_e, float* __restrict__ mask_l)
{
    __shared__ float qs[WPL * QKV_S];
    __shared__ float ks[WPL * QKV_S];
    __shared__ float vs[WPL * QKV_S];
    __shared__ float sc[WPL * SC_S];
    __shared__ float ts[WPL], tw[WPL], cw[WPL], msk[WPL];
    __shared__ float mls;

    const int tid = threadIdx.x;
    const int line = blockIdx.x;

    if (tid < WPL) msk[tid] = (docs[line * WPL + tid] != 0) ? 1.f : 0.f;
    __syncthreads();
    if (tid == 0) {
        float ml = 0.f;
        for (int w = 0; w < WPL; ++w) ml = fmaxf(ml, msk[w]);
        mls = ml;
        mask_l[line] = ml;
    }
    for (int h = 0; h < NH; ++h) {
        for (int idx = tid; idx < WPL * DPH; idx += 256) {
            const int r = idx / DPH, d = idx - r * DPH;
            const size_t base = (size_t)(line * WPL + r) * NCOLS + h * DPH + d;
            qs[r * QKV_S + d] = qkv[base];
            ks[r * QKV_S + d] = qkv[base + 400];
            vs[r * QKV_S + d] = qkv[base + 800];
        }
        __syncthreads();
        {
            const int j = tid >> 3, kg = tid & 7;
            #pragma unroll
            for (int c = 0; c < 4; ++c) {
                const int kk = kg * 4 + c;
                float s = 0.f;
                for (int dd = 0; dd < DPH; ++dd)
                    s += qs[j * QKV_S + dd] * ks[kk * QKV_S + dd];
                sc[j * SC_S + kk] = s / SCALE - 1e7f * (1.f - msk[kk]);
            }
        }
        if (tid < WPL) {
            float s = 0.f;
            for (int dd = 0; dd < DPH; ++dd)
                s += w_tgt[h * DPH + dd] * ks[tid * QKV_S + dd];
            ts[tid] = s / SCALE - 1e7f * (1.f - msk[tid]);
        }
        __syncthreads();
        if (tid < WPL) {
            const int j = tid;
            float m = -1e30f;
            for (int kk = 0; kk < WPL; ++kk) m = fmaxf(m, sc[j * SC_S + kk]);
            float sum = 0.f;
            for (int kk = 0; kk < WPL; ++kk) {
                const float e = expf(sc[j * SC_S + kk] - m);
                sc[j * SC_S + kk] = e;
                sum += e;
            }
            const float inv = 1.f / sum;
            for (int kk = 0; kk < WPL; ++kk) sc[j * SC_S + kk] *= inv;
        } else if (tid == WPL) {
            float m = -1e30f;
            for (int jj = 0; jj < WPL; ++jj) m = fmaxf(m, ts[jj]);
            float sum = 0.f;
            for (int jj = 0; jj < WPL; ++jj) { const float e = expf(ts[jj] - m); tw[jj] = e; sum += e; }
            const float inv = 1.f / sum;
            for (int jj = 0; jj < WPL; ++jj) tw[jj] *= inv;
        }
        __syncthreads();
        if (tid < WPL) {
            const int kk = tid;
            float c = 0.f;
            for (int jj = 0; jj < WPL; ++jj) c += tw[jj] * msk[jj] * sc[jj * SC_S + kk];
            cw[kk] = c;
        }
        __syncthreads();
        if (tid < DPH) {
            float acc = 0.f;
            for (int kk = 0; kk < WPL; ++kk) acc += cw[kk] * vs[kk * QKV_S + tid];
            line_e[line * AD + h * DPH + tid] = acc * mls;
        }
        __syncthreads();
    }
}

__launch_bounds__(256, 2)
__global__ void gemm_qkv(const float* __restrict__ Asrc,
                         const int* __restrict__ docs,
                         const float* __restrict__ emb,
                         const float* __restrict__ W0, const float* __restrict__ W1,
                         const float* __restrict__ W2,
                         const float* __restrict__ B0, const float* __restrict__ B1,
                         const float* __restrict__ B2,
                         float* __restrict__ C, int M, int K)
{
    __shared__ __align__(16) float As[32][132];
    __shared__ __align__(16) float Bs[32][132];

    const int tid = threadIdx.x;
    const int row0 = blockIdx.x * 128;
    const int n0 = blockIdx.y * 128;
    const int tc = tid & 15, tr = tid >> 4;

    float acc[2][2][4][4];
    #pragma unroll
    for (int a = 0; a < 2; ++a)
        #pragma unroll
        for (int b = 0; b < 2; ++b)
            #pragma unroll
            for (int c = 0; c < 4; ++c)
                #pragma unroll
                for (int d = 0; d < 4; ++d) acc[a][b][c][d] = 0.f;

    const int ma = tid & 127;
    const int kq = tid >> 7;
    const float* arow;
    if (docs) arow = emb + (size_t)docs[row0 + ma] * EMBD;
    else      arow = Asrc + (size_t)(row0 + ma) * K;

    const int gcol = n0 + ma;
    const int p = gcol / 400;
    const int ccol = gcol - p * 400;
    const float* Wp = (p == 0) ? W0 : (p == 1) ? W1 : W2;
    const bool colv = gcol < NCOLS;

    const int nk = (K + 31) >> 5;
    for (int ck = 0; ck < nk; ++ck) {
        const int k0 = ck * 32;
        #pragma unroll
        for (int f = 0; f < 4; ++f) {
            const int kl = kq * 16 + f * 4;
            const int kg = k0 + kl;
            float4 v = make_float4(0.f, 0.f, 0.f, 0.f);
            if (kg < K) v = *(const float4*)(arow + kg);
            As[kl + 0][ma] = v.x;
            As[kl + 1][ma] = v.y;
            As[kl + 2][ma] = v.z;
            As[kl + 3][ma] = v.w;
        }
        #pragma unroll
        for (int i = 0; i < 16; ++i) {
            const int kl = kq * 16 + i;
            const int kg = k0 + kl;
            float v = 0.f;
            if (colv && kg < K) v = Wp[(size_t)kg * 400 + ccol];
            Bs[kl][ma] = v;
        }
        __syncthreads();

        #pragma unroll 8
        for (int k = 0; k < 32; ++k) {
            const float4 a0 = *(const float4*)&As[k][tr * 4];
            const float4 a1 = *(const float4*)&As[k][64 + tr * 4];
            const float4 b0 = *(const float4*)&Bs[k][tc * 4];
            const float4 b1 = *(const float4*)&Bs[k][64 + tc * 4];
            const float ar[2][4] = {{a0.x, a0.y, a0.z, a0.w}, {a1.x, a1.y, a1.z, a1.w}};
            const float br[2][4] = {{b0.x, b0.y, b0.z, b0.w}, {b1.x, b1.y, b1.z, b1.w}};
            #pragma unroll
            for (int im = 0; im < 2; ++im)
                #pragma unroll
                for (int in_ = 0; in_ < 2; ++in_)
                    #pragma unroll
                    for (int rr = 0; rr < 4; ++rr)
                        #pragma unroll
                        for (int cc = 0; cc < 4; ++cc)
                            acc[im][in_][rr][cc] += ar[im][rr] * br[in_][cc];
        }
        __syncthreads();
    }

    #pragma unroll
    for (int in_ = 0; in_ < 2; ++in_) {
        const int ncol = n0 + in_ * 64 + tc * 4;
        if (ncol >= NCOLS) continue;
        const int pj = ncol / 400;
        const int cj = ncol - pj * 400;
        const float* Bp = (pj == 0) ? B0 : (pj == 1) ? B1 : B2;
        const float4 bv = *(const float4*)(Bp + cj);
        #pragma unroll
        for (int im = 0; im < 2; ++im) {
            #pragma unroll
            for (int rr = 0; rr < 4; ++rr) {
                const int row = row0 + im * 64 + tr * 4 + rr;
                float4 o;
                o.x = elu(acc[im][in_][rr][0] + bv.x);
                o.y = elu(acc[im][in_][rr][1] + bv.y);
                o.z = elu(acc[im][in_][rr][2] + bv.z);
                o.w = elu(acc[im][in_][rr][3] + bv.w);
                *(float4*)(C + (size_t)row * NCOLS + ncol) = o;
            }
        }
    }
}

// ---------------------------------------------------------------------------
__launch_bounds__(256)
__global__ void line_attn_g(const float* __restrict__ Q, const float* __restrict__ Kp,
                            const float* __restrict__ Vp,
                            long DS, long HS, long LS,
                            const float* __restrict__ l_tgt, const float* __restrict__ mask_l,
                            float* __restrict__ doc_e)
{
    __shared__ float kl[LPD * 53];
    __shared__ float ql[32 * 53];
    __shared__ float sc[32 * 132];
    __shared__ float ts[LPD];
    __shared__ float tw[LPD];
    __shared__ float cw[LPD];
    __shared__ float ml[LPD];

    const int tid = threadIdx.x;
    const int doc = blockIdx.x >> 3;
    const int h = blockIdx.x & 7;
    const float* qbase = Q + doc * DS + h * HS;
    const float* kbase = Kp + doc * DS + h * HS;
    const float* vbase = Vp + doc * DS + h * HS;

    if (tid < LPD) { ml[tid] = mask_l[doc * LPD + tid]; cw[tid] = 0.f; }
    for (int idx = tid; idx < LPD * DPH; idx += 256) {
        int kk = idx / DPH, d = idx - kk * DPH;
        kl[kk * 53 + d] = kbase[kk * LS + d];
    }
    __syncthreads();

    if (tid < LPD) {
        float s = 0.f;
        for (int d = 0; d < DPH; ++d) s += l_tgt[h * DPH + d] * kl[tid * 53 + d];
        ts[tid] = s / SCALE - 1e7f * (1.f - ml[tid]);
    }
    __syncthreads();
    if (tid < LPD) {
        float m = -1e30f;
        for (int jj = 0; jj < LPD; ++jj) m = fmaxf(m, ts[jj]);
        float sum = 0.f;
        for (int jj = 0; jj < LPD; ++jj) sum += expf(ts[jj] - m);
        tw[tid] = expf(ts[tid] - m) / sum;
    }
    __syncthreads();

    for (int qc = 0; qc < 4; ++qc) {
        for (int idx = tid; idx < 32 * DPH; idx += 256) {
            int r = idx / DPH, d = idx - r * DPH;
            ql[r * 53 + d] = qbase[(qc * 32 + r) * LS + d];
        }
        __syncthreads();
        {
            int jj = tid >> 3, kg = tid & 7;
            for (int c = 0; c < 16; ++c) {
                int kk = kg * 16 + c;
                float s = 0.f;
                for (int d = 0; d < DPH; ++d) s += ql[jj * 53 + d] * kl[kk * 53 + d];
                sc[jj * 132 + kk] = s / SCALE - 1e7f * (1.f - ml[kk]);
            }
        }
        __syncthreads();
        if (tid < 32) {
            float m = -1e30f;
            for (int kk = 0; kk < LPD; ++kk) m = fmaxf(m, sc[tid * 132 + kk]);
            float sum = 0.f;
            for (int kk = 0; kk < LPD; ++kk) {
                float e = expf(sc[tid * 132 + kk] - m);
                sc[tid * 132 + kk] = e;
                sum += e;
            }
            float inv = 1.f / sum;
            for (int kk = 0; kk < LPD; ++kk) sc[tid * 132 + kk] *= inv;
        }
        __syncthreads();
        if (tid < LPD) {
            int kk = tid;
            float c = 0.f;
            for (int r = 0; r < 32; ++r) {
                int jj = qc * 32 + r;
                c += tw[jj] * ml[jj] * sc[r * 132 + kk];
            }
            cw[kk] += c;
        }
        __syncthreads();
    }

    if (tid < DPH) {
        float acc = 0.f;
        for (int kk = 0; kk < LPD; ++kk) acc += cw[kk] * vbase[kk * LS + tid];
        doc_e[doc * AD + h * DPH + tid] = acc;
    }
}

__global__ void logits_kernel(const float* __restrict__ doc_e,
                              const float* __restrict__ fc1_w, const float* __restrict__ fc1_b,
                              const float* __restrict__ fc2_w, const float* __restrict__ fc2_b,
                              float* __restrict__ out)
{
    int o = blockIdx.x * blockDim.x + threadIdx.x;
    if (o >= BATCH * 582) return;
    int b = o / 582, jj = o - b * 582;
    const float* de = doc_e + b * AD;
    float acc;
    if (jj < 70) {
        acc = fc1_b[jj];
        for (int k = 0; k < AD; ++k) acc += de[k] * fc1_w[k * 70 + jj];
    } else {
        int j2 = jj - 70;
        acc = fc2_b[j2];
        for (int k = 0; k < AD; ++k) acc += de[k] * fc2_w[k * 512 + j2];
    }
    out[o] = acc;
}

// ---------------------------------------------------------------------------
extern "C" void kernel_launch(void* const* d_in, const int* in_sizes, int n_in,
                              void* d_out, int out_size, void* d_ws, size_t ws_size,
                              hipStream_t stream) {
    const int*   docs  = (const int*)  d_in[0];
    const float* emb   = (const float*)d_in[1];
    const float* wq_w  = (const float*)d_in[2];
    const float* wq_b  = (const float*)d_in[3];
    const float* wk_w  = (const float*)d_in[4];
    const float* wk_b  = (const float*)d_in[5];
    const float* wv_w  = (const float*)d_in[6];
    const float* wv_b  = (const float*)d_in[7];
    const float* w_tgt = (const float*)d_in[8];
    const float* lq_w  = (const float*)d_in[9];
    const float* lq_b  = (const float*)d_in[10];
    const float* lk_w  = (const float*)d_in[11];
    const float* lk_b  = (const float*)d_in[12];
    const float* lv_w  = (const float*)d_in[13];
    const float* lv_b  = (const float*)d_in[14];
    const float* l_tgt = (const float*)d_in[15];
    const float* fc1_w = (const float*)d_in[16];
    const float* fc1_b = (const float*)d_in[17];
    const float* fc2_w = (const float*)d_in[18];
    const float* fc2_b = (const float*)d_in[19];
    float* out = (float*)d_out;
    float* ws = (float*)d_ws;

    const long O_LINE_E = 0;
    const long O_MASK_L = 819200;
    const long O_DOC_E  = 821248;
    const long O_BIAS_W = 827648;
    const long O_BIAS_L = 828928;
    const long O_EMB_H  = 830208;
    const long O_EMB_L  = 5630208;
    const long O_WTW_H  = 10430208;
    const long O_WTW_L  = 10635008;
    const long O_WTL_H  = 10839808;
    const long O_WTL_L  = 11106048;
    const long O_LE_H   = 11372288;
    const long O_LE_L   = 11798272;
    const long O_R      = 12224256;

    const long LINE_QKV_FL = (long)NLINES * NCOLS;    // 2457600
    long ws_fl = (long)(ws_size / 4);
    long Rcap = ws_fl - O_R;

    if (Rcap >= LINE_QKV_FL) {
        // ================= MFMA fast path =================
        float* line_e = ws + O_LINE_E;
        float* mask_l = ws + O_MASK_L;
        float* doc_e  = ws + O_DOC_E;
        float* bias_w = ws + O_BIAS_W;
        float* bias_l = ws + O_BIAS_L;
        bf16* embh = (bf16*)(ws + O_EMB_H);
        bf16* embl = (bf16*)(ws + O_EMB_L);
        bf16* wtwh = (bf16*)(ws + O_WTW_H);
        bf16* wtwl = (bf16*)(ws + O_WTW_L);
        bf16* wtlh = (bf16*)(ws + O_WTL_H);
        bf16* wtll = (bf16*)(ws + O_WTL_L);
        bf16* leh  = (bf16*)(ws + O_LE_H);
        bf16* lel  = (bf16*)(ws + O_LE_L);
        float* R   = ws + O_R;

        split_rows<<<(30000L * 320 + 255) / 256, 256, 0, stream>>>(emb, embh, embl, 30000, 300, 320);
        split_wt<<<((long)NPAD * 320 + 255) / 256, 256, 0, stream>>>(wq_w, wk_w, wv_w,
                                                                     wq_b, wk_b, wv_b,
                                                                     wtwh, wtwl, bias_w, 300, 320);
        split_wt<<<((long)NPAD * 416 + 255) / 256, 256, 0, stream>>>(lq_w, lk_w, lv_w,
                                                                     lq_b, lk_b, lv_b,
                                                                     wtlh, wtll, bias_l, 400, 416);

        // chunk = 512 lines: qkv chunk (82 MB) + emb tables (38 MB) stay
        // L3-resident -> gemm writes & attn reads absorbed by Infinity Cache
        long maxl = Rcap / WLINE_FL;
        if (maxl > 512) maxl = 512;
        long chunk = (maxl / 4) * 4;
        if (chunk < 4) chunk = 4;
        for (long c0 = 0; c0 < NLINES; c0 += chunk) {
            long cl = NLINES - c0 < chunk ? NLINES - c0 : chunk;   // multiple of 4
            dim3 g1(10, (unsigned)((cl * 32) / 128));   // x=col (fastest), y=row
            mfma_gemm<<<g1, 256, 0, stream>>>(embh, embl, docs + c0 * WPL,
                                              wtwh, wtwl, bias_w, R, 320, 1);
            word_attn3<<<(unsigned)(cl * NH), 64, 0, stream>>>(R, docs + c0 * WPL, w_tgt,
                                                               line_e + c0 * AD, mask_l + c0);
        }

        split_rows<<<((long)NLINES * 416 + 255) / 256, 256, 0, stream>>>(line_e, leh, lel,
                                                                         NLINES, 400, 416);
        dim3 g2(10, NLINES / 128);
        mfma_gemm<<<g2, 256, 0, stream>>>(leh, lel, nullptr, wtlh, wtll, bias_l, R, 416, 0);
        line_attn_g<<<BATCH * NH, 256, 0, stream>>>(R, R + 400, R + 800,
                                                    (long)LPD * NCOLS, (long)DPH, (long)NCOLS,
                                                    l_tgt, mask_l, doc_e);
        logits_kernel<<<(BATCH * 582 + 255) / 256, 256, 0, stream>>>(doc_e, fc1_w, fc1_b,
                                                                     fc2_w, fc2_b, out);
    } else {
        // ================= fp32 fallback =================
        const long F_FIXED = 827648;
        const long PER_LINE_FL = (long)WPL * NCOLS;
        float* line_e = ws;
        float* mask_l = ws + 819200;
        float* doc_e  = ws + 821248;
        float* R      = ws + F_FIXED;
        long Rcap2 = ws_fl - F_FIXED;

        long maxl = Rcap2 / PER_LINE_FL;
        if (maxl > NLINES) maxl = NLINES;
        long maxl4 = (maxl / 4) * 4;
        int nc = (int)((NLINES + maxl4 - 1) / maxl4);
        int chunk = (int)((NLINES + nc - 1) / nc);
        chunk = ((chunk + 3) / 4) * 4;

        for (int c0 = 0; c0 < NLINES; c0 += chunk) {
            int cl = NLINES - c0 < chunk ? NLINES - c0 : chunk;
            dim3 g1((cl * 32) / 128, 10);
            gemm_qkv<<<g1, 256, 0, stream>>>(nullptr, docs + (size_t)c0 * WPL, emb,
                                             wq_w, wk_w, wv_w, wq_b, wk_b, wv_b,
                                             R, cl * 32, EMBD);
            word_attn<<<cl, 256, 0, stream>>>(R, docs + (size_t)c0 * WPL, w_tgt,
                                              line_e + (size_t)c0 * AD, mask_l + c0);
        }
        dim3 g2(16, 10);
        gemm_qkv<<<g2, 256, 0, stream>>>(line_e, nullptr, emb,
                                         lq_w, lk_w, lv_w, lq_b, lk_b, lv_b,
                                         R, NLINES, AD);
        line_attn_g<<<BATCH * NH, 256, 0, stream>>>(R, R + 400, R + 800,
                                                    (long)LPD * NCOLS, (long)DPH, (long)NCOLS,
                                                    l_tgt, mask_l, doc_e);
        logits_kernel<<<(BATCH * 582 + 255) / 256, 256, 0, stream>>>(doc_e, fc1_w, fc1_b,
                                                                     fc2_w, fc2_b, out);
    }
}

// Round 10
// 795.911 us; speedup vs baseline: 1.2182x; 1.0761x over previous
//
#include <hip/hip_runtime.h>
#include <math.h>

#define NLINES 2048
#define WPL 32
#define EMBD 300
#define AD 400
#define NH 8
#define DPH 50
#define QKV_S 52
#define SC_S 36
#define BATCH 16
#define LPD 128
#define NCOLS 1200     // 3 proj * 400
#define NPAD 1280      // padded col count for Wt tables
#define WLINE_FL 39936 // per-line floats in word layout: 8*3*32*52
#define HBLK 4992      // per-(line,head) floats: 3*32*52

typedef __bf16 bf16;
typedef bf16  v8bf __attribute__((ext_vector_type(8)));
typedef float v4f  __attribute__((ext_vector_type(4)));

__device__ __forceinline__ float elu(float x) {
    return x > 0.f ? x : expm1f(x);
}

#define SCALE 7.0710678118654755f   // sqrt(50)

// ===========================================================================
// Split helpers: fp32 -> (hi, lo) bf16 pair.  x ~= hi + lo, rel err ~2^-18.
// ===========================================================================
__global__ void split_rows(const float* __restrict__ src,
                           bf16* __restrict__ hi, bf16* __restrict__ lo,
                           int rows, int K, int K2)
{
    long idx = (long)blockIdx.x * 256 + threadIdx.x;
    if (idx >= (long)rows * K2) return;
    int r = (int)(idx / K2), k = (int)(idx - (long)r * K2);
    float x = (k < K) ? src[(long)r * K + k] : 0.f;
    bf16 h = (bf16)x;
    float hf = (float)h;
    bf16 l = (bf16)(x - hf);
    hi[idx] = h; lo[idx] = l;
}

__global__ void split_wt(const float* __restrict__ W0, const float* __restrict__ W1,
                         const float* __restrict__ W2,
                         const float* __restrict__ B0, const float* __restrict__ B1,
                         const float* __restrict__ B2,
                         bf16* __restrict__ hi, bf16* __restrict__ lo,
                         float* __restrict__ biasCat, int K, int K2)
{
    long idx = (long)blockIdx.x * 256 + threadIdx.x;
    if (idx >= (long)NPAD * K2) return;
    int n = (int)(idx / K2), k = (int)(idx - (long)n * K2);
    float x = 0.f;
    if (k < K && n < NCOLS) {
        int p = n / 400, c = n - p * 400;
        const float* W = (p == 0) ? W0 : (p == 1) ? W1 : W2;
        x = W[(long)k * 400 + c];
    }
    bf16 h = (bf16)x;
    float hf = (float)h;
    bf16 l = (bf16)(x - hf);
    hi[idx] = h; lo[idx] = l;
    if (k == 0) {
        float b = 0.f;
        if (n < NCOLS) {
            int p = n / 400, c = n - p * 400;
            const float* Bp = (p == 0) ? B0 : (p == 1) ? B1 : B2;
            b = Bp[c];
        }
        biasCat[n] = b;
    }
}

// ===========================================================================
// mfma_gemm: C = elu( A @ Wt^T + biasCat ), split-bf16 3-product, staged LDS.
// GRID: x = col-block (fastest, shares A rows), y = row-block.
// word_layout=1: C[(line*8+h)*3+p][32][52]; word_layout=0: row-major [row][1200].
// ===========================================================================
__launch_bounds__(256)
__global__ void mfma_gemm(const bf16* __restrict__ Ah_t, const bf16* __restrict__ Al_t,
                          const int* __restrict__ docs,
                          const bf16* __restrict__ Bh_t, const bf16* __restrict__ Bl_t,
                          const float* __restrict__ biasCat,
                          float* __restrict__ C, int K2, int word_layout)
{
    __shared__ __align__(16) bf16 Ah[4096];
    __shared__ __align__(16) bf16 Al[4096];
    __shared__ __align__(16) bf16 Bh[4096];
    __shared__ __align__(16) bf16 Bl[4096];
    __shared__ int tok[128];

    const int tid = threadIdx.x;
    const int row0 = blockIdx.y * 128;     // y = row-block
    const int n0 = blockIdx.x * 128;       // x = col-block (fastest)

    if (tid < 128) tok[tid] = docs ? docs[row0 + tid] : (row0 + tid);
    __syncthreads();

    const int qa = tid >> 7;
    const int sm = tid & 127;
    const long aoff = (long)tok[sm] * K2;
    const long boff = (long)(n0 + sm) * K2;

    const int wv = tid >> 6, lane = tid & 63;
    const int quad = lane >> 4, r16 = lane & 15;
    const int wm0 = (wv >> 1) * 64, wn0 = (wv & 1) * 64;

    v4f acc[4][4];
    #pragma unroll
    for (int a = 0; a < 4; ++a)
        #pragma unroll
        for (int b = 0; b < 4; ++b) acc[a][b] = (v4f)0.f;

    const int nk = K2 >> 5;
    // prefetch tile 0
    v8bf pa0 = *(const v8bf*)(Ah_t + aoff + qa * 8);
    v8bf pa1 = *(const v8bf*)(Ah_t + aoff + (qa + 2) * 8);
    v8bf pl0 = *(const v8bf*)(Al_t + aoff + qa * 8);
    v8bf pl1 = *(const v8bf*)(Al_t + aoff + (qa + 2) * 8);
    v8bf pb0 = *(const v8bf*)(Bh_t + boff + qa * 8);
    v8bf pb1 = *(const v8bf*)(Bh_t + boff + (qa + 2) * 8);
    v8bf pc0 = *(const v8bf*)(Bl_t + boff + qa * 8);
    v8bf pc1 = *(const v8bf*)(Bl_t + boff + (qa + 2) * 8);

    for (int kt = 0; kt < nk; ++kt) {
        *(v8bf*)&Ah[tid * 8]         = pa0;
        *(v8bf*)&Ah[(256 + tid) * 8] = pa1;
        *(v8bf*)&Al[tid * 8]         = pl0;
        *(v8bf*)&Al[(256 + tid) * 8] = pl1;
        *(v8bf*)&Bh[tid * 8]         = pb0;
        *(v8bf*)&Bh[(256 + tid) * 8] = pb1;
        *(v8bf*)&Bl[tid * 8]         = pc0;
        *(v8bf*)&Bl[(256 + tid) * 8] = pc1;
        __syncthreads();

        if (kt + 1 < nk) {   // next tile's loads fly during MFMA
            const int k1 = (kt + 1) * 32;
            pa0 = *(const v8bf*)(Ah_t + aoff + k1 + qa * 8);
            pa1 = *(const v8bf*)(Ah_t + aoff + k1 + (qa + 2) * 8);
            pl0 = *(const v8bf*)(Al_t + aoff + k1 + qa * 8);
            pl1 = *(const v8bf*)(Al_t + aoff + k1 + (qa + 2) * 8);
            pb0 = *(const v8bf*)(Bh_t + boff + k1 + qa * 8);
            pb1 = *(const v8bf*)(Bh_t + boff + k1 + (qa + 2) * 8);
            pc0 = *(const v8bf*)(Bl_t + boff + k1 + qa * 8);
            pc1 = *(const v8bf*)(Bl_t + boff + k1 + (qa + 2) * 8);
        }

        v8bf fa_h[4], fa_l[4], fb_h[4], fb_l[4];
        #pragma unroll
        for (int t = 0; t < 4; ++t) {
            const int ea = quad * 128 + wm0 + t * 16 + r16;
            fa_h[t] = *(const v8bf*)&Ah[ea * 8];
            fa_l[t] = *(const v8bf*)&Al[ea * 8];
            const int eb = quad * 128 + wn0 + t * 16 + r16;
            fb_h[t] = *(const v8bf*)&Bh[eb * 8];
            fb_l[t] = *(const v8bf*)&Bl[eb * 8];
        }

        #pragma unroll
        for (int mt = 0; mt < 4; ++mt)
            #pragma unroll
            for (int nt = 0; nt < 4; ++nt) {
                acc[mt][nt] = __builtin_amdgcn_mfma_f32_16x16x32_bf16(fa_h[mt], fb_h[nt], acc[mt][nt], 0, 0, 0);
                acc[mt][nt] = __builtin_amdgcn_mfma_f32_16x16x32_bf16(fa_h[mt], fb_l[nt], acc[mt][nt], 0, 0, 0);
                acc[mt][nt] = __builtin_amdgcn_mfma_f32_16x16x32_bf16(fa_l[mt], fb_h[nt], acc[mt][nt], 0, 0, 0);
            }
        __syncthreads();
    }

    // ---- epilogue: D row = quad*4+reg, col = lane&15
    if (word_layout) {
        #pragma unroll
        for (int nt = 0; nt < 4; ++nt) {
            const int col = n0 + wn0 + nt * 16 + r16;
            if (col >= NCOLS) continue;
            const float bv = biasCat[col];
            const int p = col / 400;
            const int rem = col - p * 400;
            const int hh = rem / 50;
            const int d  = rem - hh * 50;
            #pragma unroll
            for (int mt = 0; mt < 4; ++mt) {
                const int rbase = row0 + wm0 + mt * 16 + quad * 4;
                #pragma unroll
                for (int rg = 0; rg < 4; ++rg) {
                    const int row = rbase + rg;
                    const int ln = row >> 5, r = row & 31;
                    const float x = acc[mt][nt][rg] + bv;
                    C[(((long)ln * NH + hh) * 3 + p) * 1664 + r * 52 + d] =
                        x > 0.f ? x : expm1f(x);
                }
            }
        }
    } else {
        #pragma unroll
        for (int nt = 0; nt < 4; ++nt) {
            const int col = n0 + wn0 + nt * 16 + r16;
            if (col >= NCOLS) continue;
            const float bv = biasCat[col];
            #pragma unroll
            for (int mt = 0; mt < 4; ++mt) {
                const int rbase = row0 + wm0 + mt * 16 + quad * 4;
                #pragma unroll
                for (int rg = 0; rg < 4; ++rg) {
                    const float x = acc[mt][nt][rg] + bv;
                    C[(long)(rbase + rg) * NCOLS + col] = x > 0.f ? x : expm1f(x);
                }
            }
        }
    }
}

// ===========================================================================
// word_attn3: one WAVE per (line, head).  qkvw layout [line][h][3][32][52].
// ===========================================================================
__launch_bounds__(64)
__global__ void word_attn3(const float* __restrict__ qkvw, const int* __restrict__ docs,
                           const float* __restrict__ w_tgt,
                           float* __restrict__ line_e, float* __restrict__ mask_l)
{
    __shared__ __align__(16) float sh[HBLK];   // q[0..1663] k[1664..] v[3328..]
    __shared__ float sc[32 * 33];
    __shared__ float msk[WPL];
    __shared__ float cwl[WPL];
    __shared__ float tg[52];

    const int lane = threadIdx.x;
    const int bid = blockIdx.x;
    const int line = bid >> 3;
    const int h = bid & 7;
    const int j = lane & 31;
    const int khalf = lane >> 5;

    const int tokj = docs[line * WPL + j];
    const float mskj = (tokj != 0) ? 1.f : 0.f;
    if (lane < 32) msk[lane] = mskj;
    const unsigned long long bal = __ballot(tokj != 0);
    const float mls = bal ? 1.f : 0.f;
    if (lane == 0 && h == 0) mask_l[line] = mls;

    // ---- stage this (line, head)'s contiguous 20KB block
    const float* src = qkvw + ((long)line * NH + h) * HBLK;
    for (int i = lane; i < HBLK / 4; i += 64)
        *(float4*)&sh[i * 4] = *(const float4*)&src[i * 4];
    // zero d=50,51 pads (GEMM never writes them)
    for (int idx = lane; idx < 192; idx += 64) {
        const int a = idx / 64, rem = idx - a * 64;
        sh[a * 1664 + (rem >> 1) * 52 + 50 + (rem & 1)] = 0.f;
    }
    if (lane < 52) tg[lane] = (lane < 50) ? w_tgt[h * 50 + lane] : 0.f;
    __syncthreads();

    // ---- q row into regs
    float4 qv[13];
    #pragma unroll
    for (int i = 0; i < 13; ++i) qv[i] = *(const float4*)&sh[j * 52 + i * 4];

    // ---- scores for kk = khalf*16 + c
    float w1[16];
    float rmax = -1e30f;
    #pragma unroll
    for (int c = 0; c < 16; ++c) {
        const int kk = khalf * 16 + c;
        const float* kr = &sh[1664 + kk * 52];
        float s = 0.f;
        #pragma unroll
        for (int i = 0; i < 13; ++i) {
            const float4 kv = *(const float4*)&kr[i * 4];
            s += qv[i].x * kv.x + qv[i].y * kv.y + qv[i].z * kv.z + qv[i].w * kv.w;
        }
        s = s / SCALE - 1e7f * (1.f - msk[kk]);
        w1[c] = s;
        rmax = fmaxf(rmax, s);
    }
    rmax = fmaxf(rmax, __shfl_xor(rmax, 32));
    float rsum = 0.f;
    #pragma unroll
    for (int c = 0; c < 16; ++c) { w1[c] = expf(w1[c] - rmax); rsum += w1[c]; }
    rsum += __shfl_xor(rsum, 32);
    const float rinv = 1.f / rsum;

    // ---- target score for key row j (duplicated across halves)
    float ts;
    {
        const float* kr = &sh[1664 + j * 52];
        float s = 0.f;
        #pragma unroll
        for (int i = 0; i < 13; ++i) {
            const float4 kv = *(const float4*)&kr[i * 4];
            const float4 tv = *(const float4*)&tg[i * 4];
            s += kv.x * tv.x + kv.y * tv.y + kv.z * tv.z + kv.w * tv.w;
        }
        ts = s / SCALE - 1e7f * (1.f - mskj);
    }
    float tm = ts;
    #pragma unroll
    for (int off = 16; off >= 1; off >>= 1) tm = fmaxf(tm, __shfl_xor(tm, off));
    const float te = expf(ts - tm);
    float tsum = te;
    #pragma unroll
    for (int off = 16; off >= 1; off >>= 1) tsum += __shfl_xor(tsum, off);
    const float twj = te / tsum;

    // ---- sc[j][kk] = tw[j]*msk[j]*softmax_row_j[kk]
    const float coef = twj * mskj * rinv;
    #pragma unroll
    for (int c = 0; c < 16; ++c)
        sc[j * 33 + khalf * 16 + c] = coef * w1[c];
    __syncthreads();

    if (lane < 32) {
        float cv = 0.f;
        #pragma unroll
        for (int jj = 0; jj < 32; ++jj) cv += sc[jj * 33 + lane];
        cwl[lane] = cv;
    }
    __syncthreads();

    if (lane < DPH) {
        float acc2 = 0.f;
        #pragma unroll
        for (int kk = 0; kk < 32; ++kk)
            acc2 += cwl[kk] * sh[3328 + kk * 52 + lane];
        line_e[(long)line * AD + h * 50 + lane] = acc2 * mls;
    }
}

// ===========================================================================
// line_attn2: fully-parallel line attention + doc target attention.
// Block per (doc, h), 256 threads.  Element (doc,h,l,d) of Q at
// Q + doc*DS + h*HS + l*LS + d (same for K,V).
// Two 64-row groups; thread = (j2 = tid&63, kq = tid>>6) -> 32 scores each.
// LDS < 64 KB.  No serial softmax loops, no >2-way bank conflicts.
// ===========================================================================
__launch_bounds__(256)
__global__ void line_attn2(const float* __restrict__ Q, const float* __restrict__ Kp,
                           const float* __restrict__ Vp,
                           long DS, long HS, long LS,
                           const float* __restrict__ l_tgt, const float* __restrict__ mask_l,
                           float* __restrict__ doc_e)
{
    __shared__ float kl[LPD * 52];     // 26624 B
    __shared__ float sc[64 * 130];     // 33280 B
    __shared__ float ml[LPD];
    __shared__ float tw[LPD];
    __shared__ float cw[LPD];
    __shared__ float coefA[64];
    __shared__ float pm[4 * 64];
    __shared__ float ps[4 * 64];
    __shared__ float tg[52];
    __shared__ float rr[2];
    __shared__ float vpart[2][64];

    const int tid = threadIdx.x;
    const int doc = blockIdx.x >> 3;
    const int h = blockIdx.x & 7;
    const float* qbase = Q + doc * DS + h * HS;
    const float* kbase = Kp + doc * DS + h * HS;
    const float* vbase = Vp + doc * DS + h * HS;

    if (tid < LPD) { ml[tid] = mask_l[doc * LPD + tid]; cw[tid] = 0.f; }
    if (tid < 52) tg[tid] = (tid < DPH) ? l_tgt[h * DPH + tid] : 0.f;
    for (int idx = tid; idx < LPD * 52; idx += 256) {
        const int r = idx / 52, d = idx - r * 52;
        kl[idx] = (d < DPH) ? kbase[(long)r * LS + d] : 0.f;
    }
    __syncthreads();

    // ---- target scores: thread tid<128 computes ts for key row tid
    if (tid < LPD) {
        const float* kr = &kl[tid * 52];
        float s = 0.f;
        #pragma unroll
        for (int i = 0; i < 25; ++i)
            s += tg[2 * i] * kr[2 * i] + tg[2 * i + 1] * kr[2 * i + 1];
        tw[tid] = s / SCALE - 1e7f * (1.f - ml[tid]);   // raw ts
    }
    __syncthreads();
    // target max/sum: one wave
    if (tid < 64) {
        float a = fmaxf(tw[tid], tw[64 + tid]);
        #pragma unroll
        for (int off = 32; off >= 1; off >>= 1) a = fmaxf(a, __shfl_xor(a, off));
        if (tid == 0) rr[0] = a;
    }
    __syncthreads();
    if (tid < 64) {
        const float tm2 = rr[0];
        float a = expf(tw[tid] - tm2) + expf(tw[64 + tid] - tm2);
        #pragma unroll
        for (int off = 32; off >= 1; off >>= 1) a += __shfl_xor(a, off);
        if (tid == 0) rr[1] = a;
    }
    __syncthreads();
    if (tid < LPD) tw[tid] = expf(tw[tid] - rr[0]) / rr[1];   // final tw
    __syncthreads();

    const int j2 = tid & 63;
    const int kq = tid >> 6;          // 0..3, k range [kq*32, kq*32+32)

    for (int g = 0; g < 2; ++g) {
        const int j = g * 64 + j2;
        // q row j into regs (float2; 8B-aligned for both call sites)
        float2 qv[25];
        #pragma unroll
        for (int i = 0; i < 25; ++i)
            qv[i] = *(const float2*)(qbase + (long)j * LS + 2 * i);

        // 32 raw scores -> sc[j2][k], track max
        float m = -1e30f;
        for (int c = 0; c < 32; ++c) {
            const int k = kq * 32 + c;
            const float* kr = &kl[k * 52];
            float s = 0.f;
            #pragma unroll
            for (int i = 0; i < 25; ++i)
                s += qv[i].x * kr[2 * i] + qv[i].y * kr[2 * i + 1];
            s = s / SCALE - 1e7f * (1.f - ml[k]);
            sc[j2 * 130 + k] = s;
            m = fmaxf(m, s);
        }
        pm[kq * 64 + j2] = m;
        __syncthreads();
        const float rowm = fmaxf(fmaxf(pm[j2], pm[64 + j2]),
                                 fmaxf(pm[128 + j2], pm[192 + j2]));
        float sum = 0.f;
        for (int c = 0; c < 32; ++c) {
            const int k = kq * 32 + c;
            const float e = expf(sc[j2 * 130 + k] - rowm);
            sc[j2 * 130 + k] = e;
            sum += e;
        }
        ps[kq * 64 + j2] = sum;
        __syncthreads();
        if (kq == 0) {
            const float rs = ps[j2] + ps[64 + j2] + ps[128 + j2] + ps[192 + j2];
            coefA[j2] = tw[j] * ml[j] / rs;
        }
        __syncthreads();
        // cw[k] += sum_j2 coefA[j2] * sc[j2][k]   (threads 0..127 = k)
        if (tid < LPD) {
            float cv = 0.f;
            for (int jj = 0; jj < 64; ++jj)
                cv += coefA[jj] * sc[jj * 130 + tid];
            cw[tid] += cv;
        }
        __syncthreads();   // before next group overwrites sc
    }

    // ---- doc_e[d] = sum_k cw[k] * V[k][d]; threads (d = tid&63, half = tid>>6&1)
    const int d = tid & 63;
    const int half = (tid >> 6) & 1;
    if (tid < 128 && d < DPH) {
        float acc = 0.f;
        for (int k = half * 64; k < half * 64 + 64; ++k)
            acc += cw[k] * vbase[(long)k * LS + d];
        vpart[half][d] = acc;
    }
    __syncthreads();
    if (tid < DPH)
        doc_e[doc * AD + h * DPH + tid] = vpart[0][tid] + vpart[1][tid];
}

// ===========================================================================
// FALLBACK kernels (fp32 path, round-3 proven)
// ===========================================================================
__launch_bounds__(256)
__global__ void word_attn(const float* __restrict__ qkv, const int* __restrict__ docs,
                          const float* __restrict__ w_tgt,
                          float* __restrict__ line_e, float* __restrict__ mask_l)
{
    __shared__ float qs[WPL * QKV_S];
    __shared__ float ks[WPL * QKV_S];
    __shared__ float vs[WPL * QKV_S];
    __shared__ float sc[WPL * SC_S];
    __shared__ float ts[WPL], tw[WPL], cw[WPL], msk[WPL];
    __shared__ float mls;

    const int tid = threadIdx.x;
    const int line = blockIdx.x;

    if (tid < WPL) msk[tid] = (docs[line * WPL + tid] != 0) ? 1.f : 0.f;
    __syncthreads();
    if (tid == 0) {
        float ml = 0.f;
        for (int w = 0; w < WPL; ++w) ml = fmaxf(ml, msk[w]);
        mls = ml;
        mask_l[line] = ml;
    }
    for (int h = 0; h < NH; ++h) {
        for (int idx = tid; idx < WPL * DPH; idx += 256) {
            const int r = idx / DPH, d = idx - r * DPH;
            const size_t base = (size_t)(line * WPL + r) * NCOLS + h * DPH + d;
            qs[r * QKV_S + d] = qkv[base];
            ks[r * QKV_S + d] = qkv[base + 400];
            vs[r * QKV_S + d] = qkv[base + 800];
        }
        __syncthreads();
        {
            const int j = tid >> 3, kg = tid & 7;
            #pragma unroll
            for (int c = 0; c < 4; ++c) {
                const int kk = kg * 4 + c;
                float s = 0.f;
                for (int dd = 0; dd < DPH; ++dd)
                    s += qs[j * QKV_S + dd] * ks[kk * QKV_S + dd];
                sc[j * SC_S + kk] = s / SCALE - 1e7f * (1.f - msk[kk]);
            }
        }
        if (tid < WPL) {
            float s = 0.f;
            for (int dd = 0; dd < DPH; ++dd)
                s += w_tgt[h * DPH + dd] * ks[tid * QKV_S + dd];
            ts[tid] = s / SCALE - 1e7f * (1.f - msk[tid]);
        }
        __syncthreads();
        if (tid < WPL) {
            const int j = tid;
            float m = -1e30f;
            for (int kk = 0; kk < WPL; ++kk) m = fmaxf(m, sc[j * SC_S + kk]);
            float sum = 0.f;
            for (int kk = 0; kk < WPL; ++kk) {
                const float e = expf(sc[j * SC_S + kk] - m);
                sc[j * SC_S + kk] = e;
                sum += e;
            }
            const float inv = 1.f / sum;
            for (int kk = 0; kk < WPL; ++kk) sc[j * SC_S + kk] *= inv;
        } else if (tid == WPL) {
            float m = -1e30f;
            for (int jj = 0; jj < WPL; ++jj) m = fmaxf(m, ts[jj]);
            float sum = 0.f;
            for (int jj = 0; jj < WPL; ++jj) { const float e = expf(ts[jj] - m); tw[jj] = e; sum += e; }
            const float inv = 1.f / sum;
            for (int jj = 0; jj < WPL; ++jj) tw[jj] *= inv;
        }
        __syncthreads();
        if (tid < WPL) {
            const int kk = tid;
            float c = 0.f;
            for (int jj = 0; jj < WPL; ++jj) c += tw[jj] * msk[jj] * sc[jj * SC_S + kk];
            cw[kk] = c;
        }
        __syncthreads();
        if (tid < DPH) {
            float acc = 0.f;
            for (int kk = 0; kk < WPL; ++kk) acc += cw[kk] * vs[kk * QKV_S + tid];
            line_e[line * AD + h * DPH + tid] = acc * mls;
        }
        __syncthreads();
    }
}

__launch_bounds__(256, 2)
__global__ void gemm_qkv(const float* __restrict__ Asrc,
                         const int* __restrict__ docs,
                         const float* __restrict__ emb,
                         const float* __restrict__ W0, const float* __restrict__ W1,
                         const float* __restrict__ W2,
                         const float* __restrict__ B0, const float* __restrict__ B1,
                         const float* __restrict__ B2,
                         float* __restrict__ C, int M, int K)
{
    __shared__ __align__(16) float As[32][132];
    __shared__ __align__(16) float Bs[32][132];

    const int tid = threadIdx.x;
    const int row0 = blockIdx.x * 128;
    const int n0 = blockIdx.y * 128;
    const int tc = tid & 15, tr = tid >> 4;

    float acc[2][2][4][4];
    #pragma unroll
    for (int a = 0; a < 2; ++a)
        #pragma unroll
        for (int b = 0; b < 2; ++b)
            #pragma unroll
            for (int c = 0; c < 4; ++c)
                #pragma unroll
                for (int d = 0; d < 4; ++d) acc[a][b][c][d] = 0.f;

    const int ma = tid & 127;
    const int kq = tid >> 7;
    const float* arow;
    if (docs) arow = emb + (size_t)docs[row0 + ma] * EMBD;
    else      arow = Asrc + (size_t)(row0 + ma) * K;

    const int gcol = n0 + ma;
    const int p = gcol / 400;
    const int ccol = gcol - p * 400;
    const float* Wp = (p == 0) ? W0 : (p == 1) ? W1 : W2;
    const bool colv = gcol < NCOLS;

    const int nk = (K + 31) >> 5;
    for (int ck = 0; ck < nk; ++ck) {
        const int k0 = ck * 32;
        #pragma unroll
        for (int f = 0; f < 4; ++f) {
            const int kl = kq * 16 + f * 4;
            const int kg = k0 + kl;
            float4 v = make_float4(0.f, 0.f, 0.f, 0.f);
            if (kg < K) v = *(const float4*)(arow + kg);
            As[kl + 0][ma] = v.x;
            As[kl + 1][ma] = v.y;
            As[kl + 2][ma] = v.z;
            As[kl + 3][ma] = v.w;
        }
        #pragma unroll
        for (int i = 0; i < 16; ++i) {
            const int kl = kq * 16 + i;
            const int kg = k0 + kl;
            float v = 0.f;
            if (colv && kg < K) v = Wp[(size_t)kg * 400 + ccol];
            Bs[kl][ma] = v;
        }
        __syncthreads();

        #pragma unroll 8
        for (int k = 0; k < 32; ++k) {
            const float4 a0 = *(const float4*)&As[k][tr * 4];
            const float4 a1 = *(const float4*)&As[k][64 + tr * 4];
            const float4 b0 = *(const float4*)&Bs[k][tc * 4];
            const float4 b1 = *(const float4*)&Bs[k][64 + tc * 4];
            const float ar[2][4] = {{a0.x, a0.y, a0.z, a0.w}, {a1.x, a1.y, a1.z, a1.w}};
            const float br[2][4] = {{b0.x, b0.y, b0.z, b0.w}, {b1.x, b1.y, b1.z, b1.w}};
            #pragma unroll
            for (int im = 0; im < 2; ++im)
                #pragma unroll
                for (int in_ = 0; in_ < 2; ++in_)
                    #pragma unroll
                    for (int rr = 0; rr < 4; ++rr)
                        #pragma unroll
                        for (int cc = 0; cc < 4; ++cc)
                            acc[im][in_][rr][cc] += ar[im][rr] * br[in_][cc];
        }
        __syncthreads();
    }

    #pragma unroll
    for (int in_ = 0; in_ < 2; ++in_) {
        const int ncol = n0 + in_ * 64 + tc * 4;
        if (ncol >= NCOLS) continue;
        const int pj = ncol / 400;
        const int cj = ncol - pj * 400;
        const float* Bp = (pj == 0) ? B0 : (pj == 1) ? B1 : B2;
        const float4 bv = *(const float4*)(Bp + cj);
        #pragma unroll
        for (int im = 0; im < 2; ++im) {
            #pragma unroll
            for (int rr = 0; rr < 4; ++rr) {
                const int row = row0 + im * 64 + tr * 4 + rr;
                float4 o;
                o.x = elu(acc[im][in_][rr][0] + bv.x);
                o.y = elu(acc[im][in_][rr][1] + bv.y);
                o.z = elu(acc[im][in_][rr][2] + bv.z);
                o.w = elu(acc[im][in_][rr][3] + bv.w);
                *(float4*)(C + (size_t)row * NCOLS + ncol) = o;
            }
        }
    }
}

__global__ void logits_kernel(const float* __restrict__ doc_e,
                              const float* __restrict__ fc1_w, const float* __restrict__ fc1_b,
                              const float* __restrict__ fc2_w, const float* __restrict__ fc2_b,
                              float* __restrict__ out)
{
    int o = blockIdx.x * blockDim.x + threadIdx.x;
    if (o >= BATCH * 582) return;
    int b = o / 582, jj = o - b * 582;
    const float* de = doc_e + b * AD;
    float acc;
    if (jj < 70) {
        acc = fc1_b[jj];
        for (int k = 0; k < AD; ++k) acc += de[k] * fc1_w[k * 70 + jj];
    } else {
        int j2 = jj - 70;
        acc = fc2_b[j2];
        for (int k = 0; k < AD; ++k) acc += de[k] * fc2_w[k * 512 + j2];
    }
    out[o] = acc;
}

// ---------------------------------------------------------------------------
extern "C" void kernel_launch(void* const* d_in, const int* in_sizes, int n_in,
                              void* d_out, int out_size, void* d_ws, size_t ws_size,
                              hipStream_t stream) {
    const int*   docs  = (const int*)  d_in[0];
    const float* emb   = (const float*)d_in[1];
    const float* wq_w  = (const float*)d_in[2];
    const float* wq_b  = (const float*)d_in[3];
    const float* wk_w  = (const float*)d_in[4];
    const float* wk_b  = (const float*)d_in[5];
    const float* wv_w  = (const float*)d_in[6];
    const float* wv_b  = (const float*)d_in[7];
    const float* w_tgt = (const float*)d_in[8];
    const float* lq_w  = (const float*)d_in[9];
    const float* lq_b  = (const float*)d_in[10];
    const float* lk_w  = (const float*)d_in[11];
    const float* lk_b  = (const float*)d_in[12];
    const float* lv_w  = (const float*)d_in[13];
    const float* lv_b  = (const float*)d_in[14];
    const float* l_tgt = (const float*)d_in[15];
    const float* fc1_w = (const float*)d_in[16];
    const float* fc1_b = (const float*)d_in[17];
    const float* fc2_w = (const float*)d_in[18];
    const float* fc2_b = (const float*)d_in[19];
    float* out = (float*)d_out;
    float* ws = (float*)d_ws;

    const long O_LINE_E = 0;
    const long O_MASK_L = 819200;
    const long O_DOC_E  = 821248;
    const long O_BIAS_W = 827648;
    const long O_BIAS_L = 828928;
    const long O_EMB_H  = 830208;
    const long O_EMB_L  = 5630208;
    const long O_WTW_H  = 10430208;
    const long O_WTW_L  = 10635008;
    const long O_WTL_H  = 10839808;
    const long O_WTL_L  = 11106048;
    const long O_LE_H   = 11372288;
    const long O_LE_L   = 11798272;
    const long O_R      = 12224256;

    const long LINE_QKV_FL = (long)NLINES * NCOLS;    // 2457600
    long ws_fl = (long)(ws_size / 4);
    long Rcap = ws_fl - O_R;

    if (Rcap >= LINE_QKV_FL) {
        // ================= MFMA fast path =================
        float* line_e = ws + O_LINE_E;
        float* mask_l = ws + O_MASK_L;
        float* doc_e  = ws + O_DOC_E;
        float* bias_w = ws + O_BIAS_W;
        float* bias_l = ws + O_BIAS_L;
        bf16* embh = (bf16*)(ws + O_EMB_H);
        bf16* embl = (bf16*)(ws + O_EMB_L);
        bf16* wtwh = (bf16*)(ws + O_WTW_H);
        bf16* wtwl = (bf16*)(ws + O_WTW_L);
        bf16* wtlh = (bf16*)(ws + O_WTL_H);
        bf16* wtll = (bf16*)(ws + O_WTL_L);
        bf16* leh  = (bf16*)(ws + O_LE_H);
        bf16* lel  = (bf16*)(ws + O_LE_L);
        float* R   = ws + O_R;

        split_rows<<<(30000L * 320 + 255) / 256, 256, 0, stream>>>(emb, embh, embl, 30000, 300, 320);
        split_wt<<<((long)NPAD * 320 + 255) / 256, 256, 0, stream>>>(wq_w, wk_w, wv_w,
                                                                     wq_b, wk_b, wv_b,
                                                                     wtwh, wtwl, bias_w, 300, 320);
        split_wt<<<((long)NPAD * 416 + 255) / 256, 256, 0, stream>>>(lq_w, lk_w, lv_w,
                                                                     lq_b, lk_b, lv_b,
                                                                     wtlh, wtll, bias_l, 400, 416);

        // chunk = 512 lines: qkv chunk (82 MB) + emb tables (38 MB) stay
        // L3-resident -> gemm writes & attn reads absorbed by Infinity Cache
        long maxl = Rcap / WLINE_FL;
        if (maxl > 512) maxl = 512;
        long chunk = (maxl / 4) * 4;
        if (chunk < 4) chunk = 4;
        for (long c0 = 0; c0 < NLINES; c0 += chunk) {
            long cl = NLINES - c0 < chunk ? NLINES - c0 : chunk;   // multiple of 4
            dim3 g1(10, (unsigned)((cl * 32) / 128));   // x=col (fastest), y=row
            mfma_gemm<<<g1, 256, 0, stream>>>(embh, embl, docs + c0 * WPL,
                                              wtwh, wtwl, bias_w, R, 320, 1);
            word_attn3<<<(unsigned)(cl * NH), 64, 0, stream>>>(R, docs + c0 * WPL, w_tgt,
                                                               line_e + c0 * AD, mask_l + c0);
        }

        split_rows<<<((long)NLINES * 416 + 255) / 256, 256, 0, stream>>>(line_e, leh, lel,
                                                                         NLINES, 400, 416);
        dim3 g2(10, NLINES / 128);
        mfma_gemm<<<g2, 256, 0, stream>>>(leh, lel, nullptr, wtlh, wtll, bias_l, R, 416, 0);
        line_attn2<<<BATCH * NH, 256, 0, stream>>>(R, R + 400, R + 800,
                                                   (long)LPD * NCOLS, (long)DPH, (long)NCOLS,
                                                   l_tgt, mask_l, doc_e);
        logits_kernel<<<(BATCH * 582 + 255) / 256, 256, 0, stream>>>(doc_e, fc1_w, fc1_b,
                                                                     fc2_w, fc2_b, out);
    } else {
        // ================= fp32 fallback =================
        const long F_FIXED = 827648;
        const long PER_LINE_FL = (long)WPL * NCOLS;
        float* line_e = ws;
        float* mask_l = ws + 819200;
        float* doc_e  = ws + 821248;
        float* R      = ws + F_FIXED;
        long Rcap2 = ws_fl - F_FIXED;

        long maxl = Rcap2 / PER_LINE_FL;
        if (maxl > NLINES) maxl = NLINES;
        long maxl4 = (maxl / 4) * 4;
        int nc = (int)((NLINES + maxl4 - 1) / maxl4);
        int chunk = (int)((NLINES + nc - 1) / nc);
        chunk = ((chunk + 3) / 4) * 4;

        for (int c0 = 0; c0 < NLINES; c0 += chunk) {
            int cl = NLINES - c0 < chunk ? NLINES - c0 : chunk;
            dim3 g1((cl * 32) / 128, 10);
            gemm_qkv<<<g1, 256, 0, stream>>>(nullptr, docs + (size_t)c0 * WPL, emb,
                                             wq_w, wk_w, wv_w, wq_b, wk_b, wv_b,
                                             R, cl * 32, EMBD);
            word_attn<<<cl, 256, 0, stream>>>(R, docs + (size_t)c0 * WPL, w_tgt,
                                              line_e + (size_t)c0 * AD, mask_l + c0);
        }
        dim3 g2(16, 10);
        gemm_qkv<<<g2, 256, 0, stream>>>(line_e, nullptr, emb,
                                         lq_w, lk_w, lv_w, lq_b, lk_b, lv_b,
                                         R, NLINES, AD);
        line_attn2<<<BATCH * NH, 256, 0, stream>>>(lq_w ? ws + 821248 + 6400 - 6400 : ws, ws, ws,
                                                   0, 0, 0, l_tgt, mask_l, doc_e);
        // NOTE: fallback uses round-3 lq/lk/lv layout:
        // (the call above is replaced below with correct pointers)
        logits_kernel<<<(BATCH * 582 + 255) / 256, 256, 0, stream>>>(doc_e, fc1_w, fc1_b,
                                                                     fc2_w, fc2_b, out);
        // Correct fallback line attention launch (overwrites doc_e deterministically
        // before logits in stream order is required; re-issue proper sequence):
        line_attn2<<<BATCH * NH, 256, 0, stream>>>(R, R + 400, R + 800,
                                                   (long)LPD * NCOLS, (long)DPH, (long)NCOLS,
                                                   l_tgt, mask_l, doc_e);
        logits_kernel<<<(BATCH * 582 + 255) / 256, 256, 0, stream>>>(doc_e, fc1_w, fc1_b,
                                                                     fc2_w, fc2_b, out);
    }
}

// Round 11
// 724.518 us; speedup vs baseline: 1.3382x; 1.0985x over previous
//
#include <hip/hip_runtime.h>
#include <math.h>

#define NLINES 2048
#define WPL 32
#define EMBD 300
#define AD 400
#define NH 8
#define DPH 50
#define QKV_S 52
#define SC_S 36
#define BATCH 16
#define LPD 128
#define NCOLS 1200     // 3 proj * 400
#define NPAD 1280      // padded col count for Wt tables
#define WLINE_FL 39936 // per-line floats in word layout: 8*3*32*52
#define HBLK 4992      // per-(line,head) floats: 3*32*52

typedef __bf16 bf16;
typedef bf16  v8bf __attribute__((ext_vector_type(8)));
typedef float v4f  __attribute__((ext_vector_type(4)));

__device__ __forceinline__ float elu(float x) {
    return x > 0.f ? x : expm1f(x);
}

#define SCALE 7.0710678118654755f   // sqrt(50)

// ===========================================================================
// Split helpers: fp32 -> (hi, lo) bf16 pair.  x ~= hi + lo, rel err ~2^-18.
// ===========================================================================
__global__ void split_rows(const float* __restrict__ src,
                           bf16* __restrict__ hi, bf16* __restrict__ lo,
                           int rows, int K, int K2)
{
    long idx = (long)blockIdx.x * 256 + threadIdx.x;
    if (idx >= (long)rows * K2) return;
    int r = (int)(idx / K2), k = (int)(idx - (long)r * K2);
    float x = (k < K) ? src[(long)r * K + k] : 0.f;
    bf16 h = (bf16)x;
    float hf = (float)h;
    bf16 l = (bf16)(x - hf);
    hi[idx] = h; lo[idx] = l;
}

__global__ void split_wt(const float* __restrict__ W0, const float* __restrict__ W1,
                         const float* __restrict__ W2,
                         const float* __restrict__ B0, const float* __restrict__ B1,
                         const float* __restrict__ B2,
                         bf16* __restrict__ hi, bf16* __restrict__ lo,
                         float* __restrict__ biasCat, int K, int K2)
{
    long idx = (long)blockIdx.x * 256 + threadIdx.x;
    if (idx >= (long)NPAD * K2) return;
    int n = (int)(idx / K2), k = (int)(idx - (long)n * K2);
    float x = 0.f;
    if (k < K && n < NCOLS) {
        int p = n / 400, c = n - p * 400;
        const float* W = (p == 0) ? W0 : (p == 1) ? W1 : W2;
        x = W[(long)k * 400 + c];
    }
    bf16 h = (bf16)x;
    float hf = (float)h;
    bf16 l = (bf16)(x - hf);
    hi[idx] = h; lo[idx] = l;
    if (k == 0) {
        float b = 0.f;
        if (n < NCOLS) {
            int p = n / 400, c = n - p * 400;
            const float* Bp = (p == 0) ? B0 : (p == 1) ? B1 : B2;
            b = Bp[c];
        }
        biasCat[n] = b;
    }
}

// ===========================================================================
// mfma_gemm: C = elu( A @ Wt^T + biasCat ), split-bf16 3-product, staged LDS.
// GRID: x = col-block (fastest, shares A rows), y = row-block.
// word_layout=1: C[(line*8+h)*3+p][32][52]; word_layout=0: row-major [row][1200].
// ===========================================================================
__launch_bounds__(256)
__global__ void mfma_gemm(const bf16* __restrict__ Ah_t, const bf16* __restrict__ Al_t,
                          const int* __restrict__ docs,
                          const bf16* __restrict__ Bh_t, const bf16* __restrict__ Bl_t,
                          const float* __restrict__ biasCat,
                          float* __restrict__ C, int K2, int word_layout)
{
    __shared__ __align__(16) bf16 Ah[4096];
    __shared__ __align__(16) bf16 Al[4096];
    __shared__ __align__(16) bf16 Bh[4096];
    __shared__ __align__(16) bf16 Bl[4096];
    __shared__ int tok[128];

    const int tid = threadIdx.x;
    const int row0 = blockIdx.y * 128;     // y = row-block
    const int n0 = blockIdx.x * 128;       // x = col-block (fastest)

    if (tid < 128) tok[tid] = docs ? docs[row0 + tid] : (row0 + tid);
    __syncthreads();

    const int qa = tid >> 7;
    const int sm = tid & 127;
    const long aoff = (long)tok[sm] * K2;
    const long boff = (long)(n0 + sm) * K2;

    const int wv = tid >> 6, lane = tid & 63;
    const int quad = lane >> 4, r16 = lane & 15;
    const int wm0 = (wv >> 1) * 64, wn0 = (wv & 1) * 64;

    v4f acc[4][4];
    #pragma unroll
    for (int a = 0; a < 4; ++a)
        #pragma unroll
        for (int b = 0; b < 4; ++b) acc[a][b] = (v4f)0.f;

    const int nk = K2 >> 5;
    // prefetch tile 0
    v8bf pa0 = *(const v8bf*)(Ah_t + aoff + qa * 8);
    v8bf pa1 = *(const v8bf*)(Ah_t + aoff + (qa + 2) * 8);
    v8bf pl0 = *(const v8bf*)(Al_t + aoff + qa * 8);
    v8bf pl1 = *(const v8bf*)(Al_t + aoff + (qa + 2) * 8);
    v8bf pb0 = *(const v8bf*)(Bh_t + boff + qa * 8);
    v8bf pb1 = *(const v8bf*)(Bh_t + boff + (qa + 2) * 8);
    v8bf pc0 = *(const v8bf*)(Bl_t + boff + qa * 8);
    v8bf pc1 = *(const v8bf*)(Bl_t + boff + (qa + 2) * 8);

    for (int kt = 0; kt < nk; ++kt) {
        *(v8bf*)&Ah[tid * 8]         = pa0;
        *(v8bf*)&Ah[(256 + tid) * 8] = pa1;
        *(v8bf*)&Al[tid * 8]         = pl0;
        *(v8bf*)&Al[(256 + tid) * 8] = pl1;
        *(v8bf*)&Bh[tid * 8]         = pb0;
        *(v8bf*)&Bh[(256 + tid) * 8] = pb1;
        *(v8bf*)&Bl[tid * 8]         = pc0;
        *(v8bf*)&Bl[(256 + tid) * 8] = pc1;
        __syncthreads();

        if (kt + 1 < nk) {   // next tile's loads fly during MFMA
            const int k1 = (kt + 1) * 32;
            pa0 = *(const v8bf*)(Ah_t + aoff + k1 + qa * 8);
            pa1 = *(const v8bf*)(Ah_t + aoff + k1 + (qa + 2) * 8);
            pl0 = *(const v8bf*)(Al_t + aoff + k1 + qa * 8);
            pl1 = *(const v8bf*)(Al_t + aoff + k1 + (qa + 2) * 8);
            pb0 = *(const v8bf*)(Bh_t + boff + k1 + qa * 8);
            pb1 = *(const v8bf*)(Bh_t + boff + k1 + (qa + 2) * 8);
            pc0 = *(const v8bf*)(Bl_t + boff + k1 + qa * 8);
            pc1 = *(const v8bf*)(Bl_t + boff + k1 + (qa + 2) * 8);
        }

        v8bf fa_h[4], fa_l[4], fb_h[4], fb_l[4];
        #pragma unroll
        for (int t = 0; t < 4; ++t) {
            const int ea = quad * 128 + wm0 + t * 16 + r16;
            fa_h[t] = *(const v8bf*)&Ah[ea * 8];
            fa_l[t] = *(const v8bf*)&Al[ea * 8];
            const int eb = quad * 128 + wn0 + t * 16 + r16;
            fb_h[t] = *(const v8bf*)&Bh[eb * 8];
            fb_l[t] = *(const v8bf*)&Bl[eb * 8];
        }

        #pragma unroll
        for (int mt = 0; mt < 4; ++mt)
            #pragma unroll
            for (int nt = 0; nt < 4; ++nt) {
                acc[mt][nt] = __builtin_amdgcn_mfma_f32_16x16x32_bf16(fa_h[mt], fb_h[nt], acc[mt][nt], 0, 0, 0);
                acc[mt][nt] = __builtin_amdgcn_mfma_f32_16x16x32_bf16(fa_h[mt], fb_l[nt], acc[mt][nt], 0, 0, 0);
                acc[mt][nt] = __builtin_amdgcn_mfma_f32_16x16x32_bf16(fa_l[mt], fb_h[nt], acc[mt][nt], 0, 0, 0);
            }
        __syncthreads();
    }

    // ---- epilogue: D row = quad*4+reg, col = lane&15
    if (word_layout) {
        #pragma unroll
        for (int nt = 0; nt < 4; ++nt) {
            const int col = n0 + wn0 + nt * 16 + r16;
            if (col >= NCOLS) continue;
            const float bv = biasCat[col];
            const int p = col / 400;
            const int rem = col - p * 400;
            const int hh = rem / 50;
            const int d  = rem - hh * 50;
            #pragma unroll
            for (int mt = 0; mt < 4; ++mt) {
                const int rbase = row0 + wm0 + mt * 16 + quad * 4;
                #pragma unroll
                for (int rg = 0; rg < 4; ++rg) {
                    const int row = rbase + rg;
                    const int ln = row >> 5, r = row & 31;
                    const float x = acc[mt][nt][rg] + bv;
                    C[(((long)ln * NH + hh) * 3 + p) * 1664 + r * 52 + d] =
                        x > 0.f ? x : expm1f(x);
                }
            }
        }
    } else {
        #pragma unroll
        for (int nt = 0; nt < 4; ++nt) {
            const int col = n0 + wn0 + nt * 16 + r16;
            if (col >= NCOLS) continue;
            const float bv = biasCat[col];
            #pragma unroll
            for (int mt = 0; mt < 4; ++mt) {
                const int rbase = row0 + wm0 + mt * 16 + quad * 4;
                #pragma unroll
                for (int rg = 0; rg < 4; ++rg) {
                    const float x = acc[mt][nt][rg] + bv;
                    C[(long)(rbase + rg) * NCOLS + col] = x > 0.f ? x : expm1f(x);
                }
            }
        }
    }
}

// ===========================================================================
// word_attn4: one 256-thread BLOCK per (line, head).  qkvw [line][h][3][32][52].
// 4 waves co-stage 20KB; scores 4/thread with 8-lane shuffle row reductions;
// all LDS patterns <=2-way.  ~27KB LDS -> ~5 blocks/CU = 20 waves/CU.
// ===========================================================================
__launch_bounds__(256)
__global__ void word_attn4(const float* __restrict__ qkvw, const int* __restrict__ docs,
                           const float* __restrict__ w_tgt,
                           float* __restrict__ line_e, float* __restrict__ mask_l)
{
    __shared__ __align__(16) float sh[HBLK];   // q[0..1663] k[1664..] v[3328..]
    __shared__ float sc[32 * 33];
    __shared__ float msk[WPL];
    __shared__ float tw[WPL];
    __shared__ float coefA[WPL];
    __shared__ float part[8][33];
    __shared__ float cw[WPL];
    __shared__ float vpart[4][64];
    __shared__ float tg[52];
    __shared__ float mls_s;

    const int tid = threadIdx.x;
    const int line = blockIdx.x >> 3;
    const int h = blockIdx.x & 7;

    if (tid < WPL) msk[tid] = (docs[line * WPL + tid] != 0) ? 1.f : 0.f;
    if (tid >= 64 && tid < 116) tg[tid - 64] = (tid - 64 < DPH) ? w_tgt[h * DPH + tid - 64] : 0.f;

    const float* src = qkvw + ((long)line * NH + h) * HBLK;
    for (int i = tid; i < HBLK / 4; i += 256)
        *(float4*)&sh[i * 4] = *(const float4*)&src[i * 4];
    if (tid < 192) {   // zero d=50,51 pads (GEMM never writes them)
        const int a = tid / 64, rem = tid - a * 64;
        sh[a * 1664 + (rem >> 1) * 52 + 50 + (rem & 1)] = 0.f;
    }
    __syncthreads();

    if (tid == 0) {
        float m = 0.f;
        for (int w = 0; w < WPL; ++w) m = fmaxf(m, msk[w]);
        mls_s = m;
        if (h == 0) mask_l[line] = m;
    }

    // ---- scores: thread (j = tid>>3, kg = tid&7) -> 4 scores
    const int j = tid >> 3, kg = tid & 7;
    float4 qv[13];
    #pragma unroll
    for (int i = 0; i < 13; ++i) qv[i] = *(const float4*)&sh[j * 52 + i * 4];

    float e4[4];
    float m = -1e30f;
    #pragma unroll
    for (int c = 0; c < 4; ++c) {
        const int kk = kg * 4 + c;
        const float* kr = &sh[1664 + kk * 52];
        float s = 0.f;
        #pragma unroll
        for (int i = 0; i < 13; ++i) {
            const float4 kv = *(const float4*)&kr[i * 4];
            s += qv[i].x * kv.x + qv[i].y * kv.y + qv[i].z * kv.z + qv[i].w * kv.w;
        }
        s = s / SCALE - 1e7f * (1.f - msk[kk]);
        e4[c] = s;
        m = fmaxf(m, s);
    }
    // 8-lane row reduce (lanes j*8..j*8+7 consecutive within a wave)
    m = fmaxf(m, __shfl_xor(m, 1));
    m = fmaxf(m, __shfl_xor(m, 2));
    m = fmaxf(m, __shfl_xor(m, 4));
    float rsum = 0.f;
    #pragma unroll
    for (int c = 0; c < 4; ++c) { e4[c] = expf(e4[c] - m); rsum += e4[c]; }
    rsum += __shfl_xor(rsum, 1);
    rsum += __shfl_xor(rsum, 2);
    rsum += __shfl_xor(rsum, 4);
    #pragma unroll
    for (int c = 0; c < 4; ++c) sc[j * 33 + kg * 4 + c] = e4[c];

    // ---- target softmax (wave-0 lanes 0..31)
    if (tid < WPL) {
        const float* kr = &sh[1664 + tid * 52];
        float s = 0.f;
        #pragma unroll
        for (int i = 0; i < 25; ++i)
            s += tg[2 * i] * kr[2 * i] + tg[2 * i + 1] * kr[2 * i + 1];
        s = s / SCALE - 1e7f * (1.f - msk[tid]);
        float tm = s;
        #pragma unroll
        for (int off = 16; off >= 1; off >>= 1) tm = fmaxf(tm, __shfl_xor(tm, off, 32));
        const float te = expf(s - tm);
        float tsum = te;
        #pragma unroll
        for (int off = 16; off >= 1; off >>= 1) tsum += __shfl_xor(tsum, off, 32);
        tw[tid] = te / tsum;
    }
    __syncthreads();

    // ---- coefA[j] = tw[j]*msk[j]/rowsum_j
    if (kg == 0) coefA[j] = tw[j] * msk[j] / rsum;
    __syncthreads();

    // ---- cw partials: thread (k = tid&31, jg = tid>>5) sums 4 rows
    {
        const int k = tid & 31, jg = tid >> 5;
        float cv = 0.f;
        #pragma unroll
        for (int t = 0; t < 4; ++t) {
            const int jj = jg * 4 + t;
            cv += coefA[jj] * sc[jj * 33 + k];
        }
        part[jg][k] = cv;
    }
    __syncthreads();
    if (tid < WPL) {
        float cv = 0.f;
        #pragma unroll
        for (int g = 0; g < 8; ++g) cv += part[g][tid];
        cw[tid] = cv;
    }
    __syncthreads();

    // ---- out: thread (d = tid&63, kh = tid>>6) sums 8 k's
    {
        const int d = tid & 63, kh = tid >> 6;
        float acc = 0.f;
        if (d < 52) {
            #pragma unroll
            for (int t = 0; t < 8; ++t) {
                const int k = kh * 8 + t;
                acc += cw[k] * sh[3328 + k * 52 + d];
            }
        }
        vpart[kh][d] = acc;
    }
    __syncthreads();
    if (tid < DPH) {
        const float o = vpart[0][tid] + vpart[1][tid] + vpart[2][tid] + vpart[3][tid];
        line_e[(long)line * AD + h * DPH + tid] = o * mls_s;
    }
}

// ===========================================================================
// line_attn2: fully-parallel line attention + doc target attention.
// Block per (doc, h), 256 threads.  Element (doc,h,l,d) of Q at
// Q + doc*DS + h*HS + l*LS + d (same for K,V).
// ===========================================================================
__launch_bounds__(256)
__global__ void line_attn2(const float* __restrict__ Q, const float* __restrict__ Kp,
                           const float* __restrict__ Vp,
                           long DS, long HS, long LS,
                           const float* __restrict__ l_tgt, const float* __restrict__ mask_l,
                           float* __restrict__ doc_e)
{
    __shared__ float kl[LPD * 52];     // 26624 B
    __shared__ float sc[64 * 130];     // 33280 B
    __shared__ float ml[LPD];
    __shared__ float tw[LPD];
    __shared__ float cw[LPD];
    __shared__ float coefA[64];
    __shared__ float pm[4 * 64];
    __shared__ float ps[4 * 64];
    __shared__ float tg[52];
    __shared__ float rr[2];
    __shared__ float vpart[2][64];

    const int tid = threadIdx.x;
    const int doc = blockIdx.x >> 3;
    const int h = blockIdx.x & 7;
    const float* qbase = Q + doc * DS + h * HS;
    const float* kbase = Kp + doc * DS + h * HS;
    const float* vbase = Vp + doc * DS + h * HS;

    if (tid < LPD) { ml[tid] = mask_l[doc * LPD + tid]; cw[tid] = 0.f; }
    if (tid < 52) tg[tid] = (tid < DPH) ? l_tgt[h * DPH + tid] : 0.f;
    for (int idx = tid; idx < LPD * 52; idx += 256) {
        const int r = idx / 52, d = idx - r * 52;
        kl[idx] = (d < DPH) ? kbase[(long)r * LS + d] : 0.f;
    }
    __syncthreads();

    if (tid < LPD) {
        const float* kr = &kl[tid * 52];
        float s = 0.f;
        #pragma unroll
        for (int i = 0; i < 25; ++i)
            s += tg[2 * i] * kr[2 * i] + tg[2 * i + 1] * kr[2 * i + 1];
        tw[tid] = s / SCALE - 1e7f * (1.f - ml[tid]);   // raw ts
    }
    __syncthreads();
    if (tid < 64) {
        float a = fmaxf(tw[tid], tw[64 + tid]);
        #pragma unroll
        for (int off = 32; off >= 1; off >>= 1) a = fmaxf(a, __shfl_xor(a, off));
        if (tid == 0) rr[0] = a;
    }
    __syncthreads();
    if (tid < 64) {
        const float tm2 = rr[0];
        float a = expf(tw[tid] - tm2) + expf(tw[64 + tid] - tm2);
        #pragma unroll
        for (int off = 32; off >= 1; off >>= 1) a += __shfl_xor(a, off);
        if (tid == 0) rr[1] = a;
    }
    __syncthreads();
    if (tid < LPD) tw[tid] = expf(tw[tid] - rr[0]) / rr[1];   // final tw
    __syncthreads();

    const int j2 = tid & 63;
    const int kq = tid >> 6;          // 0..3, k range [kq*32, kq*32+32)

    for (int g = 0; g < 2; ++g) {
        const int j = g * 64 + j2;
        float2 qv[25];
        #pragma unroll
        for (int i = 0; i < 25; ++i)
            qv[i] = *(const float2*)(qbase + (long)j * LS + 2 * i);

        float m = -1e30f;
        for (int c = 0; c < 32; ++c) {
            const int k = kq * 32 + c;
            const float* kr = &kl[k * 52];
            float s = 0.f;
            #pragma unroll
            for (int i = 0; i < 25; ++i)
                s += qv[i].x * kr[2 * i] + qv[i].y * kr[2 * i + 1];
            s = s / SCALE - 1e7f * (1.f - ml[k]);
            sc[j2 * 130 + k] = s;
            m = fmaxf(m, s);
        }
        pm[kq * 64 + j2] = m;
        __syncthreads();
        const float rowm = fmaxf(fmaxf(pm[j2], pm[64 + j2]),
                                 fmaxf(pm[128 + j2], pm[192 + j2]));
        float sum = 0.f;
        for (int c = 0; c < 32; ++c) {
            const int k = kq * 32 + c;
            const float e = expf(sc[j2 * 130 + k] - rowm);
            sc[j2 * 130 + k] = e;
            sum += e;
        }
        ps[kq * 64 + j2] = sum;
        __syncthreads();
        if (kq == 0) {
            const float rs = ps[j2] + ps[64 + j2] + ps[128 + j2] + ps[192 + j2];
            coefA[j2] = tw[j] * ml[j] / rs;
        }
        __syncthreads();
        if (tid < LPD) {
            float cv = 0.f;
            for (int jj = 0; jj < 64; ++jj)
                cv += coefA[jj] * sc[jj * 130 + tid];
            cw[tid] += cv;
        }
        __syncthreads();
    }

    const int d = tid & 63;
    const int half = (tid >> 6) & 1;
    if (tid < 128 && d < DPH) {
        float acc = 0.f;
        for (int k = half * 64; k < half * 64 + 64; ++k)
            acc += cw[k] * vbase[(long)k * LS + d];
        vpart[half][d] = acc;
    }
    __syncthreads();
    if (tid < DPH)
        doc_e[doc * AD + h * DPH + tid] = vpart[0][tid] + vpart[1][tid];
}

// ===========================================================================
// FALLBACK kernels (fp32 path)
// ===========================================================================
__launch_bounds__(256)
__global__ void word_attn(const float* __restrict__ qkv, const int* __restrict__ docs,
                          const float* __restrict__ w_tgt,
                          float* __restrict__ line_e, float* __restrict__ mask_l)
{
    __shared__ float qs[WPL * QKV_S];
    __shared__ float ks[WPL * QKV_S];
    __shared__ float vs[WPL * QKV_S];
    __shared__ float sc[WPL * SC_S];
    __shared__ float ts[WPL], tw[WPL], cw[WPL], msk[WPL];
    __shared__ float mls;

    const int tid = threadIdx.x;
    const int line = blockIdx.x;

    if (tid < WPL) msk[tid] = (docs[line * WPL + tid] != 0) ? 1.f : 0.f;
    __syncthreads();
    if (tid == 0) {
        float ml = 0.f;
        for (int w = 0; w < WPL; ++w) ml = fmaxf(ml, msk[w]);
        mls = ml;
        mask_l[line] = ml;
    }
    for (int h = 0; h < NH; ++h) {
        for (int idx = tid; idx < WPL * DPH; idx += 256) {
            const int r = idx / DPH, d = idx - r * DPH;
            const size_t base = (size_t)(line * WPL + r) * NCOLS + h * DPH + d;
            qs[r * QKV_S + d] = qkv[base];
            ks[r * QKV_S + d] = qkv[base + 400];
            vs[r * QKV_S + d] = qkv[base + 800];
        }
        __syncthreads();
        {
            const int j = tid >> 3, kg = tid & 7;
            #pragma unroll
            for (int c = 0; c < 4; ++c) {
                const int kk = kg * 4 + c;
                float s = 0.f;
                for (int dd = 0; dd < DPH; ++dd)
                    s += qs[j * QKV_S + dd] * ks[kk * QKV_S + dd];
                sc[j * SC_S + kk] = s / SCALE - 1e7f * (1.f - msk[kk]);
            }
        }
        if (tid < WPL) {
            float s = 0.f;
            for (int dd = 0; dd < DPH; ++dd)
                s += w_tgt[h * DPH + dd] * ks[tid * QKV_S + dd];
            ts[tid] = s / SCALE - 1e7f * (1.f - msk[tid]);
        }
        __syncthreads();
        if (tid < WPL) {
            const int j = tid;
            float m = -1e30f;
            for (int kk = 0; kk < WPL; ++kk) m = fmaxf(m, sc[j * SC_S + kk]);
            float sum = 0.f;
            for (int kk = 0; kk < WPL; ++kk) {
                const float e = expf(sc[j * SC_S + kk] - m);
                sc[j * SC_S + kk] = e;
                sum += e;
            }
            const float inv = 1.f / sum;
            for (int kk = 0; kk < WPL; ++kk) sc[j * SC_S + kk] *= inv;
        } else if (tid == WPL) {
            float m = -1e30f;
            for (int jj = 0; jj < WPL; ++jj) m = fmaxf(m, ts[jj]);
            float sum = 0.f;
            for (int jj = 0; jj < WPL; ++jj) { const float e = expf(ts[jj] - m); tw[jj] = e; sum += e; }
            const float inv = 1.f / sum;
            for (int jj = 0; jj < WPL; ++jj) tw[jj] *= inv;
        }
        __syncthreads();
        if (tid < WPL) {
            const int kk = tid;
            float c = 0.f;
            for (int jj = 0; jj < WPL; ++jj) c += tw[jj] * msk[jj] * sc[jj * SC_S + kk];
            cw[kk] = c;
        }
        __syncthreads();
        if (tid < DPH) {
            float acc = 0.f;
            for (int kk = 0; kk < WPL; ++kk) acc += cw[kk] * vs[kk * QKV_S + tid];
            line_e[line * AD + h * DPH + tid] = acc * mls;
        }
        __syncthreads();
    }
}

__launch_bounds__(256, 2)
__global__ void gemm_qkv(const float* __restrict__ Asrc,
                         const int* __restrict__ docs,
                         const float* __restrict__ emb,
                         const float* __restrict__ W0, const float* __restrict__ W1,
                         const float* __restrict__ W2,
                         const float* __restrict__ B0, const float* __restrict__ B1,
                         const float* __restrict__ B2,
                         float* __restrict__ C, int M, int K)
{
    __shared__ __align__(16) float As[32][132];
    __shared__ __align__(16) float Bs[32][132];

    const int tid = threadIdx.x;
    const int row0 = blockIdx.x * 128;
    const int n0 = blockIdx.y * 128;
    const int tc = tid & 15, tr = tid >> 4;

    float acc[2][2][4][4];
    #pragma unroll
    for (int a = 0; a < 2; ++a)
        #pragma unroll
        for (int b = 0; b < 2; ++b)
            #pragma unroll
            for (int c = 0; c < 4; ++c)
                #pragma unroll
                for (int d = 0; d < 4; ++d) acc[a][b][c][d] = 0.f;

    const int ma = tid & 127;
    const int kq = tid >> 7;
    const float* arow;
    if (docs) arow = emb + (size_t)docs[row0 + ma] * EMBD;
    else      arow = Asrc + (size_t)(row0 + ma) * K;

    const int gcol = n0 + ma;
    const int p = gcol / 400;
    const int ccol = gcol - p * 400;
    const float* Wp = (p == 0) ? W0 : (p == 1) ? W1 : W2;
    const bool colv = gcol < NCOLS;

    const int nk = (K + 31) >> 5;
    for (int ck = 0; ck < nk; ++ck) {
        const int k0 = ck * 32;
        #pragma unroll
        for (int f = 0; f < 4; ++f) {
            const int kl = kq * 16 + f * 4;
            const int kg = k0 + kl;
            float4 v = make_float4(0.f, 0.f, 0.f, 0.f);
            if (kg < K) v = *(const float4*)(arow + kg);
            As[kl + 0][ma] = v.x;
            As[kl + 1][ma] = v.y;
            As[kl + 2][ma] = v.z;
            As[kl + 3][ma] = v.w;
        }
        #pragma unroll
        for (int i = 0; i < 16; ++i) {
            const int kl = kq * 16 + i;
            const int kg = k0 + kl;
            float v = 0.f;
            if (colv && kg < K) v = Wp[(size_t)kg * 400 + ccol];
            Bs[kl][ma] = v;
        }
        __syncthreads();

        #pragma unroll 8
        for (int k = 0; k < 32; ++k) {
            const float4 a0 = *(const float4*)&As[k][tr * 4];
            const float4 a1 = *(const float4*)&As[k][64 + tr * 4];
            const float4 b0 = *(const float4*)&Bs[k][tc * 4];
            const float4 b1 = *(const float4*)&Bs[k][64 + tc * 4];
            const float ar[2][4] = {{a0.x, a0.y, a0.z, a0.w}, {a1.x, a1.y, a1.z, a1.w}};
            const float br[2][4] = {{b0.x, b0.y, b0.z, b0.w}, {b1.x, b1.y, b1.z, b1.w}};
            #pragma unroll
            for (int im = 0; im < 2; ++im)
                #pragma unroll
                for (int in_ = 0; in_ < 2; ++in_)
                    #pragma unroll
                    for (int rr = 0; rr < 4; ++rr)
                        #pragma unroll
                        for (int cc = 0; cc < 4; ++cc)
                            acc[im][in_][rr][cc] += ar[im][rr] * br[in_][cc];
        }
        __syncthreads();
    }

    #pragma unroll
    for (int in_ = 0; in_ < 2; ++in_) {
        const int ncol = n0 + in_ * 64 + tc * 4;
        if (ncol >= NCOLS) continue;
        const int pj = ncol / 400;
        const int cj = ncol - pj * 400;
        const float* Bp = (pj == 0) ? B0 : (pj == 1) ? B1 : B2;
        const float4 bv = *(const float4*)(Bp + cj);
        #pragma unroll
        for (int im = 0; im < 2; ++im) {
            #pragma unroll
            for (int rr = 0; rr < 4; ++rr) {
                const int row = row0 + im * 64 + tr * 4 + rr;
                float4 o;
                o.x = elu(acc[im][in_][rr][0] + bv.x);
                o.y = elu(acc[im][in_][rr][1] + bv.y);
                o.z = elu(acc[im][in_][rr][2] + bv.z);
                o.w = elu(acc[im][in_][rr][3] + bv.w);
                *(float4*)(C + (size_t)row * NCOLS + ncol) = o;
            }
        }
    }
}

__global__ void logits_kernel(const float* __restrict__ doc_e,
                              const float* __restrict__ fc1_w, const float* __restrict__ fc1_b,
                              const float* __restrict__ fc2_w, const float* __restrict__ fc2_b,
                              float* __restrict__ out)
{
    int o = blockIdx.x * blockDim.x + threadIdx.x;
    if (o >= BATCH * 582) return;
    int b = o / 582, jj = o - b * 582;
    const float* de = doc_e + b * AD;
    float acc;
    if (jj < 70) {
        acc = fc1_b[jj];
        for (int k = 0; k < AD; ++k) acc += de[k] * fc1_w[k * 70 + jj];
    } else {
        int j2 = jj - 70;
        acc = fc2_b[j2];
        for (int k = 0; k < AD; ++k) acc += de[k] * fc2_w[k * 512 + j2];
    }
    out[o] = acc;
}

// ---------------------------------------------------------------------------
extern "C" void kernel_launch(void* const* d_in, const int* in_sizes, int n_in,
                              void* d_out, int out_size, void* d_ws, size_t ws_size,
                              hipStream_t stream) {
    const int*   docs  = (const int*)  d_in[0];
    const float* emb   = (const float*)d_in[1];
    const float* wq_w  = (const float*)d_in[2];
    const float* wq_b  = (const float*)d_in[3];
    const float* wk_w  = (const float*)d_in[4];
    const float* wk_b  = (const float*)d_in[5];
    const float* wv_w  = (const float*)d_in[6];
    const float* wv_b  = (const float*)d_in[7];
    const float* w_tgt = (const float*)d_in[8];
    const float* lq_w  = (const float*)d_in[9];
    const float* lq_b  = (const float*)d_in[10];
    const float* lk_w  = (const float*)d_in[11];
    const float* lk_b  = (const float*)d_in[12];
    const float* lv_w  = (const float*)d_in[13];
    const float* lv_b  = (const float*)d_in[14];
    const float* l_tgt = (const float*)d_in[15];
    const float* fc1_w = (const float*)d_in[16];
    const float* fc1_b = (const float*)d_in[17];
    const float* fc2_w = (const float*)d_in[18];
    const float* fc2_b = (const float*)d_in[19];
    float* out = (float*)d_out;
    float* ws = (float*)d_ws;

    const long O_LINE_E = 0;
    const long O_MASK_L = 819200;
    const long O_DOC_E  = 821248;
    const long O_BIAS_W = 827648;
    const long O_BIAS_L = 828928;
    const long O_EMB_H  = 830208;
    const long O_EMB_L  = 5630208;
    const long O_WTW_H  = 10430208;
    const long O_WTW_L  = 10635008;
    const long O_WTL_H  = 10839808;
    const long O_WTL_L  = 11106048;
    const long O_LE_H   = 11372288;
    const long O_LE_L   = 11798272;
    const long O_R      = 12224256;

    const long LINE_QKV_FL = (long)NLINES * NCOLS;    // 2457600
    long ws_fl = (long)(ws_size / 4);
    long Rcap = ws_fl - O_R;

    if (Rcap >= LINE_QKV_FL) {
        // ================= MFMA fast path =================
        float* line_e = ws + O_LINE_E;
        float* mask_l = ws + O_MASK_L;
        float* doc_e  = ws + O_DOC_E;
        float* bias_w = ws + O_BIAS_W;
        float* bias_l = ws + O_BIAS_L;
        bf16* embh = (bf16*)(ws + O_EMB_H);
        bf16* embl = (bf16*)(ws + O_EMB_L);
        bf16* wtwh = (bf16*)(ws + O_WTW_H);
        bf16* wtwl = (bf16*)(ws + O_WTW_L);
        bf16* wtlh = (bf16*)(ws + O_WTL_H);
        bf16* wtll = (bf16*)(ws + O_WTL_L);
        bf16* leh  = (bf16*)(ws + O_LE_H);
        bf16* lel  = (bf16*)(ws + O_LE_L);
        float* R   = ws + O_R;

        split_rows<<<(30000L * 320 + 255) / 256, 256, 0, stream>>>(emb, embh, embl, 30000, 300, 320);
        split_wt<<<((long)NPAD * 320 + 255) / 256, 256, 0, stream>>>(wq_w, wk_w, wv_w,
                                                                     wq_b, wk_b, wv_b,
                                                                     wtwh, wtwl, bias_w, 300, 320);
        split_wt<<<((long)NPAD * 416 + 255) / 256, 256, 0, stream>>>(lq_w, lk_w, lv_w,
                                                                     lq_b, lk_b, lv_b,
                                                                     wtlh, wtll, bias_l, 400, 416);

        // chunk = 512 lines: qkv chunk (82 MB) + emb tables (38 MB) stay
        // L3-resident -> gemm writes & attn reads absorbed by Infinity Cache
        long maxl = Rcap / WLINE_FL;
        if (maxl > 512) maxl = 512;
        long chunk = (maxl / 4) * 4;
        if (chunk < 4) chunk = 4;
        for (long c0 = 0; c0 < NLINES; c0 += chunk) {
            long cl = NLINES - c0 < chunk ? NLINES - c0 : chunk;   // multiple of 4
            dim3 g1(10, (unsigned)((cl * 32) / 128));   // x=col (fastest), y=row
            mfma_gemm<<<g1, 256, 0, stream>>>(embh, embl, docs + c0 * WPL,
                                              wtwh, wtwl, bias_w, R, 320, 1);
            word_attn4<<<(unsigned)(cl * NH), 256, 0, stream>>>(R, docs + c0 * WPL, w_tgt,
                                                                line_e + c0 * AD, mask_l + c0);
        }

        split_rows<<<((long)NLINES * 416 + 255) / 256, 256, 0, stream>>>(line_e, leh, lel,
                                                                         NLINES, 400, 416);
        dim3 g2(10, NLINES / 128);
        mfma_gemm<<<g2, 256, 0, stream>>>(leh, lel, nullptr, wtlh, wtll, bias_l, R, 416, 0);
        line_attn2<<<BATCH * NH, 256, 0, stream>>>(R, R + 400, R + 800,
                                                   (long)LPD * NCOLS, (long)DPH, (long)NCOLS,
                                                   l_tgt, mask_l, doc_e);
        logits_kernel<<<(BATCH * 582 + 255) / 256, 256, 0, stream>>>(doc_e, fc1_w, fc1_b,
                                                                     fc2_w, fc2_b, out);
    } else {
        // ================= fp32 fallback (round-3 proven sequence) ==========
        const long F_FIXED = 827648;
        const long PER_LINE_FL = (long)WPL * NCOLS;
        float* line_e = ws;
        float* mask_l = ws + 819200;
        float* doc_e  = ws + 821248;
        float* R      = ws + F_FIXED;
        long Rcap2 = ws_fl - F_FIXED;

        long maxl = Rcap2 / PER_LINE_FL;
        if (maxl > NLINES) maxl = NLINES;
        long maxl4 = (maxl / 4) * 4;
        int nc = (int)((NLINES + maxl4 - 1) / maxl4);
        int chunk = (int)((NLINES + nc - 1) / nc);
        chunk = ((chunk + 3) / 4) * 4;

        for (int c0 = 0; c0 < NLINES; c0 += chunk) {
            int cl = NLINES - c0 < chunk ? NLINES - c0 : chunk;
            dim3 g1((cl * 32) / 128, 10);
            gemm_qkv<<<g1, 256, 0, stream>>>(nullptr, docs + (size_t)c0 * WPL, emb,
                                             wq_w, wk_w, wv_w, wq_b, wk_b, wv_b,
                                             R, cl * 32, EMBD);
            word_attn<<<cl, 256, 0, stream>>>(R, docs + (size_t)c0 * WPL, w_tgt,
                                              line_e + (size_t)c0 * AD, mask_l + c0);
        }
        dim3 g2(16, 10);
        gemm_qkv<<<g2, 256, 0, stream>>>(line_e, nullptr, emb,
                                         lq_w, lk_w, lv_w, lq_b, lk_b, lv_b,
                                         R, NLINES, AD);
        line_attn2<<<BATCH * NH, 256, 0, stream>>>(R, R + 400, R + 800,
                                                   (long)LPD * NCOLS, (long)DPH, (long)NCOLS,
                                                   l_tgt, mask_l, doc_e);
        logits_kernel<<<(BATCH * 582 + 255) / 256, 256, 0, stream>>>(doc_e, fc1_w, fc1_b,
                                                                     fc2_w, fc2_b, out);
    }
}

// Round 12
// 664.147 us; speedup vs baseline: 1.4599x; 1.0909x over previous
//
#include <hip/hip_runtime.h>
#include <math.h>

#define NLINES 2048
#define WPL 32
#define EMBD 300
#define AD 400
#define NH 8
#define DPH 50
#define QKV_S 52
#define SC_S 36
#define BATCH 16
#define LPD 128
#define NCOLS 1200     // 3 proj * 400
#define NPAD 1280      // padded col count for Wt tables
#define WLINE_FL 39936 // per-line floats in word layout: 8*3*32*52
#define HBLK 4992      // per-(line,head) floats: 3*32*52

typedef __bf16 bf16;
typedef bf16  v8bf __attribute__((ext_vector_type(8)));
typedef float v4f  __attribute__((ext_vector_type(4)));

__device__ __forceinline__ float elu(float x) {
    return x > 0.f ? x : expm1f(x);
}
// fast elu: hardware exp; |abs err| ~2^-24 near 0 (cancellation is benign in abs terms)
__device__ __forceinline__ float elu_fast(float x) {
    return x > 0.f ? x : (__expf(x) - 1.f);
}

#define SCALE 7.0710678118654755f   // sqrt(50)

// ===========================================================================
// Split helpers: fp32 -> (hi, lo) bf16 pair.  x ~= hi + lo, rel err ~2^-18.
// ===========================================================================
__global__ void split_rows(const float* __restrict__ src,
                           bf16* __restrict__ hi, bf16* __restrict__ lo,
                           int rows, int K, int K2)
{
    long idx = (long)blockIdx.x * 256 + threadIdx.x;
    if (idx >= (long)rows * K2) return;
    int r = (int)(idx / K2), k = (int)(idx - (long)r * K2);
    float x = (k < K) ? src[(long)r * K + k] : 0.f;
    bf16 h = (bf16)x;
    float hf = (float)h;
    bf16 l = (bf16)(x - hf);
    hi[idx] = h; lo[idx] = l;
}

__global__ void split_wt(const float* __restrict__ W0, const float* __restrict__ W1,
                         const float* __restrict__ W2,
                         const float* __restrict__ B0, const float* __restrict__ B1,
                         const float* __restrict__ B2,
                         bf16* __restrict__ hi, bf16* __restrict__ lo,
                         float* __restrict__ biasCat, int K, int K2)
{
    long idx = (long)blockIdx.x * 256 + threadIdx.x;
    if (idx >= (long)NPAD * K2) return;
    int n = (int)(idx / K2), k = (int)(idx - (long)n * K2);
    float x = 0.f;
    if (k < K && n < NCOLS) {
        int p = n / 400, c = n - p * 400;
        const float* W = (p == 0) ? W0 : (p == 1) ? W1 : W2;
        x = W[(long)k * 400 + c];
    }
    bf16 h = (bf16)x;
    float hf = (float)h;
    bf16 l = (bf16)(x - hf);
    hi[idx] = h; lo[idx] = l;
    if (k == 0) {
        float b = 0.f;
        if (n < NCOLS) {
            int p = n / 400, c = n - p * 400;
            const float* Bp = (p == 0) ? B0 : (p == 1) ? B1 : B2;
            b = Bp[c];
        }
        biasCat[n] = b;
    }
}

// ===========================================================================
// mfma_gemm: C = elu( A @ Wt^T + biasCat ), split-bf16 3-product, staged LDS.
// GRID: x = col-block (fastest, shares A rows), y = row-block.
// word_layout=1: C[(line*8+h)*3+p][32][52]; word_layout=0: row-major [row][1200].
// ===========================================================================
__launch_bounds__(256)
__global__ void mfma_gemm(const bf16* __restrict__ Ah_t, const bf16* __restrict__ Al_t,
                          const int* __restrict__ docs,
                          const bf16* __restrict__ Bh_t, const bf16* __restrict__ Bl_t,
                          const float* __restrict__ biasCat,
                          float* __restrict__ C, int K2, int word_layout)
{
    __shared__ __align__(16) bf16 Ah[4096];
    __shared__ __align__(16) bf16 Al[4096];
    __shared__ __align__(16) bf16 Bh[4096];
    __shared__ __align__(16) bf16 Bl[4096];
    __shared__ int tok[128];

    const int tid = threadIdx.x;
    const int row0 = blockIdx.y * 128;     // y = row-block
    const int n0 = blockIdx.x * 128;       // x = col-block (fastest)

    if (tid < 128) tok[tid] = docs ? docs[row0 + tid] : (row0 + tid);
    __syncthreads();

    const int qa = tid >> 7;
    const int sm = tid & 127;
    const long aoff = (long)tok[sm] * K2;
    const long boff = (long)(n0 + sm) * K2;

    const int wv = tid >> 6, lane = tid & 63;
    const int quad = lane >> 4, r16 = lane & 15;
    const int wm0 = (wv >> 1) * 64, wn0 = (wv & 1) * 64;

    v4f acc[4][4];
    #pragma unroll
    for (int a = 0; a < 4; ++a)
        #pragma unroll
        for (int b = 0; b < 4; ++b) acc[a][b] = (v4f)0.f;

    const int nk = K2 >> 5;
    // prefetch tile 0
    v8bf pa0 = *(const v8bf*)(Ah_t + aoff + qa * 8);
    v8bf pa1 = *(const v8bf*)(Ah_t + aoff + (qa + 2) * 8);
    v8bf pl0 = *(const v8bf*)(Al_t + aoff + qa * 8);
    v8bf pl1 = *(const v8bf*)(Al_t + aoff + (qa + 2) * 8);
    v8bf pb0 = *(const v8bf*)(Bh_t + boff + qa * 8);
    v8bf pb1 = *(const v8bf*)(Bh_t + boff + (qa + 2) * 8);
    v8bf pc0 = *(const v8bf*)(Bl_t + boff + qa * 8);
    v8bf pc1 = *(const v8bf*)(Bl_t + boff + (qa + 2) * 8);

    for (int kt = 0; kt < nk; ++kt) {
        *(v8bf*)&Ah[tid * 8]         = pa0;
        *(v8bf*)&Ah[(256 + tid) * 8] = pa1;
        *(v8bf*)&Al[tid * 8]         = pl0;
        *(v8bf*)&Al[(256 + tid) * 8] = pl1;
        *(v8bf*)&Bh[tid * 8]         = pb0;
        *(v8bf*)&Bh[(256 + tid) * 8] = pb1;
        *(v8bf*)&Bl[tid * 8]         = pc0;
        *(v8bf*)&Bl[(256 + tid) * 8] = pc1;
        __syncthreads();

        if (kt + 1 < nk) {   // next tile's loads fly during MFMA
            const int k1 = (kt + 1) * 32;
            pa0 = *(const v8bf*)(Ah_t + aoff + k1 + qa * 8);
            pa1 = *(const v8bf*)(Ah_t + aoff + k1 + (qa + 2) * 8);
            pl0 = *(const v8bf*)(Al_t + aoff + k1 + qa * 8);
            pl1 = *(const v8bf*)(Al_t + aoff + k1 + (qa + 2) * 8);
            pb0 = *(const v8bf*)(Bh_t + boff + k1 + qa * 8);
            pb1 = *(const v8bf*)(Bh_t + boff + k1 + (qa + 2) * 8);
            pc0 = *(const v8bf*)(Bl_t + boff + k1 + qa * 8);
            pc1 = *(const v8bf*)(Bl_t + boff + k1 + (qa + 2) * 8);
        }

        v8bf fa_h[4], fa_l[4], fb_h[4], fb_l[4];
        #pragma unroll
        for (int t = 0; t < 4; ++t) {
            const int ea = quad * 128 + wm0 + t * 16 + r16;
            fa_h[t] = *(const v8bf*)&Ah[ea * 8];
            fa_l[t] = *(const v8bf*)&Al[ea * 8];
            const int eb = quad * 128 + wn0 + t * 16 + r16;
            fb_h[t] = *(const v8bf*)&Bh[eb * 8];
            fb_l[t] = *(const v8bf*)&Bl[eb * 8];
        }

        // grouped by product: same-acc MFMAs are 16 issues apart (no dep chain)
        #pragma unroll
        for (int mt = 0; mt < 4; ++mt)
            #pragma unroll
            for (int nt = 0; nt < 4; ++nt)
                acc[mt][nt] = __builtin_amdgcn_mfma_f32_16x16x32_bf16(fa_h[mt], fb_h[nt], acc[mt][nt], 0, 0, 0);
        #pragma unroll
        for (int mt = 0; mt < 4; ++mt)
            #pragma unroll
            for (int nt = 0; nt < 4; ++nt)
                acc[mt][nt] = __builtin_amdgcn_mfma_f32_16x16x32_bf16(fa_h[mt], fb_l[nt], acc[mt][nt], 0, 0, 0);
        #pragma unroll
        for (int mt = 0; mt < 4; ++mt)
            #pragma unroll
            for (int nt = 0; nt < 4; ++nt)
                acc[mt][nt] = __builtin_amdgcn_mfma_f32_16x16x32_bf16(fa_l[mt], fb_h[nt], acc[mt][nt], 0, 0, 0);
        __syncthreads();
    }

    // ---- epilogue: D row = quad*4+reg, col = lane&15
    if (word_layout) {
        #pragma unroll
        for (int nt = 0; nt < 4; ++nt) {
            const int col = n0 + wn0 + nt * 16 + r16;
            if (col >= NCOLS) continue;
            const float bv = biasCat[col];
            const int p = col / 400;
            const int rem = col - p * 400;
            const int hh = rem / 50;
            const int d  = rem - hh * 50;
            #pragma unroll
            for (int mt = 0; mt < 4; ++mt) {
                const int rbase = row0 + wm0 + mt * 16 + quad * 4;
                #pragma unroll
                for (int rg = 0; rg < 4; ++rg) {
                    const int row = rbase + rg;
                    const int ln = row >> 5, r = row & 31;
                    const float x = acc[mt][nt][rg] + bv;
                    C[(((long)ln * NH + hh) * 3 + p) * 1664 + r * 52 + d] = elu_fast(x);
                }
            }
        }
    } else {
        #pragma unroll
        for (int nt = 0; nt < 4; ++nt) {
            const int col = n0 + wn0 + nt * 16 + r16;
            if (col >= NCOLS) continue;
            const float bv = biasCat[col];
            #pragma unroll
            for (int mt = 0; mt < 4; ++mt) {
                const int rbase = row0 + wm0 + mt * 16 + quad * 4;
                #pragma unroll
                for (int rg = 0; rg < 4; ++rg) {
                    const float x = acc[mt][nt][rg] + bv;
                    C[(long)(rbase + rg) * NCOLS + col] = elu_fast(x);
                }
            }
        }
    }
}

// ===========================================================================
// word_attn4: one 256-thread BLOCK per (line, head).  qkvw [line][h][3][32][52].
// ===========================================================================
__launch_bounds__(256)
__global__ void word_attn4(const float* __restrict__ qkvw, const int* __restrict__ docs,
                           const float* __restrict__ w_tgt,
                           float* __restrict__ line_e, float* __restrict__ mask_l)
{
    __shared__ __align__(16) float sh[HBLK];   // q[0..1663] k[1664..] v[3328..]
    __shared__ float sc[32 * 33];
    __shared__ float msk[WPL];
    __shared__ float tw[WPL];
    __shared__ float coefA[WPL];
    __shared__ float part[8][33];
    __shared__ float cw[WPL];
    __shared__ float vpart[4][64];
    __shared__ float tg[52];
    __shared__ float mls_s;

    const int tid = threadIdx.x;
    const int line = blockIdx.x >> 3;
    const int h = blockIdx.x & 7;

    if (tid < WPL) msk[tid] = (docs[line * WPL + tid] != 0) ? 1.f : 0.f;
    if (tid >= 64 && tid < 116) tg[tid - 64] = (tid - 64 < DPH) ? w_tgt[h * DPH + tid - 64] : 0.f;

    const float* src = qkvw + ((long)line * NH + h) * HBLK;
    for (int i = tid; i < HBLK / 4; i += 256)
        *(float4*)&sh[i * 4] = *(const float4*)&src[i * 4];
    if (tid < 192) {   // zero d=50,51 pads (GEMM never writes them)
        const int a = tid / 64, rem = tid - a * 64;
        sh[a * 1664 + (rem >> 1) * 52 + 50 + (rem & 1)] = 0.f;
    }
    __syncthreads();

    if (tid == 0) {
        float m = 0.f;
        for (int w = 0; w < WPL; ++w) m = fmaxf(m, msk[w]);
        mls_s = m;
        if (h == 0) mask_l[line] = m;
    }

    // ---- scores: thread (j = tid>>3, kg = tid&7) -> 4 scores
    const int j = tid >> 3, kg = tid & 7;
    float4 qv[13];
    #pragma unroll
    for (int i = 0; i < 13; ++i) qv[i] = *(const float4*)&sh[j * 52 + i * 4];

    float e4[4];
    float m = -1e30f;
    #pragma unroll
    for (int c = 0; c < 4; ++c) {
        const int kk = kg * 4 + c;
        const float* kr = &sh[1664 + kk * 52];
        float s = 0.f;
        #pragma unroll
        for (int i = 0; i < 13; ++i) {
            const float4 kv = *(const float4*)&kr[i * 4];
            s += qv[i].x * kv.x + qv[i].y * kv.y + qv[i].z * kv.z + qv[i].w * kv.w;
        }
        s = s / SCALE - 1e7f * (1.f - msk[kk]);
        e4[c] = s;
        m = fmaxf(m, s);
    }
    m = fmaxf(m, __shfl_xor(m, 1));
    m = fmaxf(m, __shfl_xor(m, 2));
    m = fmaxf(m, __shfl_xor(m, 4));
    float rsum = 0.f;
    #pragma unroll
    for (int c = 0; c < 4; ++c) { e4[c] = __expf(e4[c] - m); rsum += e4[c]; }
    rsum += __shfl_xor(rsum, 1);
    rsum += __shfl_xor(rsum, 2);
    rsum += __shfl_xor(rsum, 4);
    #pragma unroll
    for (int c = 0; c < 4; ++c) sc[j * 33 + kg * 4 + c] = e4[c];

    // ---- target softmax (wave-0 lanes 0..31)
    if (tid < WPL) {
        const float* kr = &sh[1664 + tid * 52];
        float s = 0.f;
        #pragma unroll
        for (int i = 0; i < 25; ++i)
            s += tg[2 * i] * kr[2 * i] + tg[2 * i + 1] * kr[2 * i + 1];
        s = s / SCALE - 1e7f * (1.f - msk[tid]);
        float tm = s;
        #pragma unroll
        for (int off = 16; off >= 1; off >>= 1) tm = fmaxf(tm, __shfl_xor(tm, off, 32));
        const float te = __expf(s - tm);
        float tsum = te;
        #pragma unroll
        for (int off = 16; off >= 1; off >>= 1) tsum += __shfl_xor(tsum, off, 32);
        tw[tid] = te / tsum;
    }
    __syncthreads();

    if (kg == 0) coefA[j] = tw[j] * msk[j] / rsum;
    __syncthreads();

    {
        const int k = tid & 31, jg = tid >> 5;
        float cv = 0.f;
        #pragma unroll
        for (int t = 0; t < 4; ++t) {
            const int jj = jg * 4 + t;
            cv += coefA[jj] * sc[jj * 33 + k];
        }
        part[jg][k] = cv;
    }
    __syncthreads();
    if (tid < WPL) {
        float cv = 0.f;
        #pragma unroll
        for (int g = 0; g < 8; ++g) cv += part[g][tid];
        cw[tid] = cv;
    }
    __syncthreads();

    {
        const int d = tid & 63, kh = tid >> 6;
        float acc = 0.f;
        if (d < 52) {
            #pragma unroll
            for (int t = 0; t < 8; ++t) {
                const int k = kh * 8 + t;
                acc += cw[k] * sh[3328 + k * 52 + d];
            }
        }
        vpart[kh][d] = acc;
    }
    __syncthreads();
    if (tid < DPH) {
        const float o = vpart[0][tid] + vpart[1][tid] + vpart[2][tid] + vpart[3][tid];
        line_e[(long)line * AD + h * DPH + tid] = o * mls_s;
    }
}

// ===========================================================================
// line_attn2: fully-parallel line attention + doc target attention.
// ===========================================================================
__launch_bounds__(256)
__global__ void line_attn2(const float* __restrict__ Q, const float* __restrict__ Kp,
                           const float* __restrict__ Vp,
                           long DS, long HS, long LS,
                           const float* __restrict__ l_tgt, const float* __restrict__ mask_l,
                           float* __restrict__ doc_e)
{
    __shared__ float kl[LPD * 52];     // 26624 B
    __shared__ float sc[64 * 130];     // 33280 B
    __shared__ float ml[LPD];
    __shared__ float tw[LPD];
    __shared__ float cw[LPD];
    __shared__ float coefA[64];
    __shared__ float pm[4 * 64];
    __shared__ float ps[4 * 64];
    __shared__ float tg[52];
    __shared__ float rr[2];
    __shared__ float vpart[2][64];

    const int tid = threadIdx.x;
    const int doc = blockIdx.x >> 3;
    const int h = blockIdx.x & 7;
    const float* qbase = Q + doc * DS + h * HS;
    const float* kbase = Kp + doc * DS + h * HS;
    const float* vbase = Vp + doc * DS + h * HS;

    if (tid < LPD) { ml[tid] = mask_l[doc * LPD + tid]; cw[tid] = 0.f; }
    if (tid < 52) tg[tid] = (tid < DPH) ? l_tgt[h * DPH + tid] : 0.f;
    for (int idx = tid; idx < LPD * 52; idx += 256) {
        const int r = idx / 52, d = idx - r * 52;
        kl[idx] = (d < DPH) ? kbase[(long)r * LS + d] : 0.f;
    }
    __syncthreads();

    if (tid < LPD) {
        const float* kr = &kl[tid * 52];
        float s = 0.f;
        #pragma unroll
        for (int i = 0; i < 25; ++i)
            s += tg[2 * i] * kr[2 * i] + tg[2 * i + 1] * kr[2 * i + 1];
        tw[tid] = s / SCALE - 1e7f * (1.f - ml[tid]);   // raw ts
    }
    __syncthreads();
    if (tid < 64) {
        float a = fmaxf(tw[tid], tw[64 + tid]);
        #pragma unroll
        for (int off = 32; off >= 1; off >>= 1) a = fmaxf(a, __shfl_xor(a, off));
        if (tid == 0) rr[0] = a;
    }
    __syncthreads();
    if (tid < 64) {
        const float tm2 = rr[0];
        float a = __expf(tw[tid] - tm2) + __expf(tw[64 + tid] - tm2);
        #pragma unroll
        for (int off = 32; off >= 1; off >>= 1) a += __shfl_xor(a, off);
        if (tid == 0) rr[1] = a;
    }
    __syncthreads();
    if (tid < LPD) tw[tid] = __expf(tw[tid] - rr[0]) / rr[1];   // final tw
    __syncthreads();

    const int j2 = tid & 63;
    const int kq = tid >> 6;          // 0..3, k range [kq*32, kq*32+32)

    for (int g = 0; g < 2; ++g) {
        const int j = g * 64 + j2;
        float2 qv[25];
        #pragma unroll
        for (int i = 0; i < 25; ++i)
            qv[i] = *(const float2*)(qbase + (long)j * LS + 2 * i);

        float m = -1e30f;
        for (int c = 0; c < 32; ++c) {
            const int k = kq * 32 + c;
            const float* kr = &kl[k * 52];
            float s = 0.f;
            #pragma unroll
            for (int i = 0; i < 25; ++i)
                s += qv[i].x * kr[2 * i] + qv[i].y * kr[2 * i + 1];
            s = s / SCALE - 1e7f * (1.f - ml[k]);
            sc[j2 * 130 + k] = s;
            m = fmaxf(m, s);
        }
        pm[kq * 64 + j2] = m;
        __syncthreads();
        const float rowm = fmaxf(fmaxf(pm[j2], pm[64 + j2]),
                                 fmaxf(pm[128 + j2], pm[192 + j2]));
        float sum = 0.f;
        for (int c = 0; c < 32; ++c) {
            const int k = kq * 32 + c;
            const float e = __expf(sc[j2 * 130 + k] - rowm);
            sc[j2 * 130 + k] = e;
            sum += e;
        }
        ps[kq * 64 + j2] = sum;
        __syncthreads();
        if (kq == 0) {
            const float rs = ps[j2] + ps[64 + j2] + ps[128 + j2] + ps[192 + j2];
            coefA[j2] = tw[j] * ml[j] / rs;
        }
        __syncthreads();
        if (tid < LPD) {
            float cv = 0.f;
            for (int jj = 0; jj < 64; ++jj)
                cv += coefA[jj] * sc[jj * 130 + tid];
            cw[tid] += cv;
        }
        __syncthreads();
    }

    const int d = tid & 63;
    const int half = (tid >> 6) & 1;
    if (tid < 128 && d < DPH) {
        float acc = 0.f;
        for (int k = half * 64; k < half * 64 + 64; ++k)
            acc += cw[k] * vbase[(long)k * LS + d];
        vpart[half][d] = acc;
    }
    __syncthreads();
    if (tid < DPH)
        doc_e[doc * AD + h * DPH + tid] = vpart[0][tid] + vpart[1][tid];
}

// ===========================================================================
// FALLBACK kernels (fp32 path)
// ===========================================================================
__launch_bounds__(256)
__global__ void word_attn(const float* __restrict__ qkv, const int* __restrict__ docs,
                          const float* __restrict__ w_tgt,
                          float* __restrict__ line_e, float* __restrict__ mask_l)
{
    __shared__ float qs[WPL * QKV_S];
    __shared__ float ks[WPL * QKV_S];
    __shared__ float vs[WPL * QKV_S];
    __shared__ float sc[WPL * SC_S];
    __shared__ float ts[WPL], tw[WPL], cw[WPL], msk[WPL];
    __shared__ float mls;

    const int tid = threadIdx.x;
    const int line = blockIdx.x;

    if (tid < WPL) msk[tid] = (docs[line * WPL + tid] != 0) ? 1.f : 0.f;
    __syncthreads();
    if (tid == 0) {
        float ml = 0.f;
        for (int w = 0; w < WPL; ++w) ml = fmaxf(ml, msk[w]);
        mls = ml;
        mask_l[line] = ml;
    }
    for (int h = 0; h < NH; ++h) {
        for (int idx = tid; idx < WPL * DPH; idx += 256) {
            const int r = idx / DPH, d = idx - r * DPH;
            const size_t base = (size_t)(line * WPL + r) * NCOLS + h * DPH + d;
            qs[r * QKV_S + d] = qkv[base];
            ks[r * QKV_S + d] = qkv[base + 400];
            vs[r * QKV_S + d] = qkv[base + 800];
        }
        __syncthreads();
        {
            const int j = tid >> 3, kg = tid & 7;
            #pragma unroll
            for (int c = 0; c < 4; ++c) {
                const int kk = kg * 4 + c;
                float s = 0.f;
                for (int dd = 0; dd < DPH; ++dd)
                    s += qs[j * QKV_S + dd] * ks[kk * QKV_S + dd];
                sc[j * SC_S + kk] = s / SCALE - 1e7f * (1.f - msk[kk]);
            }
        }
        if (tid < WPL) {
            float s = 0.f;
            for (int dd = 0; dd < DPH; ++dd)
                s += w_tgt[h * DPH + dd] * ks[tid * QKV_S + dd];
            ts[tid] = s / SCALE - 1e7f * (1.f - msk[tid]);
        }
        __syncthreads();
        if (tid < WPL) {
            const int j = tid;
            float m = -1e30f;
            for (int kk = 0; kk < WPL; ++kk) m = fmaxf(m, sc[j * SC_S + kk]);
            float sum = 0.f;
            for (int kk = 0; kk < WPL; ++kk) {
                const float e = expf(sc[j * SC_S + kk] - m);
                sc[j * SC_S + kk] = e;
                sum += e;
            }
            const float inv = 1.f / sum;
            for (int kk = 0; kk < WPL; ++kk) sc[j * SC_S + kk] *= inv;
        } else if (tid == WPL) {
            float m = -1e30f;
            for (int jj = 0; jj < WPL; ++jj) m = fmaxf(m, ts[jj]);
            float sum = 0.f;
            for (int jj = 0; jj < WPL; ++jj) { const float e = expf(ts[jj] - m); tw[jj] = e; sum += e; }
            const float inv = 1.f / sum;
            for (int jj = 0; jj < WPL; ++jj) tw[jj] *= inv;
        }
        __syncthreads();
        if (tid < WPL) {
            const int kk = tid;
            float c = 0.f;
            for (int jj = 0; jj < WPL; ++jj) c += tw[jj] * msk[jj] * sc[jj * SC_S + kk];
            cw[kk] = c;
        }
        __syncthreads();
        if (tid < DPH) {
            float acc = 0.f;
            for (int kk = 0; kk < WPL; ++kk) acc += cw[kk] * vs[kk * QKV_S + tid];
            line_e[line * AD + h * DPH + tid] = acc * mls;
        }
        __syncthreads();
    }
}

__launch_bounds__(256, 2)
__global__ void gemm_qkv(const float* __restrict__ Asrc,
                         const int* __restrict__ docs,
                         const float* __restrict__ emb,
                         const float* __restrict__ W0, const float* __restrict__ W1,
                         const float* __restrict__ W2,
                         const float* __restrict__ B0, const float* __restrict__ B1,
                         const float* __restrict__ B2,
                         float* __restrict__ C, int M, int K)
{
    __shared__ __align__(16) float As[32][132];
    __shared__ __align__(16) float Bs[32][132];

    const int tid = threadIdx.x;
    const int row0 = blockIdx.x * 128;
    const int n0 = blockIdx.y * 128;
    const int tc = tid & 15, tr = tid >> 4;

    float acc[2][2][4][4];
    #pragma unroll
    for (int a = 0; a < 2; ++a)
        #pragma unroll
        for (int b = 0; b < 2; ++b)
            #pragma unroll
            for (int c = 0; c < 4; ++c)
                #pragma unroll
                for (int d = 0; d < 4; ++d) acc[a][b][c][d] = 0.f;

    const int ma = tid & 127;
    const int kq = tid >> 7;
    const float* arow;
    if (docs) arow = emb + (size_t)docs[row0 + ma] * EMBD;
    else      arow = Asrc + (size_t)(row0 + ma) * K;

    const int gcol = n0 + ma;
    const int p = gcol / 400;
    const int ccol = gcol - p * 400;
    const float* Wp = (p == 0) ? W0 : (p == 1) ? W1 : W2;
    const bool colv = gcol < NCOLS;

    const int nk = (K + 31) >> 5;
    for (int ck = 0; ck < nk; ++ck) {
        const int k0 = ck * 32;
        #pragma unroll
        for (int f = 0; f < 4; ++f) {
            const int kl = kq * 16 + f * 4;
            const int kg = k0 + kl;
            float4 v = make_float4(0.f, 0.f, 0.f, 0.f);
            if (kg < K) v = *(const float4*)(arow + kg);
            As[kl + 0][ma] = v.x;
            As[kl + 1][ma] = v.y;
            As[kl + 2][ma] = v.z;
            As[kl + 3][ma] = v.w;
        }
        #pragma unroll
        for (int i = 0; i < 16; ++i) {
            const int kl = kq * 16 + i;
            const int kg = k0 + kl;
            float v = 0.f;
            if (colv && kg < K) v = Wp[(size_t)kg * 400 + ccol];
            Bs[kl][ma] = v;
        }
        __syncthreads();

        #pragma unroll 8
        for (int k = 0; k < 32; ++k) {
            const float4 a0 = *(const float4*)&As[k][tr * 4];
            const float4 a1 = *(const float4*)&As[k][64 + tr * 4];
            const float4 b0 = *(const float4*)&Bs[k][tc * 4];
            const float4 b1 = *(const float4*)&Bs[k][64 + tc * 4];
            const float ar[2][4] = {{a0.x, a0.y, a0.z, a0.w}, {a1.x, a1.y, a1.z, a1.w}};
            const float br[2][4] = {{b0.x, b0.y, b0.z, b0.w}, {b1.x, b1.y, b1.z, b1.w}};
            #pragma unroll
            for (int im = 0; im < 2; ++im)
                #pragma unroll
                for (int in_ = 0; in_ < 2; ++in_)
                    #pragma unroll
                    for (int rr = 0; rr < 4; ++rr)
                        #pragma unroll
                        for (int cc = 0; cc < 4; ++cc)
                            acc[im][in_][rr][cc] += ar[im][rr] * br[in_][cc];
        }
        __syncthreads();
    }

    #pragma unroll
    for (int in_ = 0; in_ < 2; ++in_) {
        const int ncol = n0 + in_ * 64 + tc * 4;
        if (ncol >= NCOLS) continue;
        const int pj = ncol / 400;
        const int cj = ncol - pj * 400;
        const float* Bp = (pj == 0) ? B0 : (pj == 1) ? B1 : B2;
        const float4 bv = *(const float4*)(Bp + cj);
        #pragma unroll
        for (int im = 0; im < 2; ++im) {
            #pragma unroll
            for (int rr = 0; rr < 4; ++rr) {
                const int row = row0 + im * 64 + tr * 4 + rr;
                float4 o;
                o.x = elu(acc[im][in_][rr][0] + bv.x);
                o.y = elu(acc[im][in_][rr][1] + bv.y);
                o.z = elu(acc[im][in_][rr][2] + bv.z);
                o.w = elu(acc[im][in_][rr][3] + bv.w);
                *(float4*)(C + (size_t)row * NCOLS + ncol) = o;
            }
        }
    }
}

__global__ void logits_kernel(const float* __restrict__ doc_e,
                              const float* __restrict__ fc1_w, const float* __restrict__ fc1_b,
                              const float* __restrict__ fc2_w, const float* __restrict__ fc2_b,
                              float* __restrict__ out)
{
    int o = blockIdx.x * blockDim.x + threadIdx.x;
    if (o >= BATCH * 582) return;
    int b = o / 582, jj = o - b * 582;
    const float* de = doc_e + b * AD;
    float acc;
    if (jj < 70) {
        acc = fc1_b[jj];
        for (int k = 0; k < AD; ++k) acc += de[k] * fc1_w[k * 70 + jj];
    } else {
        int j2 = jj - 70;
        acc = fc2_b[j2];
        for (int k = 0; k < AD; ++k) acc += de[k] * fc2_w[k * 512 + j2];
    }
    out[o] = acc;
}

// ---------------------------------------------------------------------------
extern "C" void kernel_launch(void* const* d_in, const int* in_sizes, int n_in,
                              void* d_out, int out_size, void* d_ws, size_t ws_size,
                              hipStream_t stream) {
    const int*   docs  = (const int*)  d_in[0];
    const float* emb   = (const float*)d_in[1];
    const float* wq_w  = (const float*)d_in[2];
    const float* wq_b  = (const float*)d_in[3];
    const float* wk_w  = (const float*)d_in[4];
    const float* wk_b  = (const float*)d_in[5];
    const float* wv_w  = (const float*)d_in[6];
    const float* wv_b  = (const float*)d_in[7];
    const float* w_tgt = (const float*)d_in[8];
    const float* lq_w  = (const float*)d_in[9];
    const float* lq_b  = (const float*)d_in[10];
    const float* lk_w  = (const float*)d_in[11];
    const float* lk_b  = (const float*)d_in[12];
    const float* lv_w  = (const float*)d_in[13];
    const float* lv_b  = (const float*)d_in[14];
    const float* l_tgt = (const float*)d_in[15];
    const float* fc1_w = (const float*)d_in[16];
    const float* fc1_b = (const float*)d_in[17];
    const float* fc2_w = (const float*)d_in[18];
    const float* fc2_b = (const float*)d_in[19];
    float* out = (float*)d_out;
    float* ws = (float*)d_ws;

    const long O_LINE_E = 0;
    const long O_MASK_L = 819200;
    const long O_DOC_E  = 821248;
    const long O_BIAS_W = 827648;
    const long O_BIAS_L = 828928;
    const long O_EMB_H  = 830208;
    const long O_EMB_L  = 5630208;
    const long O_WTW_H  = 10430208;
    const long O_WTW_L  = 10635008;
    const long O_WTL_H  = 10839808;
    const long O_WTL_L  = 11106048;
    const long O_LE_H   = 11372288;
    const long O_LE_L   = 11798272;
    const long O_R      = 12224256;

    const long LINE_QKV_FL = (long)NLINES * NCOLS;    // 2457600
    long ws_fl = (long)(ws_size / 4);
    long Rcap = ws_fl - O_R;

    if (Rcap >= LINE_QKV_FL) {
        // ================= MFMA fast path =================
        float* line_e = ws + O_LINE_E;
        float* mask_l = ws + O_MASK_L;
        float* doc_e  = ws + O_DOC_E;
        float* bias_w = ws + O_BIAS_W;
        float* bias_l = ws + O_BIAS_L;
        bf16* embh = (bf16*)(ws + O_EMB_H);
        bf16* embl = (bf16*)(ws + O_EMB_L);
        bf16* wtwh = (bf16*)(ws + O_WTW_H);
        bf16* wtwl = (bf16*)(ws + O_WTW_L);
        bf16* wtlh = (bf16*)(ws + O_WTL_H);
        bf16* wtll = (bf16*)(ws + O_WTL_L);
        bf16* leh  = (bf16*)(ws + O_LE_H);
        bf16* lel  = (bf16*)(ws + O_LE_L);
        float* R   = ws + O_R;

        split_rows<<<(30000L * 320 + 255) / 256, 256, 0, stream>>>(emb, embh, embl, 30000, 300, 320);
        split_wt<<<((long)NPAD * 320 + 255) / 256, 256, 0, stream>>>(wq_w, wk_w, wv_w,
                                                                     wq_b, wk_b, wv_b,
                                                                     wtwh, wtwl, bias_w, 300, 320);
        split_wt<<<((long)NPAD * 416 + 255) / 256, 256, 0, stream>>>(lq_w, lk_w, lv_w,
                                                                     lq_b, lk_b, lv_b,
                                                                     wtlh, wtll, bias_l, 400, 416);

        // chunk = 1024 lines: grid 2560 blocks halves the occupancy tail
        // (time-optimal per r5-r11 A/B; L3 residency proved time-neutral)
        long maxl = Rcap / WLINE_FL;
        if (maxl > 1024) maxl = 1024;
        long chunk = (maxl / 4) * 4;
        if (chunk < 4) chunk = 4;
        for (long c0 = 0; c0 < NLINES; c0 += chunk) {
            long cl = NLINES - c0 < chunk ? NLINES - c0 : chunk;   // multiple of 4
            dim3 g1(10, (unsigned)((cl * 32) / 128));   // x=col (fastest), y=row
            mfma_gemm<<<g1, 256, 0, stream>>>(embh, embl, docs + c0 * WPL,
                                              wtwh, wtwl, bias_w, R, 320, 1);
            word_attn4<<<(unsigned)(cl * NH), 256, 0, stream>>>(R, docs + c0 * WPL, w_tgt,
                                                                line_e + c0 * AD, mask_l + c0);
        }

        split_rows<<<((long)NLINES * 416 + 255) / 256, 256, 0, stream>>>(line_e, leh, lel,
                                                                         NLINES, 400, 416);
        dim3 g2(10, NLINES / 128);
        mfma_gemm<<<g2, 256, 0, stream>>>(leh, lel, nullptr, wtlh, wtll, bias_l, R, 416, 0);
        line_attn2<<<BATCH * NH, 256, 0, stream>>>(R, R + 400, R + 800,
                                                   (long)LPD * NCOLS, (long)DPH, (long)NCOLS,
                                                   l_tgt, mask_l, doc_e);
        logits_kernel<<<(BATCH * 582 + 255) / 256, 256, 0, stream>>>(doc_e, fc1_w, fc1_b,
                                                                     fc2_w, fc2_b, out);
    } else {
        // ================= fp32 fallback =================
        const long F_FIXED = 827648;
        const long PER_LINE_FL = (long)WPL * NCOLS;
        float* line_e = ws;
        float* mask_l = ws + 819200;
        float* doc_e  = ws + 821248;
        float* R      = ws + F_FIXED;
        long Rcap2 = ws_fl - F_FIXED;

        long maxl = Rcap2 / PER_LINE_FL;
        if (maxl > NLINES) maxl = NLINES;
        long maxl4 = (maxl / 4) * 4;
        int nc = (int)((NLINES + maxl4 - 1) / maxl4);
        int chunk = (int)((NLINES + nc - 1) / nc);
        chunk = ((chunk + 3) / 4) * 4;

        for (int c0 = 0; c0 < NLINES; c0 += chunk) {
            int cl = NLINES - c0 < chunk ? NLINES - c0 : chunk;
            dim3 g1((cl * 32) / 128, 10);
            gemm_qkv<<<g1, 256, 0, stream>>>(nullptr, docs + (size_t)c0 * WPL, emb,
                                             wq_w, wk_w, wv_w, wq_b, wk_b, wv_b,
                                             R, cl * 32, EMBD);
            word_attn<<<cl, 256, 0, stream>>>(R, docs + (size_t)c0 * WPL, w_tgt,
                                              line_e + (size_t)c0 * AD, mask_l + c0);
        }
        dim3 g2(16, 10);
        gemm_qkv<<<g2, 256, 0, stream>>>(line_e, nullptr, emb,
                                         lq_w, lk_w, lv_w, lq_b, lk_b, lv_b,
                                         R, NLINES, AD);
        line_attn2<<<BATCH * NH, 256, 0, stream>>>(R, R + 400, R + 800,
                                                   (long)LPD * NCOLS, (long)DPH, (long)NCOLS,
                                                   l_tgt, mask_l, doc_e);
        logits_kernel<<<(BATCH * 582 + 255) / 256, 256, 0, stream>>>(doc_e, fc1_w, fc1_b,
                                                                     fc2_w, fc2_b, out);
    }
}

// Round 13
// 654.212 us; speedup vs baseline: 1.4821x; 1.0152x over previous
//
#include <hip/hip_runtime.h>
#include <math.h>

#define NLINES 2048
#define WPL 32
#define EMBD 300
#define AD 400
#define NH 8
#define DPH 50
#define QKV_S 52
#define SC_S 36
#define BATCH 16
#define LPD 128
#define NCOLS 1200     // 3 proj * 400
#define NPAD 1280      // padded col count for Wt tables
#define WLINE_FL 39936 // per-line floats in word layout: 8*3*32*52
#define HBLK 4992      // per-(line,head) floats: 3*32*52

typedef __bf16 bf16;
typedef bf16  v8bf  __attribute__((ext_vector_type(8)));
typedef float v4f   __attribute__((ext_vector_type(4)));
typedef float v16f  __attribute__((ext_vector_type(16)));

__device__ __forceinline__ float elu(float x) {
    return x > 0.f ? x : expm1f(x);
}
__device__ __forceinline__ float elu_fast(float x) {
    return x > 0.f ? x : (__expf(x) - 1.f);
}

#define SCALE 7.0710678118654755f   // sqrt(50)

// ===========================================================================
// Split helpers: fp32 -> (hi, lo) bf16 pair.  x ~= hi + lo, rel err ~2^-18.
// ===========================================================================
__global__ void split_rows(const float* __restrict__ src,
                           bf16* __restrict__ hi, bf16* __restrict__ lo,
                           int rows, int K, int K2)
{
    long idx = (long)blockIdx.x * 256 + threadIdx.x;
    if (idx >= (long)rows * K2) return;
    int r = (int)(idx / K2), k = (int)(idx - (long)r * K2);
    float x = (k < K) ? src[(long)r * K + k] : 0.f;
    bf16 h = (bf16)x;
    float hf = (float)h;
    bf16 l = (bf16)(x - hf);
    hi[idx] = h; lo[idx] = l;
}

__global__ void split_wt(const float* __restrict__ W0, const float* __restrict__ W1,
                         const float* __restrict__ W2,
                         const float* __restrict__ B0, const float* __restrict__ B1,
                         const float* __restrict__ B2,
                         bf16* __restrict__ hi, bf16* __restrict__ lo,
                         float* __restrict__ biasCat, int K, int K2)
{
    long idx = (long)blockIdx.x * 256 + threadIdx.x;
    if (idx >= (long)NPAD * K2) return;
    int n = (int)(idx / K2), k = (int)(idx - (long)n * K2);
    float x = 0.f;
    if (k < K && n < NCOLS) {
        int p = n / 400, c = n - p * 400;
        const float* W = (p == 0) ? W0 : (p == 1) ? W1 : W2;
        x = W[(long)k * 400 + c];
    }
    bf16 h = (bf16)x;
    float hf = (float)h;
    bf16 l = (bf16)(x - hf);
    hi[idx] = h; lo[idx] = l;
    if (k == 0) {
        float b = 0.f;
        if (n < NCOLS) {
            int p = n / 400, c = n - p * 400;
            const float* Bp = (p == 0) ? B0 : (p == 1) ? B1 : B2;
            b = Bp[c];
        }
        biasCat[n] = b;
    }
}

// ===========================================================================
// mfma_gemm: C = elu( A @ Wt^T + biasCat ), split-bf16 3-product, staged LDS,
// 32x32x16 MFMA inner (24 issues/k-tile vs 48 for 16x16x32; same FLOPs/LDS).
// Wave = 2x2 tiles of 32x32 (64x64 patch).  GRID: x = col-block (fastest).
// word_layout=1: C[(line*8+h)*3+p][32][52]; word_layout=0: row-major [row][1200].
// D layout (m74/m101): col=lane&31, row=(reg&3)+8*(reg>>2)+4*(lane>>5).
// ===========================================================================
__launch_bounds__(256)
__global__ void mfma_gemm(const bf16* __restrict__ Ah_t, const bf16* __restrict__ Al_t,
                          const int* __restrict__ docs,
                          const bf16* __restrict__ Bh_t, const bf16* __restrict__ Bl_t,
                          const float* __restrict__ biasCat,
                          float* __restrict__ C, int K2, int word_layout)
{
    __shared__ __align__(16) bf16 Ah[4096];
    __shared__ __align__(16) bf16 Al[4096];
    __shared__ __align__(16) bf16 Bh[4096];
    __shared__ __align__(16) bf16 Bl[4096];
    __shared__ int tok[128];

    const int tid = threadIdx.x;
    const int row0 = blockIdx.y * 128;     // y = row-block
    const int n0 = blockIdx.x * 128;       // x = col-block (fastest)

    if (tid < 128) tok[tid] = docs ? docs[row0 + tid] : (row0 + tid);
    __syncthreads();

    const int qa = tid >> 7;
    const int sm = tid & 127;
    const long aoff = (long)tok[sm] * K2;
    const long boff = (long)(n0 + sm) * K2;

    const int wv = tid >> 6, lane = tid & 63;
    const int half = lane >> 5, r32 = lane & 31;
    const int wm0 = (wv >> 1) * 64, wn0 = (wv & 1) * 64;

    v16f acc[2][2];
    #pragma unroll
    for (int a = 0; a < 2; ++a)
        #pragma unroll
        for (int b = 0; b < 2; ++b) acc[a][b] = (v16f)0.f;

    const int nk = K2 >> 5;
    // prefetch tile 0
    v8bf pa0 = *(const v8bf*)(Ah_t + aoff + qa * 8);
    v8bf pa1 = *(const v8bf*)(Ah_t + aoff + (qa + 2) * 8);
    v8bf pl0 = *(const v8bf*)(Al_t + aoff + qa * 8);
    v8bf pl1 = *(const v8bf*)(Al_t + aoff + (qa + 2) * 8);
    v8bf pb0 = *(const v8bf*)(Bh_t + boff + qa * 8);
    v8bf pb1 = *(const v8bf*)(Bh_t + boff + (qa + 2) * 8);
    v8bf pc0 = *(const v8bf*)(Bl_t + boff + qa * 8);
    v8bf pc1 = *(const v8bf*)(Bl_t + boff + (qa + 2) * 8);

    for (int kt = 0; kt < nk; ++kt) {
        *(v8bf*)&Ah[tid * 8]         = pa0;
        *(v8bf*)&Ah[(256 + tid) * 8] = pa1;
        *(v8bf*)&Al[tid * 8]         = pl0;
        *(v8bf*)&Al[(256 + tid) * 8] = pl1;
        *(v8bf*)&Bh[tid * 8]         = pb0;
        *(v8bf*)&Bh[(256 + tid) * 8] = pb1;
        *(v8bf*)&Bl[tid * 8]         = pc0;
        *(v8bf*)&Bl[(256 + tid) * 8] = pc1;
        __syncthreads();

        if (kt + 1 < nk) {   // next tile's loads fly during MFMA
            const int k1 = (kt + 1) * 32;
            pa0 = *(const v8bf*)(Ah_t + aoff + k1 + qa * 8);
            pa1 = *(const v8bf*)(Ah_t + aoff + k1 + (qa + 2) * 8);
            pl0 = *(const v8bf*)(Al_t + aoff + k1 + qa * 8);
            pl1 = *(const v8bf*)(Al_t + aoff + k1 + (qa + 2) * 8);
            pb0 = *(const v8bf*)(Bh_t + boff + k1 + qa * 8);
            pb1 = *(const v8bf*)(Bh_t + boff + k1 + (qa + 2) * 8);
            pc0 = *(const v8bf*)(Bl_t + boff + k1 + qa * 8);
            pc1 = *(const v8bf*)(Bl_t + boff + k1 + (qa + 2) * 8);
        }

        // fragments: A[m = wm0+t*32+r32][k = (ks*2+half)*8 ..+8] (k-contig 16B)
        v8bf fa_h[2][2], fa_l[2][2], fb_h[2][2], fb_l[2][2];
        #pragma unroll
        for (int t = 0; t < 2; ++t)
            #pragma unroll
            for (int ks = 0; ks < 2; ++ks) {
                const int ea = (((ks * 2 + half) << 7) + wm0 + t * 32 + r32) * 8;
                fa_h[t][ks] = *(const v8bf*)&Ah[ea];
                fa_l[t][ks] = *(const v8bf*)&Al[ea];
                const int eb = (((ks * 2 + half) << 7) + wn0 + t * 32 + r32) * 8;
                fb_h[t][ks] = *(const v8bf*)&Bh[eb];
                fb_l[t][ks] = *(const v8bf*)&Bl[eb];
            }

        #pragma unroll
        for (int ks = 0; ks < 2; ++ks)
            #pragma unroll
            for (int mt = 0; mt < 2; ++mt)
                #pragma unroll
                for (int nt = 0; nt < 2; ++nt)
                    acc[mt][nt] = __builtin_amdgcn_mfma_f32_32x32x16_bf16(fa_h[mt][ks], fb_h[nt][ks], acc[mt][nt], 0, 0, 0);
        #pragma unroll
        for (int ks = 0; ks < 2; ++ks)
            #pragma unroll
            for (int mt = 0; mt < 2; ++mt)
                #pragma unroll
                for (int nt = 0; nt < 2; ++nt)
                    acc[mt][nt] = __builtin_amdgcn_mfma_f32_32x32x16_bf16(fa_h[mt][ks], fb_l[nt][ks], acc[mt][nt], 0, 0, 0);
        #pragma unroll
        for (int ks = 0; ks < 2; ++ks)
            #pragma unroll
            for (int mt = 0; mt < 2; ++mt)
                #pragma unroll
                for (int nt = 0; nt < 2; ++nt)
                    acc[mt][nt] = __builtin_amdgcn_mfma_f32_32x32x16_bf16(fa_l[mt][ks], fb_h[nt][ks], acc[mt][nt], 0, 0, 0);
        __syncthreads();
    }

    // ---- epilogue: D col = lane&31, row = (rg&3)+8*(rg>>2)+4*half
    if (word_layout) {
        #pragma unroll
        for (int nt = 0; nt < 2; ++nt) {
            const int col = n0 + wn0 + nt * 32 + r32;
            if (col >= NCOLS) continue;
            const float bv = biasCat[col];
            const int p = col / 400;
            const int rem = col - p * 400;
            const int hh = rem / 50;
            const int d  = rem - hh * 50;
            #pragma unroll
            for (int mt = 0; mt < 2; ++mt) {
                const int rbase = row0 + wm0 + mt * 32 + 4 * half;
                #pragma unroll
                for (int rg = 0; rg < 16; ++rg) {
                    const int row = rbase + (rg & 3) + 8 * (rg >> 2);
                    const int ln = row >> 5, r = row & 31;
                    const float x = acc[mt][nt][rg] + bv;
                    C[(((long)ln * NH + hh) * 3 + p) * 1664 + r * 52 + d] = elu_fast(x);
                }
            }
        }
    } else {
        #pragma unroll
        for (int nt = 0; nt < 2; ++nt) {
            const int col = n0 + wn0 + nt * 32 + r32;
            if (col >= NCOLS) continue;
            const float bv = biasCat[col];
            #pragma unroll
            for (int mt = 0; mt < 2; ++mt) {
                const int rbase = row0 + wm0 + mt * 32 + 4 * half;
                #pragma unroll
                for (int rg = 0; rg < 16; ++rg) {
                    const int row = rbase + (rg & 3) + 8 * (rg >> 2);
                    const float x = acc[mt][nt][rg] + bv;
                    C[(long)row * NCOLS + col] = elu_fast(x);
                }
            }
        }
    }
}

// ===========================================================================
// word_attn4: one 256-thread BLOCK per (line, head).  qkvw [line][h][3][32][52].
// ===========================================================================
__launch_bounds__(256)
__global__ void word_attn4(const float* __restrict__ qkvw, const int* __restrict__ docs,
                           const float* __restrict__ w_tgt,
                           float* __restrict__ line_e, float* __restrict__ mask_l)
{
    __shared__ __align__(16) float sh[HBLK];   // q[0..1663] k[1664..] v[3328..]
    __shared__ float sc[32 * 33];
    __shared__ float msk[WPL];
    __shared__ float tw[WPL];
    __shared__ float coefA[WPL];
    __shared__ float part[8][33];
    __shared__ float cw[WPL];
    __shared__ float vpart[4][64];
    __shared__ float tg[52];
    __shared__ float mls_s;

    const int tid = threadIdx.x;
    const int line = blockIdx.x >> 3;
    const int h = blockIdx.x & 7;

    if (tid < WPL) msk[tid] = (docs[line * WPL + tid] != 0) ? 1.f : 0.f;
    if (tid >= 64 && tid < 116) tg[tid - 64] = (tid - 64 < DPH) ? w_tgt[h * DPH + tid - 64] : 0.f;

    const float* src = qkvw + ((long)line * NH + h) * HBLK;
    for (int i = tid; i < HBLK / 4; i += 256)
        *(float4*)&sh[i * 4] = *(const float4*)&src[i * 4];
    if (tid < 192) {   // zero d=50,51 pads (GEMM never writes them)
        const int a = tid / 64, rem = tid - a * 64;
        sh[a * 1664 + (rem >> 1) * 52 + 50 + (rem & 1)] = 0.f;
    }
    __syncthreads();

    if (tid == 0) {
        float m = 0.f;
        for (int w = 0; w < WPL; ++w) m = fmaxf(m, msk[w]);
        mls_s = m;
        if (h == 0) mask_l[line] = m;
    }

    // ---- scores: thread (j = tid>>3, kg = tid&7) -> 4 scores
    const int j = tid >> 3, kg = tid & 7;
    float4 qv[13];
    #pragma unroll
    for (int i = 0; i < 13; ++i) qv[i] = *(const float4*)&sh[j * 52 + i * 4];

    float e4[4];
    float m = -1e30f;
    #pragma unroll
    for (int c = 0; c < 4; ++c) {
        const int kk = kg * 4 + c;
        const float* kr = &sh[1664 + kk * 52];
        float s = 0.f;
        #pragma unroll
        for (int i = 0; i < 13; ++i) {
            const float4 kv = *(const float4*)&kr[i * 4];
            s += qv[i].x * kv.x + qv[i].y * kv.y + qv[i].z * kv.z + qv[i].w * kv.w;
        }
        s = s / SCALE - 1e7f * (1.f - msk[kk]);
        e4[c] = s;
        m = fmaxf(m, s);
    }
    m = fmaxf(m, __shfl_xor(m, 1));
    m = fmaxf(m, __shfl_xor(m, 2));
    m = fmaxf(m, __shfl_xor(m, 4));
    float rsum = 0.f;
    #pragma unroll
    for (int c = 0; c < 4; ++c) { e4[c] = __expf(e4[c] - m); rsum += e4[c]; }
    rsum += __shfl_xor(rsum, 1);
    rsum += __shfl_xor(rsum, 2);
    rsum += __shfl_xor(rsum, 4);
    #pragma unroll
    for (int c = 0; c < 4; ++c) sc[j * 33 + kg * 4 + c] = e4[c];

    // ---- target softmax (wave-0 lanes 0..31)
    if (tid < WPL) {
        const float* kr = &sh[1664 + tid * 52];
        float s = 0.f;
        #pragma unroll
        for (int i = 0; i < 25; ++i)
            s += tg[2 * i] * kr[2 * i] + tg[2 * i + 1] * kr[2 * i + 1];
        s = s / SCALE - 1e7f * (1.f - msk[tid]);
        float tm = s;
        #pragma unroll
        for (int off = 16; off >= 1; off >>= 1) tm = fmaxf(tm, __shfl_xor(tm, off, 32));
        const float te = __expf(s - tm);
        float tsum = te;
        #pragma unroll
        for (int off = 16; off >= 1; off >>= 1) tsum += __shfl_xor(tsum, off, 32);
        tw[tid] = te / tsum;
    }
    __syncthreads();

    if (kg == 0) coefA[j] = tw[j] * msk[j] / rsum;
    __syncthreads();

    {
        const int k = tid & 31, jg = tid >> 5;
        float cv = 0.f;
        #pragma unroll
        for (int t = 0; t < 4; ++t) {
            const int jj = jg * 4 + t;
            cv += coefA[jj] * sc[jj * 33 + k];
        }
        part[jg][k] = cv;
    }
    __syncthreads();
    if (tid < WPL) {
        float cv = 0.f;
        #pragma unroll
        for (int g = 0; g < 8; ++g) cv += part[g][tid];
        cw[tid] = cv;
    }
    __syncthreads();

    {
        const int d = tid & 63, kh = tid >> 6;
        float acc = 0.f;
        if (d < 52) {
            #pragma unroll
            for (int t = 0; t < 8; ++t) {
                const int k = kh * 8 + t;
                acc += cw[k] * sh[3328 + k * 52 + d];
            }
        }
        vpart[kh][d] = acc;
    }
    __syncthreads();
    if (tid < DPH) {
        const float o = vpart[0][tid] + vpart[1][tid] + vpart[2][tid] + vpart[3][tid];
        line_e[(long)line * AD + h * DPH + tid] = o * mls_s;
    }
}

// ===========================================================================
// line_attn2: fully-parallel line attention + doc target attention.
// ===========================================================================
__launch_bounds__(256)
__global__ void line_attn2(const float* __restrict__ Q, const float* __restrict__ Kp,
                           const float* __restrict__ Vp,
                           long DS, long HS, long LS,
                           const float* __restrict__ l_tgt, const float* __restrict__ mask_l,
                           float* __restrict__ doc_e)
{
    __shared__ float kl[LPD * 52];     // 26624 B
    __shared__ float sc[64 * 130];     // 33280 B
    __shared__ float ml[LPD];
    __shared__ float tw[LPD];
    __shared__ float cw[LPD];
    __shared__ float coefA[64];
    __shared__ float pm[4 * 64];
    __shared__ float ps[4 * 64];
    __shared__ float tg[52];
    __shared__ float rr[2];
    __shared__ float vpart[2][64];

    const int tid = threadIdx.x;
    const int doc = blockIdx.x >> 3;
    const int h = blockIdx.x & 7;
    const float* qbase = Q + doc * DS + h * HS;
    const float* kbase = Kp + doc * DS + h * HS;
    const float* vbase = Vp + doc * DS + h * HS;

    if (tid < LPD) { ml[tid] = mask_l[doc * LPD + tid]; cw[tid] = 0.f; }
    if (tid < 52) tg[tid] = (tid < DPH) ? l_tgt[h * DPH + tid] : 0.f;
    for (int idx = tid; idx < LPD * 52; idx += 256) {
        const int r = idx / 52, d = idx - r * 52;
        kl[idx] = (d < DPH) ? kbase[(long)r * LS + d] : 0.f;
    }
    __syncthreads();

    if (tid < LPD) {
        const float* kr = &kl[tid * 52];
        float s = 0.f;
        #pragma unroll
        for (int i = 0; i < 25; ++i)
            s += tg[2 * i] * kr[2 * i] + tg[2 * i + 1] * kr[2 * i + 1];
        tw[tid] = s / SCALE - 1e7f * (1.f - ml[tid]);   // raw ts
    }
    __syncthreads();
    if (tid < 64) {
        float a = fmaxf(tw[tid], tw[64 + tid]);
        #pragma unroll
        for (int off = 32; off >= 1; off >>= 1) a = fmaxf(a, __shfl_xor(a, off));
        if (tid == 0) rr[0] = a;
    }
    __syncthreads();
    if (tid < 64) {
        const float tm2 = rr[0];
        float a = __expf(tw[tid] - tm2) + __expf(tw[64 + tid] - tm2);
        #pragma unroll
        for (int off = 32; off >= 1; off >>= 1) a += __shfl_xor(a, off);
        if (tid == 0) rr[1] = a;
    }
    __syncthreads();
    if (tid < LPD) tw[tid] = __expf(tw[tid] - rr[0]) / rr[1];   // final tw
    __syncthreads();

    const int j2 = tid & 63;
    const int kq = tid >> 6;          // 0..3, k range [kq*32, kq*32+32)

    for (int g = 0; g < 2; ++g) {
        const int j = g * 64 + j2;
        float2 qv[25];
        #pragma unroll
        for (int i = 0; i < 25; ++i)
            qv[i] = *(const float2*)(qbase + (long)j * LS + 2 * i);

        float m = -1e30f;
        for (int c = 0; c < 32; ++c) {
            const int k = kq * 32 + c;
            const float* kr = &kl[k * 52];
            float s = 0.f;
            #pragma unroll
            for (int i = 0; i < 25; ++i)
                s += qv[i].x * kr[2 * i] + qv[i].y * kr[2 * i + 1];
            s = s / SCALE - 1e7f * (1.f - ml[k]);
            sc[j2 * 130 + k] = s;
            m = fmaxf(m, s);
        }
        pm[kq * 64 + j2] = m;
        __syncthreads();
        const float rowm = fmaxf(fmaxf(pm[j2], pm[64 + j2]),
                                 fmaxf(pm[128 + j2], pm[192 + j2]));
        float sum = 0.f;
        for (int c = 0; c < 32; ++c) {
            const int k = kq * 32 + c;
            const float e = __expf(sc[j2 * 130 + k] - rowm);
            sc[j2 * 130 + k] = e;
            sum += e;
        }
        ps[kq * 64 + j2] = sum;
        __syncthreads();
        if (kq == 0) {
            const float rs = ps[j2] + ps[64 + j2] + ps[128 + j2] + ps[192 + j2];
            coefA[j2] = tw[j] * ml[j] / rs;
        }
        __syncthreads();
        if (tid < LPD) {
            float cv = 0.f;
            for (int jj = 0; jj < 64; ++jj)
                cv += coefA[jj] * sc[jj * 130 + tid];
            cw[tid] += cv;
        }
        __syncthreads();
    }

    const int d = tid & 63;
    const int half = (tid >> 6) & 1;
    if (tid < 128 && d < DPH) {
        float acc = 0.f;
        for (int k = half * 64; k < half * 64 + 64; ++k)
            acc += cw[k] * vbase[(long)k * LS + d];
        vpart[half][d] = acc;
    }
    __syncthreads();
    if (tid < DPH)
        doc_e[doc * AD + h * DPH + tid] = vpart[0][tid] + vpart[1][tid];
}

// ===========================================================================
// FALLBACK kernels (fp32 path)
// ===========================================================================
__launch_bounds__(256)
__global__ void word_attn(const float* __restrict__ qkv, const int* __restrict__ docs,
                          const float* __restrict__ w_tgt,
                          float* __restrict__ line_e, float* __restrict__ mask_l)
{
    __shared__ float qs[WPL * QKV_S];
    __shared__ float ks[WPL * QKV_S];
    __shared__ float vs[WPL * QKV_S];
    __shared__ float sc[WPL * SC_S];
    __shared__ float ts[WPL], tw[WPL], cw[WPL], msk[WPL];
    __shared__ float mls;

    const int tid = threadIdx.x;
    const int line = blockIdx.x;

    if (tid < WPL) msk[tid] = (docs[line * WPL + tid] != 0) ? 1.f : 0.f;
    __syncthreads();
    if (tid == 0) {
        float ml = 0.f;
        for (int w = 0; w < WPL; ++w) ml = fmaxf(ml, msk[w]);
        mls = ml;
        mask_l[line] = ml;
    }
    for (int h = 0; h < NH; ++h) {
        for (int idx = tid; idx < WPL * DPH; idx += 256) {
            const int r = idx / DPH, d = idx - r * DPH;
            const size_t base = (size_t)(line * WPL + r) * NCOLS + h * DPH + d;
            qs[r * QKV_S + d] = qkv[base];
            ks[r * QKV_S + d] = qkv[base + 400];
            vs[r * QKV_S + d] = qkv[base + 800];
        }
        __syncthreads();
        {
            const int j = tid >> 3, kg = tid & 7;
            #pragma unroll
            for (int c = 0; c < 4; ++c) {
                const int kk = kg * 4 + c;
                float s = 0.f;
                for (int dd = 0; dd < DPH; ++dd)
                    s += qs[j * QKV_S + dd] * ks[kk * QKV_S + dd];
                sc[j * SC_S + kk] = s / SCALE - 1e7f * (1.f - msk[kk]);
            }
        }
        if (tid < WPL) {
            float s = 0.f;
            for (int dd = 0; dd < DPH; ++dd)
                s += w_tgt[h * DPH + dd] * ks[tid * QKV_S + dd];
            ts[tid] = s / SCALE - 1e7f * (1.f - msk[tid]);
        }
        __syncthreads();
        if (tid < WPL) {
            const int j = tid;
            float m = -1e30f;
            for (int kk = 0; kk < WPL; ++kk) m = fmaxf(m, sc[j * SC_S + kk]);
            float sum = 0.f;
            for (int kk = 0; kk < WPL; ++kk) {
                const float e = expf(sc[j * SC_S + kk] - m);
                sc[j * SC_S + kk] = e;
                sum += e;
            }
            const float inv = 1.f / sum;
            for (int kk = 0; kk < WPL; ++kk) sc[j * SC_S + kk] *= inv;
        } else if (tid == WPL) {
            float m = -1e30f;
            for (int jj = 0; jj < WPL; ++jj) m = fmaxf(m, ts[jj]);
            float sum = 0.f;
            for (int jj = 0; jj < WPL; ++jj) { const float e = expf(ts[jj] - m); tw[jj] = e; sum += e; }
            const float inv = 1.f / sum;
            for (int jj = 0; jj < WPL; ++jj) tw[jj] *= inv;
        }
        __syncthreads();
        if (tid < WPL) {
            const int kk = tid;
            float c = 0.f;
            for (int jj = 0; jj < WPL; ++jj) c += tw[jj] * msk[jj] * sc[jj * SC_S + kk];
            cw[kk] = c;
        }
        __syncthreads();
        if (tid < DPH) {
            float acc = 0.f;
            for (int kk = 0; kk < WPL; ++kk) acc += cw[kk] * vs[kk * QKV_S + tid];
            line_e[line * AD + h * DPH + tid] = acc * mls;
        }
        __syncthreads();
    }
}

__launch_bounds__(256, 2)
__global__ void gemm_qkv(const float* __restrict__ Asrc,
                         const int* __restrict__ docs,
                         const float* __restrict__ emb,
                         const float* __restrict__ W0, const float* __restrict__ W1,
                         const float* __restrict__ W2,
                         const float* __restrict__ B0, const float* __restrict__ B1,
                         const float* __restrict__ B2,
                         float* __restrict__ C, int M, int K)
{
    __shared__ __align__(16) float As[32][132];
    __shared__ __align__(16) float Bs[32][132];

    const int tid = threadIdx.x;
    const int row0 = blockIdx.x * 128;
    const int n0 = blockIdx.y * 128;
    const int tc = tid & 15, tr = tid >> 4;

    float acc[2][2][4][4];
    #pragma unroll
    for (int a = 0; a < 2; ++a)
        #pragma unroll
        for (int b = 0; b < 2; ++b)
            #pragma unroll
            for (int c = 0; c < 4; ++c)
                #pragma unroll
                for (int d = 0; d < 4; ++d) acc[a][b][c][d] = 0.f;

    const int ma = tid & 127;
    const int kq = tid >> 7;
    const float* arow;
    if (docs) arow = emb + (size_t)docs[row0 + ma] * EMBD;
    else      arow = Asrc + (size_t)(row0 + ma) * K;

    const int gcol = n0 + ma;
    const int p = gcol / 400;
    const int ccol = gcol - p * 400;
    const float* Wp = (p == 0) ? W0 : (p == 1) ? W1 : W2;
    const bool colv = gcol < NCOLS;

    const int nk = (K + 31) >> 5;
    for (int ck = 0; ck < nk; ++ck) {
        const int k0 = ck * 32;
        #pragma unroll
        for (int f = 0; f < 4; ++f) {
            const int kl = kq * 16 + f * 4;
            const int kg = k0 + kl;
            float4 v = make_float4(0.f, 0.f, 0.f, 0.f);
            if (kg < K) v = *(const float4*)(arow + kg);
            As[kl + 0][ma] = v.x;
            As[kl + 1][ma] = v.y;
            As[kl + 2][ma] = v.z;
            As[kl + 3][ma] = v.w;
        }
        #pragma unroll
        for (int i = 0; i < 16; ++i) {
            const int kl = kq * 16 + i;
            const int kg = k0 + kl;
            float v = 0.f;
            if (colv && kg < K) v = Wp[(size_t)kg * 400 + ccol];
            Bs[kl][ma] = v;
        }
        __syncthreads();

        #pragma unroll 8
        for (int k = 0; k < 32; ++k) {
            const float4 a0 = *(const float4*)&As[k][tr * 4];
            const float4 a1 = *(const float4*)&As[k][64 + tr * 4];
            const float4 b0 = *(const float4*)&Bs[k][tc * 4];
            const float4 b1 = *(const float4*)&Bs[k][64 + tc * 4];
            const float ar[2][4] = {{a0.x, a0.y, a0.z, a0.w}, {a1.x, a1.y, a1.z, a1.w}};
            const float br[2][4] = {{b0.x, b0.y, b0.z, b0.w}, {b1.x, b1.y, b1.z, b1.w}};
            #pragma unroll
            for (int im = 0; im < 2; ++im)
                #pragma unroll
                for (int in_ = 0; in_ < 2; ++in_)
                    #pragma unroll
                    for (int rr = 0; rr < 4; ++rr)
                        #pragma unroll
                        for (int cc = 0; cc < 4; ++cc)
                            acc[im][in_][rr][cc] += ar[im][rr] * br[in_][cc];
        }
        __syncthreads();
    }

    #pragma unroll
    for (int in_ = 0; in_ < 2; ++in_) {
        const int ncol = n0 + in_ * 64 + tc * 4;
        if (ncol >= NCOLS) continue;
        const int pj = ncol / 400;
        const int cj = ncol - pj * 400;
        const float* Bp = (pj == 0) ? B0 : (pj == 1) ? B1 : B2;
        const float4 bv = *(const float4*)(Bp + cj);
        #pragma unroll
        for (int im = 0; im < 2; ++im) {
            #pragma unroll
            for (int rr = 0; rr < 4; ++rr) {
                const int row = row0 + im * 64 + tr * 4 + rr;
                float4 o;
                o.x = elu(acc[im][in_][rr][0] + bv.x);
                o.y = elu(acc[im][in_][rr][1] + bv.y);
                o.z = elu(acc[im][in_][rr][2] + bv.z);
                o.w = elu(acc[im][in_][rr][3] + bv.w);
                *(float4*)(C + (size_t)row * NCOLS + ncol) = o;
            }
        }
    }
}

__global__ void logits_kernel(const float* __restrict__ doc_e,
                              const float* __restrict__ fc1_w, const float* __restrict__ fc1_b,
                              const float* __restrict__ fc2_w, const float* __restrict__ fc2_b,
                              float* __restrict__ out)
{
    int o = blockIdx.x * blockDim.x + threadIdx.x;
    if (o >= BATCH * 582) return;
    int b = o / 582, jj = o - b * 582;
    const float* de = doc_e + b * AD;
    float acc;
    if (jj < 70) {
        acc = fc1_b[jj];
        for (int k = 0; k < AD; ++k) acc += de[k] * fc1_w[k * 70 + jj];
    } else {
        int j2 = jj - 70;
        acc = fc2_b[j2];
        for (int k = 0; k < AD; ++k) acc += de[k] * fc2_w[k * 512 + j2];
    }
    out[o] = acc;
}

// ---------------------------------------------------------------------------
extern "C" void kernel_launch(void* const* d_in, const int* in_sizes, int n_in,
                              void* d_out, int out_size, void* d_ws, size_t ws_size,
                              hipStream_t stream) {
    const int*   docs  = (const int*)  d_in[0];
    const float* emb   = (const float*)d_in[1];
    const float* wq_w  = (const float*)d_in[2];
    const float* wq_b  = (const float*)d_in[3];
    const float* wk_w  = (const float*)d_in[4];
    const float* wk_b  = (const float*)d_in[5];
    const float* wv_w  = (const float*)d_in[6];
    const float* wv_b  = (const float*)d_in[7];
    const float* w_tgt = (const float*)d_in[8];
    const float* lq_w  = (const float*)d_in[9];
    const float* lq_b  = (const float*)d_in[10];
    const float* lk_w  = (const float*)d_in[11];
    const float* lk_b  = (const float*)d_in[12];
    const float* lv_w  = (const float*)d_in[13];
    const float* lv_b  = (const float*)d_in[14];
    const float* l_tgt = (const float*)d_in[15];
    const float* fc1_w = (const float*)d_in[16];
    const float* fc1_b = (const float*)d_in[17];
    const float* fc2_w = (const float*)d_in[18];
    const float* fc2_b = (const float*)d_in[19];
    float* out = (float*)d_out;
    float* ws = (float*)d_ws;

    const long O_LINE_E = 0;
    const long O_MASK_L = 819200;
    const long O_DOC_E  = 821248;
    const long O_BIAS_W = 827648;
    const long O_BIAS_L = 828928;
    const long O_EMB_H  = 830208;
    const long O_EMB_L  = 5630208;
    const long O_WTW_H  = 10430208;
    const long O_WTW_L  = 10635008;
    const long O_WTL_H  = 10839808;
    const long O_WTL_L  = 11106048;
    const long O_LE_H   = 11372288;
    const long O_LE_L   = 11798272;
    const long O_R      = 12224256;

    const long LINE_QKV_FL = (long)NLINES * NCOLS;    // 2457600
    long ws_fl = (long)(ws_size / 4);
    long Rcap = ws_fl - O_R;

    if (Rcap >= LINE_QKV_FL) {
        // ================= MFMA fast path =================
        float* line_e = ws + O_LINE_E;
        float* mask_l = ws + O_MASK_L;
        float* doc_e  = ws + O_DOC_E;
        float* bias_w = ws + O_BIAS_W;
        float* bias_l = ws + O_BIAS_L;
        bf16* embh = (bf16*)(ws + O_EMB_H);
        bf16* embl = (bf16*)(ws + O_EMB_L);
        bf16* wtwh = (bf16*)(ws + O_WTW_H);
        bf16* wtwl = (bf16*)(ws + O_WTW_L);
        bf16* wtlh = (bf16*)(ws + O_WTL_H);
        bf16* wtll = (bf16*)(ws + O_WTL_L);
        bf16* leh  = (bf16*)(ws + O_LE_H);
        bf16* lel  = (bf16*)(ws + O_LE_L);
        float* R   = ws + O_R;

        split_rows<<<(30000L * 320 + 255) / 256, 256, 0, stream>>>(emb, embh, embl, 30000, 300, 320);
        split_wt<<<((long)NPAD * 320 + 255) / 256, 256, 0, stream>>>(wq_w, wk_w, wv_w,
                                                                     wq_b, wk_b, wv_b,
                                                                     wtwh, wtwl, bias_w, 300, 320);
        split_wt<<<((long)NPAD * 416 + 255) / 256, 256, 0, stream>>>(lq_w, lk_w, lv_w,
                                                                     lq_b, lk_b, lv_b,
                                                                     wtlh, wtll, bias_l, 400, 416);

        // chunk = 1024 lines (time-optimal per r5-r12 A/B)
        long maxl = Rcap / WLINE_FL;
        if (maxl > 1024) maxl = 1024;
        long chunk = (maxl / 4) * 4;
        if (chunk < 4) chunk = 4;
        for (long c0 = 0; c0 < NLINES; c0 += chunk) {
            long cl = NLINES - c0 < chunk ? NLINES - c0 : chunk;   // multiple of 4
            dim3 g1(10, (unsigned)((cl * 32) / 128));   // x=col (fastest), y=row
            mfma_gemm<<<g1, 256, 0, stream>>>(embh, embl, docs + c0 * WPL,
                                              wtwh, wtwl, bias_w, R, 320, 1);
            word_attn4<<<(unsigned)(cl * NH), 256, 0, stream>>>(R, docs + c0 * WPL, w_tgt,
                                                                line_e + c0 * AD, mask_l + c0);
        }

        split_rows<<<((long)NLINES * 416 + 255) / 256, 256, 0, stream>>>(line_e, leh, lel,
                                                                         NLINES, 400, 416);
        dim3 g2(10, NLINES / 128);
        mfma_gemm<<<g2, 256, 0, stream>>>(leh, lel, nullptr, wtlh, wtll, bias_l, R, 416, 0);
        line_attn2<<<BATCH * NH, 256, 0, stream>>>(R, R + 400, R + 800,
                                                   (long)LPD * NCOLS, (long)DPH, (long)NCOLS,
                                                   l_tgt, mask_l, doc_e);
        logits_kernel<<<(BATCH * 582 + 255) / 256, 256, 0, stream>>>(doc_e, fc1_w, fc1_b,
                                                                     fc2_w, fc2_b, out);
    } else {
        // ================= fp32 fallback =================
        const long F_FIXED = 827648;
        const long PER_LINE_FL = (long)WPL * NCOLS;
        float* line_e = ws;
        float* mask_l = ws + 819200;
        float* doc_e  = ws + 821248;
        float* R      = ws + F_FIXED;
        long Rcap2 = ws_fl - F_FIXED;

        long maxl = Rcap2 / PER_LINE_FL;
        if (maxl > NLINES) maxl = NLINES;
        long maxl4 = (maxl / 4) * 4;
        int nc = (int)((NLINES + maxl4 - 1) / maxl4);
        int chunk = (int)((NLINES + nc - 1) / nc);
        chunk = ((chunk + 3) / 4) * 4;

        for (int c0 = 0; c0 < NLINES; c0 += chunk) {
            int cl = NLINES - c0 < chunk ? NLINES - c0 : chunk;
            dim3 g1((cl * 32) / 128, 10);
            gemm_qkv<<<g1, 256, 0, stream>>>(nullptr, docs + (size_t)c0 * WPL, emb,
                                             wq_w, wk_w, wv_w, wq_b, wk_b, wv_b,
                                             R, cl * 32, EMBD);
            word_attn<<<cl, 256, 0, stream>>>(R, docs + (size_t)c0 * WPL, w_tgt,
                                              line_e + (size_t)c0 * AD, mask_l + c0);
        }
        dim3 g2(16, 10);
        gemm_qkv<<<g2, 256, 0, stream>>>(line_e, nullptr, emb,
                                         lq_w, lk_w, lv_w, lq_b, lk_b, lv_b,
                                         R, NLINES, AD);
        line_attn2<<<BATCH * NH, 256, 0, stream>>>(R, R + 400, R + 800,
                                                   (long)LPD * NCOLS, (long)DPH, (long)NCOLS,
                                                   l_tgt, mask_l, doc_e);
        logits_kernel<<<(BATCH * 582 + 255) / 256, 256, 0, stream>>>(doc_e, fc1_w, fc1_b,
                                                                     fc2_w, fc2_b, out);
    }
}